// Round 8
// baseline (23343.419 us; speedup 1.0000x reference)
//
#include <hip/hip_runtime.h>
#include <hip/hip_bf16.h>
#include <cstdint>
#include <cstddef>

// ---------------------------------------------------------------------------
// Problem constants
// ---------------------------------------------------------------------------
constexpr int V_N = 100000;   // variables
constexpr int C_N = 420000;   // clauses
constexpr int L_N = 2 * V_N;  // literals
constexpr int E_N = 3 * C_N;  // nnz edges
constexpr int NGR = 32;       // graphs
constexpr int NROUNDS = 8;
constexpr int CM_CHUNK = 28000;   // clause rows per cm-MLP chunk
constexpr int CM_NCHUNK = 15;     // 15 * 28000 = 420000

using bf16 = __hip_bfloat16;

__device__ inline float b2f(bf16 h) { return __bfloat162float(h); }
__device__ inline bf16 f2b(float f) { return __float2bfloat16(f); }

template<typename T> __device__ inline float loadT(const T* p);
template<> __device__ inline float loadT<float>(const float* p) { return *p; }
template<> __device__ inline float loadT<bf16>(const bf16* p) { return b2f(*p); }

template<typename T> __device__ inline void storeT(T* p, float v);
template<> __device__ inline void storeT<float>(float* p, float v) { *p = v; }
template<> __device__ inline void storeT<bf16>(bf16* p, float v) { *p = f2b(v); }

// runtime-dtype weight load: isf32 ? f32 buffer : packed bf16 buffer
__device__ inline float wload(const void* W, size_t idx, int isf32) {
  return isf32 ? ((const float*)W)[idx] : b2f(((const bf16*)W)[idx]);
}

// ---------------------------------------------------------------------------
// Threefry-2x32 (JAX-compatible) — host+device
// ---------------------------------------------------------------------------
__host__ __device__ inline void tf2x32(uint32_t k0, uint32_t k1,
                                       uint32_t x0, uint32_t x1,
                                       uint32_t* o0, uint32_t* o1) {
  uint32_t ks2 = k0 ^ k1 ^ 0x1BD11BDAu;
  x0 += k0; x1 += k1;
#define TFR(d) do { x0 += x1; x1 = (x1 << (d)) | (x1 >> (32 - (d))); x1 ^= x0; } while (0)
  TFR(13); TFR(15); TFR(26); TFR(6);
  x0 += k1;  x1 += ks2 + 1u;
  TFR(17); TFR(29); TFR(16); TFR(24);
  x0 += ks2; x1 += k0 + 2u;
  TFR(13); TFR(15); TFR(26); TFR(6);
  x0 += k0;  x1 += k1 + 3u;
  TFR(17); TFR(29); TFR(16); TFR(24);
  x0 += k1;  x1 += ks2 + 4u;
  TFR(13); TFR(15); TFR(26); TFR(6);
  x0 += ks2; x1 += k0 + 5u;
#undef TFR
  *o0 = x0; *o1 = x1;
}

// JAX >=0.4.30 default (threefry_partitionable=True):
// random_bits(32) element e: (h1,h2)=threefry(key, hi64(e)=0, lo64(e)=e); bits=h1^h2.
__device__ inline uint32_t part_bits(uint32_t ka, uint32_t kb, uint32_t e) {
  uint32_t h1, h2;
  tf2x32(ka, kb, 0u, e, &h1, &h2);
  return h1 ^ h2;
}

// XLA ErfInv32 polynomial (Giles)
__device__ inline float erfinv_f32(float x) {
  float w = -log1pf(-x * x);
  float p;
  if (w < 5.0f) {
    w -= 2.5f;
    p = 2.81022636e-08f;
    p = fmaf(p, w, 3.43273939e-07f);
    p = fmaf(p, w, -3.5233877e-06f);
    p = fmaf(p, w, -4.39150654e-06f);
    p = fmaf(p, w, 0.00021858087f);
    p = fmaf(p, w, -0.00125372503f);
    p = fmaf(p, w, -0.00417768164f);
    p = fmaf(p, w, 0.246640727f);
    p = fmaf(p, w, 1.50140941f);
  } else {
    w = sqrtf(w) - 3.0f;
    p = -0.000200214257f;
    p = fmaf(p, w, 0.000100950558f);
    p = fmaf(p, w, 0.00134934322f);
    p = fmaf(p, w, -0.00367342844f);
    p = fmaf(p, w, 0.00573950773f);
    p = fmaf(p, w, -0.0076224613f);
    p = fmaf(p, w, 0.00943887047f);
    p = fmaf(p, w, 1.00167406f);
    p = fmaf(p, w, 2.83297682f);
  }
  return p * x;
}

__device__ inline float normal_from_bits(uint32_t bits) {
  float u01 = __uint_as_float((bits >> 9) | 0x3f800000u) - 1.0f;  // [0,1)
  const float lo = -0.99999994f;
  float u = u01 * 2.0f + lo;   // (1.0f-lo) rounds to 2.0f in fp32
  u = fmaxf(lo, u);
  return 1.41421356f * erfinv_f32(u);
}

__device__ inline float softplusf(float x) {
  return (x > 0.0f) ? x + log1pf(expf(-x)) : log1pf(expf(x));
}

// ---------------------------------------------------------------------------
// Utility kernels
// ---------------------------------------------------------------------------
__global__ void fill_f32(float* p, size_t n, float v) {
  size_t i = (size_t)blockIdx.x * blockDim.x + threadIdx.x;
  size_t stride = (size_t)gridDim.x * blockDim.x;
  for (; i < n; i += stride) p[i] = v;
}
__global__ void fill_u32(uint32_t* p, size_t n, uint32_t v) {
  size_t i = (size_t)blockIdx.x * blockDim.x + threadIdx.x;
  size_t stride = (size_t)gridDim.x * blockDim.x;
  for (; i < n; i += stride) p[i] = v;
}
__global__ void fill_b16(bf16* p, size_t n, float v) {
  size_t i = (size_t)blockIdx.x * blockDim.x + threadIdx.x;
  size_t stride = (size_t)gridDim.x * blockDim.x;
  bf16 b = f2b(v);
  for (; i < n; i += stride) p[i] = b;
}

// Detect weight buffer dtype: packed bf16 -> low uint16 of each word is a
// Glorot weight (bf16 exponent in [0x70,0x80)); f32 -> those bits are mantissa
// noise (~6% hit rate). Majority vote. flag=1 -> f32, flag=0 -> bf16.
__global__ void detect_dtype_kernel(const uint32_t* __restrict__ w, int* __restrict__ flag) {
  if (blockIdx.x == 0 && threadIdx.x == 0) {
    int votes = 0;
    for (int i = 0; i < 16; i++) {
      uint32_t lo = w[i] & 0xFFFFu;
      uint32_t e = (lo >> 7) & 0xFFu;
      if (e >= 0x70u && e < 0x80u) votes++;
    }
    *flag = (votes >= 12) ? 0 : 1;
  }
}

__global__ void count_deg_kernel(const int* __restrict__ lit, int* __restrict__ deg) {
  int e = blockIdx.x * 256 + threadIdx.x;
  if (e < E_N) atomicAdd(&deg[lit[e]], 1);
}

__global__ void hist32_kernel(const int* __restrict__ gid, int n, int* __restrict__ out) {
  __shared__ int bins[NGR];
  int t = threadIdx.x;
  if (t < NGR) bins[t] = 0;
  __syncthreads();
  int i = blockIdx.x * 256 + t;
  if (i < n) atomicAdd(&bins[gid[i]], 1);
  __syncthreads();
  if (t < NGR && bins[t] > 0) atomicAdd(&out[t], bins[t]);
}

__global__ void weights_kernel(const int* __restrict__ deg,
                               float* __restrict__ dw, float* __restrict__ vdw) {
  int l = blockIdx.x * 256 + threadIdx.x;
  if (l < L_N) dw[l] = rsqrtf(fmaxf((float)deg[l], 1.0f));
  if (l < V_N) vdw[l] = 4.0f * rsqrtf(fmaxf((float)(deg[l] + deg[l + V_N]), 1.0f));
}

// single-block exclusive scan of L_N degrees -> offs[L_N+1]
__global__ void scan_kernel(const int* __restrict__ deg, int* __restrict__ offs) {
  __shared__ int part[256];
  __shared__ int base[257];
  int t = threadIdx.x;
  const int CH = (L_N + 255) / 256;
  int i0 = t * CH, i1 = min(L_N, i0 + CH);
  int s = 0;
  for (int i = i0; i < i1; i++) s += deg[i];
  part[t] = s;
  __syncthreads();
  if (t == 0) {
    int acc = 0;
    for (int j = 0; j < 256; j++) { base[j] = acc; acc += part[j]; }
    base[256] = acc;
  }
  __syncthreads();
  int acc = base[t];
  for (int i = i0; i < i1; i++) { offs[i] = acc; acc += deg[i]; }
  if (t == 255) offs[L_N] = base[256];
}

__global__ void csr_fill_kernel(const int* __restrict__ lit,
                                const int* __restrict__ offs, int* __restrict__ cursor,
                                int* __restrict__ csr) {
  int e = blockIdx.x * 256 + threadIdx.x;
  if (e < E_N) {
    int l = lit[e];
    int p = atomicAdd(&cursor[l], 1);
    csr[offs[l] + p] = e / 3;   // clause index (clause_idx = repeat(arange(C),3))
  }
}

// partitionable threefry normals: one eval per element
__global__ void noise_kernel(float* __restrict__ Z, uint32_t ka, uint32_t kb, int n) {
  int i = blockIdx.x * 256 + threadIdx.x;
  if (i >= n) return;
  Z[i] = normal_from_bits(part_bits(ka, kb, (uint32_t)i));
}

// ---------------------------------------------------------------------------
// GEMM: Y[N,M] = act( concat(s1*X1, s2*X2) @ W[:, wcol0:wcol0+M] + b )
// W row-major (K1+K2, Wld), runtime dtype. 64x64 tile, BK=16, 256 thr.
// ---------------------------------------------------------------------------
template<typename T1, typename T2, typename TO>
__global__ __launch_bounds__(256) void gemm_tt(
    const T1* __restrict__ X1, int ld1, int K1, float s1,
    const T2* __restrict__ X2, int ld2, int K2, float s2,
    const void* __restrict__ W, int Wld, int wcol0,
    const void* __restrict__ bias, const int* __restrict__ flagp, int relu,
    TO* __restrict__ Y, int ldy, int N, int M) {
  __shared__ __align__(16) float As[16][64];
  __shared__ __align__(16) float Bs[16][64];
  int isf32 = *flagp;
  int tid = threadIdx.x;
  int r0 = blockIdx.x * 64;
  int c0 = blockIdx.y * 64;
  int K = K1 + K2;
  float acc[4][4];
#pragma unroll
  for (int i = 0; i < 4; i++)
#pragma unroll
    for (int j = 0; j < 4; j++) acc[i][j] = 0.0f;
  int tx = tid & 15, ty = tid >> 4;
  int la_k = tid & 15, la_r = tid >> 4;
  int lb_c = tid & 63, lb_k = tid >> 6;
  for (int k0 = 0; k0 < K; k0 += 16) {
#pragma unroll
    for (int i = 0; i < 4; i++) {
      int row = r0 + la_r + 16 * i;
      int k = k0 + la_k;
      float v = 0.0f;
      if (row < N) {
        if (k < K1) v = s1 * loadT(&X1[(size_t)row * ld1 + k]);
        else if (k < K) v = s2 * loadT(&X2[(size_t)row * ld2 + (k - K1)]);
      }
      As[la_k][la_r + 16 * i] = v;
    }
#pragma unroll
    for (int i = 0; i < 4; i++) {
      int kr = k0 + lb_k + 4 * i;
      int col = c0 + lb_c;
      float v = 0.0f;
      if (kr < K && col < M) v = wload(W, (size_t)kr * Wld + wcol0 + col, isf32);
      Bs[lb_k + 4 * i][lb_c] = v;
    }
    __syncthreads();
#pragma unroll
    for (int kk = 0; kk < 16; kk++) {
      float4 a4 = *(const float4*)&As[kk][ty * 4];
      float4 b4 = *(const float4*)&Bs[kk][tx * 4];
      float a[4] = {a4.x, a4.y, a4.z, a4.w};
      float b[4] = {b4.x, b4.y, b4.z, b4.w};
#pragma unroll
      for (int i = 0; i < 4; i++)
#pragma unroll
        for (int j = 0; j < 4; j++) acc[i][j] = fmaf(a[i], b[j], acc[i][j]);
    }
    __syncthreads();
  }
  float bb[4];
#pragma unroll
  for (int j = 0; j < 4; j++) bb[j] = wload(bias, wcol0 + c0 + tx * 4 + j, isf32);
#pragma unroll
  for (int i = 0; i < 4; i++) {
    int row = r0 + ty * 4 + i;
    if (row >= N) continue;
#pragma unroll
    for (int j = 0; j < 4; j++) {
      float v = acc[i][j] + bb[j];
      if (relu) v = fmaxf(v, 0.0f);
      storeT(&Y[(size_t)row * ldy + c0 + tx * 4 + j], v);
    }
  }
}

// ug layer-0 GEMM: X = [QG(bf16) | variables(bf16) | VLpos*dw | VLneg*dw], K=256
__global__ __launch_bounds__(256) void gemm_ug0(
    const bf16* __restrict__ QG, const bf16* __restrict__ variables,
    const float* __restrict__ VL, const float* __restrict__ dw,
    const void* __restrict__ W, const void* __restrict__ bias,
    const int* __restrict__ flagp, float* __restrict__ Y, int N) {
  __shared__ __align__(16) float As[16][64];
  __shared__ __align__(16) float Bs[16][64];
  int isf32 = *flagp;
  int tid = threadIdx.x;
  int r0 = blockIdx.x * 64;
  int c0 = blockIdx.y * 64;
  float acc[4][4];
#pragma unroll
  for (int i = 0; i < 4; i++)
#pragma unroll
    for (int j = 0; j < 4; j++) acc[i][j] = 0.0f;
  int tx = tid & 15, ty = tid >> 4;
  int la_k = tid & 15, la_r = tid >> 4;
  int lb_c = tid & 63, lb_k = tid >> 6;
  for (int k0 = 0; k0 < 256; k0 += 16) {
#pragma unroll
    for (int i = 0; i < 4; i++) {
      int row = r0 + la_r + 16 * i;
      int k = k0 + la_k;
      float v = 0.0f;
      if (row < N) {
        if (k < 64)        v = b2f(QG[(size_t)row * 64 + k]);
        else if (k < 128)  v = b2f(variables[(size_t)row * 64 + (k - 64)]);
        else if (k < 192)  v = VL[(size_t)row * 64 + (k - 128)] * dw[row];
        else               v = VL[(size_t)(row + V_N) * 64 + (k - 192)] * dw[row + V_N];
      }
      As[la_k][la_r + 16 * i] = v;
    }
#pragma unroll
    for (int i = 0; i < 4; i++) {
      int kr = k0 + lb_k + 4 * i;
      Bs[lb_k + 4 * i][lb_c] = wload(W, (size_t)kr * 128 + c0 + lb_c, isf32);
    }
    __syncthreads();
#pragma unroll
    for (int kk = 0; kk < 16; kk++) {
      float4 a4 = *(const float4*)&As[kk][ty * 4];
      float4 b4 = *(const float4*)&Bs[kk][tx * 4];
      float a[4] = {a4.x, a4.y, a4.z, a4.w};
      float b[4] = {b4.x, b4.y, b4.z, b4.w};
#pragma unroll
      for (int i = 0; i < 4; i++)
#pragma unroll
        for (int j = 0; j < 4; j++) acc[i][j] = fmaf(a[i], b[j], acc[i][j]);
    }
    __syncthreads();
  }
#pragma unroll
  for (int i = 0; i < 4; i++) {
    int row = r0 + ty * 4 + i;
    if (row >= N) continue;
#pragma unroll
    for (int j = 0; j < 4; j++) {
      float v = fmaxf(acc[i][j] + wload(bias, c0 + tx * 4 + j, isf32), 0.0f);  // relu
      Y[(size_t)row * 128 + c0 + tx * 4 + j] = v;
    }
  }
}

// ---------------------------------------------------------------------------
// Edge / node kernels (wave = 64 lanes = feature dim)
// ---------------------------------------------------------------------------
__global__ void cl_kernel(const bf16* __restrict__ Q, const int* __restrict__ lit,
                          bf16* __restrict__ cl) {
  int c = blockIdx.x * 4 + threadIdx.y;
  if (c >= C_N) return;
  int k = threadIdx.x;
  float cv = 0.0f;
#pragma unroll
  for (int j = 0; j < 3; j++) {
    int l = lit[3 * c + j];
    float q = (l < V_N) ? b2f(Q[(size_t)l * 64 + k]) : -b2f(Q[(size_t)(l - V_N) * 64 + k]);
    cv += softplusf(q);
  }
  cl[(size_t)c * 64 + k] = f2b(expf(-cv));
}

// fused: G gathers (CSR) + q-grad; QG = (-sig(q)*Gpos + sig(-q)*Gneg) * vdw
__global__ void qgrad_kernel(const bf16* __restrict__ Q, const bf16* __restrict__ clb,
                             const int* __restrict__ csr, const int* __restrict__ offs,
                             const float* __restrict__ vdw, bf16* __restrict__ QG) {
  int v = blockIdx.x * 4 + threadIdx.y;
  if (v >= V_N) return;
  int k = threadIdx.x;
  float gp = 0.0f, gn = 0.0f;
  int p0 = offs[v], p1 = offs[v + 1];
  for (int p = p0; p < p1; p++) gp += b2f(clb[(size_t)csr[p] * 64 + k]);
  p0 = offs[v + V_N]; p1 = offs[v + V_N + 1];
  for (int p = p0; p < p1; p++) gn += b2f(clb[(size_t)csr[p] * 64 + k]);
  float q = b2f(Q[(size_t)v * 64 + k]);
  float sp = 1.0f / (1.0f + expf(-q));
  float sn = 1.0f / (1.0f + expf(q));
  QG[(size_t)v * 64 + k] = f2b((-sp * gp + sn * gn) * vdw[v]);
}

// scatter a Dl chunk into per-literal accumulator VL (f32 atomics)
__global__ void scatter_vl_kernel(const float* __restrict__ Dl, const int* __restrict__ lit,
                                  int e0, int e1, int r0, float* __restrict__ VL) {
  int e = e0 + blockIdx.x * 4 + threadIdx.y;
  if (e >= e1) return;
  int k = threadIdx.x;
  int l = lit[e];
  int c = e / 3;
  atomicAdd(&VL[(size_t)l * 64 + k], Dl[(size_t)(c - r0) * 64 + k]);
}

// ---------------------------------------------------------------------------
// PairNorm (3 passes; gid sorted -> run-accumulate, flush on change)
// ---------------------------------------------------------------------------
template<typename TX>
__global__ void pn_mean_kernel(const TX* __restrict__ X,
                               const int* __restrict__ gid, int n,
                               float* __restrict__ meansum) {
  int wave = blockIdx.x * blockDim.y + threadIdx.y;
  int nw = gridDim.x * blockDim.y;
  int chunk = (n + nw - 1) / nw;
  int i0 = wave * chunk;
  if (i0 >= n) return;
  int i1 = min(n, i0 + chunk);
  int k = threadIdx.x;
  int g = gid[i0];
  float acc = 0.0f;
  for (int i = i0; i < i1; i++) {
    int gi = gid[i];
    if (gi != g) { atomicAdd(&meansum[g * 64 + k], acc); acc = 0.0f; g = gi; }
    acc += loadT(&X[(size_t)i * 64 + k]);
  }
  atomicAdd(&meansum[g * 64 + k], acc);
}

template<typename TX>
__global__ void pn_var_kernel(const TX* __restrict__ X,
                              const int* __restrict__ gid, int n,
                              const int* __restrict__ cnt, const float* __restrict__ meansum,
                              float* __restrict__ varsum) {
  int wave = blockIdx.x * blockDim.y + threadIdx.y;
  int nw = gridDim.x * blockDim.y;
  int chunk = (n + nw - 1) / nw;
  int i0 = wave * chunk;
  if (i0 >= n) return;
  int i1 = min(n, i0 + chunk);
  int k = threadIdx.x;
  int g = gid[i0];
  float vacc = 0.0f;
  float invc = 1.0f / fmaxf((float)cnt[g], 1.0f);
  for (int i = i0; i < i1; i++) {
    int gi = gid[i];
    if (gi != g) {
      if (k == 0) atomicAdd(&varsum[g], vacc);
      vacc = 0.0f; g = gi;
      invc = 1.0f / fmaxf((float)cnt[g], 1.0f);
    }
    float mean = meansum[g * 64 + k] * invc;
    float d = loadT(&X[(size_t)i * 64 + k]) - mean;
    float s = d * d;
#pragma unroll
    for (int o = 32; o > 0; o >>= 1) s += __shfl_down(s, o);
    if (k == 0) vacc += s * (1.0f / 64.0f);
  }
  if (k == 0) atomicAdd(&varsum[g], vacc);
}

// state = (pairnorm(X)*0.25 + 0.1*state) * post
template<typename TX>
__global__ void pn_apply_kernel(const TX* __restrict__ X,
                                const int* __restrict__ gid, int n,
                                const int* __restrict__ cnt, const float* __restrict__ meansum,
                                const float* __restrict__ varsum, bf16* __restrict__ state,
                                float post) {
  int i = blockIdx.x * 4 + threadIdx.y;
  if (i >= n) return;
  int k = threadIdx.x;
  int g = gid[i];
  float c = fmaxf((float)cnt[g], 1.0f);
  float mean = meansum[g * 64 + k] / c;
  float var = varsum[g] / c;
  float xn = (loadT(&X[(size_t)i * 64 + k]) - mean) * rsqrtf(var + 1e-6f);
  size_t o = (size_t)i * 64 + k;
  state[o] = f2b((xn * 0.25f + 0.1f * b2f(state[o])) * post);
}

// fused co MLP: logits[c] = relu(x@W0+b0)@W1 + b1
__global__ __launch_bounds__(256) void co_kernel(
    const bf16* __restrict__ clauses, const void* __restrict__ W0,
    const void* __restrict__ b0, const void* __restrict__ W1,
    const void* __restrict__ b1, const int* __restrict__ flagp,
    float* __restrict__ logits) {
  __shared__ float w0s[64 * 64];
  int isf32 = *flagp;
  int tid = threadIdx.y * 64 + threadIdx.x;
  for (int i = tid; i < 64 * 64; i += 256) w0s[i] = wload(W0, i, isf32);
  __syncthreads();
  int c = blockIdx.x * 4 + threadIdx.y;
  if (c >= C_N) return;
  int k = threadIdx.x;
  float x = b2f(clauses[(size_t)c * 64 + k]);
  float h = wload(b0, k, isf32);
#pragma unroll 8
  for (int j = 0; j < 64; j++) h = fmaf(__shfl(x, j), w0s[j * 64 + k], h);
  h = fmaxf(h, 0.0f);
  float v = h * wload(W1, k, isf32);
#pragma unroll
  for (int o = 32; o > 0; o >>= 1) v += __shfl_down(v, o);
  if (k == 0) logits[c] = v + wload(b1, 0, isf32);
}

// out[c] = sigmoid(logit[c] + normal(keys[8])[c])   (partitionable bits, f32 out)
__global__ void final_kernel(const float* __restrict__ logits, float* __restrict__ out,
                             uint32_t ka, uint32_t kb) {
  int c = blockIdx.x * 256 + threadIdx.x;
  if (c >= C_N) return;
  float x = logits[c] + normal_from_bits(part_bits(ka, kb, (uint32_t)c));
  out[c] = 1.0f / (1.0f + expf(-x));
}

// ---------------------------------------------------------------------------
// Launch
// ---------------------------------------------------------------------------
extern "C" void kernel_launch(void* const* d_in, const int* in_sizes, int n_in,
                              void* d_out, int out_size, void* d_ws, size_t ws_size,
                              hipStream_t stream) {
  (void)in_sizes; (void)n_in; (void)out_size;
  const int* lit_idx    = (const int*)d_in[0];
  const int* var_gid    = (const int*)d_in[2];
  const int* clause_gid = (const int*)d_in[3];
  const void* vq_W0 = d_in[4];
  const void* vq_b0 = d_in[5];
  const void* vq_W1 = d_in[6];
  const void* vq_b1 = d_in[7];
  const void* cm_W0 = d_in[8];
  const void* cm_b0 = d_in[9];
  const void* cm_W1 = d_in[10];
  const void* cm_b1 = d_in[11];
  const void* ug_W0 = d_in[12];
  const void* ug_b0 = d_in[13];
  const void* ug_W1 = d_in[14];
  const void* ug_b1 = d_in[15];
  const void* ug_W2 = d_in[16];
  const void* ug_b2 = d_in[17];
  const void* co_W0 = d_in[18];
  const void* co_b0 = d_in[19];
  const void* co_W1 = d_in[20];
  const void* co_b1 = d_in[21];
  float* out = (float*)d_out;   // output read as float32 (R6 guard evidence)

  // ---- workspace layout (mixed precision; ~231 MB peak) ----
  char* ws = (char*)d_ws;
  size_t off = 0;
  auto alloc = [&](size_t bytes) -> void* {
    void* p = ws + off;
    off = (off + bytes + 255) & ~(size_t)255;
    return p;
  };
  bf16* variables = (bf16*)alloc((size_t)V_N * 64 * 2);   // persistent state
  bf16* clauses   = (bf16*)alloc((size_t)C_N * 64 * 2);   // persistent state
  // ZE: clb (Cx64 bf16) -> Dn (Cx64 bf16, chunk-reverse overlay) ->
  //     Hu (Vx128 f32) -> NV (Vx64 f32)
  char* ZE        = (char*)alloc((size_t)C_N * 64 * 2);
  // ZVL: Hv (Vx64 f32) -> VL (Lx64 f32) -> Hu2 (Vx128 f32)
  float* ZVL      = (float*)alloc((size_t)L_N * 64 * 4);
  bf16* QG        = (bf16*)alloc((size_t)V_N * 64 * 2);
  bf16* Q         = (bf16*)alloc((size_t)V_N * 64 * 2);
  float* Hc       = (float*)alloc((size_t)CM_CHUNK * 128 * 4);
  float* DlC      = (float*)alloc((size_t)CM_CHUNK * 64 * 4);
  float* Z        = (float*)alloc((size_t)V_N * 4 * 4);
  float* logits   = (float*)alloc((size_t)C_N * 4);
  int*  izone     = (int*)alloc((size_t)(2 * L_N + 64) * 4);
  int*  offs      = (int*)alloc((size_t)(L_N + 1) * 4);
  int*  csr       = (int*)alloc((size_t)E_N * 4);
  float* deg_f    = (float*)alloc((size_t)L_N * 4);
  float* vdw      = (float*)alloc((size_t)V_N * 4);
  float* stats    = (float*)alloc((size_t)(2048 + 64) * 4);
  int*   wflag    = (int*)alloc(256);
  size_t need = off;

  auto nb = [](int n, int per) { return (n + per - 1) / per; };

  if (ws_size < need) {
    // Workspace too small: DISTINCT diagnostic signature (absmax ~ 0.49).
    fill_f32<<<nb(C_N, 256), 256, 0, stream>>>(out, (size_t)C_N, 0.5f);
    return;
  }

  bf16* clb = (bf16*)ZE;                 // C x 64
  bf16* Dn  = (bf16*)ZE;                 // C x 64 (chunk-reverse overlay of clb)
  float* Hu = (float*)ZE;                // V x 128 f32 (after Dn dead)
  float* NV = (float*)ZE;                // V x 64 f32 (after Hu dead)
  float* Hv  = ZVL;                      // V x 64 f32
  float* VL  = ZVL;                      // L x 64 f32
  float* Hu2 = ZVL;                      // V x 128 f32 (after VL dead)

  int* deg_i  = izone;
  int* cursor = izone + L_N;
  int* cntv   = izone + 2 * L_N;
  int* cntc   = cntv + 32;
  float* meansum = stats;        // 32 x 64
  float* varsum  = stats + 2048; // 32

  // ---- host: JAX keys = split(key(42), 9), partitionable/foldlike:
  // subkey_i = threefry(key, x0=0, x1=i) (both output words)
  uint32_t kw0[9], kw1[9];
  for (int i = 0; i < 9; i++) tf2x32(0u, 42u, 0u, (uint32_t)i, &kw0[i], &kw1[i]);

  dim3 wb(64, 4);

  // ---- setup (re-done every call; ws is re-poisoned) ----
  detect_dtype_kernel<<<1, 64, 0, stream>>>((const uint32_t*)vq_W0, wflag);
  fill_u32<<<nb(2 * L_N + 64, 256), 256, 0, stream>>>((uint32_t*)izone, (size_t)(2 * L_N + 64), 0u);
  count_deg_kernel<<<nb(E_N, 256), 256, 0, stream>>>(lit_idx, deg_i);
  hist32_kernel<<<nb(V_N, 256), 256, 0, stream>>>(var_gid, V_N, cntv);
  hist32_kernel<<<nb(C_N, 256), 256, 0, stream>>>(clause_gid, C_N, cntc);
  weights_kernel<<<nb(L_N, 256), 256, 0, stream>>>(deg_i, deg_f, vdw);
  scan_kernel<<<1, 256, 0, stream>>>(deg_i, offs);
  csr_fill_kernel<<<nb(E_N, 256), 256, 0, stream>>>(lit_idx, offs, cursor, csr);
  fill_b16<<<2048, 256, 0, stream>>>(variables, (size_t)V_N * 64, 1.0f);
  fill_b16<<<2048, 256, 0, stream>>>(clauses, (size_t)C_N * 64, 1.0f);

  // ---- rounds ----
  for (int r = 0; r < NROUNDS; r++) {
    noise_kernel<<<nb(V_N * 4, 256), 256, 0, stream>>>(Z, kw0[r], kw1[r], V_N * 4);
    // vq MLP: query (K = 64+4)
    gemm_tt<bf16, float, float><<<dim3(nb(V_N, 64), 1), 256, 0, stream>>>(
        variables, 64, 64, 1.0f, Z, 4, 4, 1.0f, vq_W0, 64, 0, vq_b0, wflag, 1,
        Hv, 64, V_N, 64);
    gemm_tt<float, float, bf16><<<dim3(nb(V_N, 64), 1), 256, 0, stream>>>(
        Hv, 64, 64, 1.0f, (const float*)nullptr, 0, 0, 0.0f, vq_W1, 64, 0, vq_b1, wflag, 0,
        Q, 64, V_N, 64);
    // cl = exp(-sum_3 softplus(+-q))
    cl_kernel<<<nb(C_N, 4), wb, 0, stream>>>(Q, lit_idx, clb);
    // q-grad (CSR gather of clb, fused)
    qgrad_kernel<<<nb(V_N, 4), wb, 0, stream>>>(Q, clb, csr, offs, vdw, QG);
    // zero VL (Hv dead), then cm MLP chunk-REVERSE with Dn overlaying clb:
    // chunk c writes Dn rows [r0,r1) (same bytes as clb rows [r0,r1));
    // remaining chunks (< c) read clb rows < r0. Safe.
    fill_f32<<<2048, 256, 0, stream>>>(VL, (size_t)L_N * 64, 0.0f);
    for (int c = CM_NCHUNK - 1; c >= 0; c--) {
      int r0 = c * CM_CHUNK;
      int rows = min(CM_CHUNK, C_N - r0);
      gemm_tt<bf16, bf16, float><<<dim3(nb(rows, 64), 2), 256, 0, stream>>>(
          clauses + (size_t)r0 * 64, 64, 64, 1.0f, clb + (size_t)r0 * 64, 64, 64, 4.0f,
          cm_W0, 128, 0, cm_b0, wflag, 1, Hc, 128, rows, 128);
      gemm_tt<float, float, float><<<dim3(nb(rows, 64), 1), 256, 0, stream>>>(
          Hc, 128, 128, 1.0f, (const float*)nullptr, 0, 0, 0.0f, cm_W1, 128, 0, cm_b1, wflag, 0,
          DlC, 64, rows, 64);
      gemm_tt<float, float, bf16><<<dim3(nb(rows, 64), 1), 256, 0, stream>>>(
          Hc, 128, 128, 1.0f, (const float*)nullptr, 0, 0, 0.0f, cm_W1, 128, 64, cm_b1, wflag, 0,
          Dn + (size_t)r0 * 64, 64, rows, 64);
      scatter_vl_kernel<<<nb(3 * rows, 4), wb, 0, stream>>>(
          DlC, lit_idx, 3 * r0, 3 * (r0 + rows), r0, VL);
    }
    // clause pairnorm + blend (x0.2 carry except last round)
    fill_f32<<<1, 256, 0, stream>>>(stats, 2048 + 64, 0.0f);
    pn_mean_kernel<bf16><<<512, wb, 0, stream>>>(Dn, clause_gid, C_N, meansum);
    pn_var_kernel<bf16><<<512, wb, 0, stream>>>(Dn, clause_gid, C_N, cntc, meansum, varsum);
    pn_apply_kernel<bf16><<<nb(C_N, 4), wb, 0, stream>>>(Dn, clause_gid, C_N, cntc, meansum,
                                                         varsum, clauses,
                                                         (r == NROUNDS - 1) ? 1.0f : 0.2f);
    // ug MLP (Dn dead -> Hu in ZE; VL dead after ug0 -> Hu2 in ZVL; Hu dead -> NV)
    gemm_ug0<<<dim3(nb(V_N, 64), 2), 256, 0, stream>>>(QG, variables, VL, deg_f,
                                                       ug_W0, ug_b0, wflag, Hu, V_N);
    gemm_tt<float, float, float><<<dim3(nb(V_N, 64), 2), 256, 0, stream>>>(
        Hu, 128, 128, 1.0f, (const float*)nullptr, 0, 0, 0.0f, ug_W1, 128, 0, ug_b1, wflag, 1,
        Hu2, 128, V_N, 128);
    gemm_tt<float, float, float><<<dim3(nb(V_N, 64), 1), 256, 0, stream>>>(
        Hu2, 128, 128, 1.0f, (const float*)nullptr, 0, 0, 0.0f, ug_W2, 64, 0, ug_b2, wflag, 0,
        NV, 64, V_N, 64);
    // variable pairnorm + blend
    fill_f32<<<1, 256, 0, stream>>>(stats, 2048 + 64, 0.0f);
    pn_mean_kernel<float><<<512, wb, 0, stream>>>(NV, var_gid, V_N, meansum);
    pn_var_kernel<float><<<512, wb, 0, stream>>>(NV, var_gid, V_N, cntv, meansum, varsum);
    pn_apply_kernel<float><<<nb(V_N, 4), wb, 0, stream>>>(NV, var_gid, V_N, cntv, meansum,
                                                          varsum, variables, 1.0f);
  }
  // fused co MLP on final clauses -> logits; add noise(keys[8]); sigmoid
  co_kernel<<<nb(C_N, 4), wb, 0, stream>>>(clauses, co_W0, co_b0, co_W1, co_b1, wflag, logits);
  final_kernel<<<nb(C_N, 256), 256, 0, stream>>>(logits, out, kw0[8], kw1[8]);
}

// Round 9
// 15741.257 us; speedup vs baseline: 1.4829x; 1.4829x over previous
//
#include <hip/hip_runtime.h>
#include <hip/hip_bf16.h>
#include <cstdint>
#include <cstddef>

// ---------------------------------------------------------------------------
// Problem constants
// ---------------------------------------------------------------------------
constexpr int V_N = 100000;   // variables
constexpr int C_N = 420000;   // clauses
constexpr int L_N = 2 * V_N;  // literals
constexpr int E_N = 3 * C_N;  // nnz edges
constexpr int NGR = 32;       // graphs
constexpr int NROUNDS = 8;
constexpr int CM_CHUNK = 28000;   // clause rows per cm-MLP chunk
constexpr int CM_NCHUNK = 15;     // 15 * 28000 = 420000

using bf16 = __hip_bfloat16;
typedef __attribute__((ext_vector_type(8))) short short8;   // 8 bf16 (4 VGPRs)
typedef __attribute__((ext_vector_type(4))) float float4v;  // 4 fp32 acc

__device__ inline float b2f(bf16 h) { return __bfloat162float(h); }
__device__ inline bf16 f2b(float f) { return __float2bfloat16(f); }

template<typename T> __device__ inline float loadT(const T* p);
template<> __device__ inline float loadT<float>(const float* p) { return *p; }
template<> __device__ inline float loadT<bf16>(const bf16* p) { return b2f(*p); }

template<typename T> __device__ inline void storeT(T* p, float v);
template<> __device__ inline void storeT<float>(float* p, float v) { *p = v; }
template<> __device__ inline void storeT<bf16>(bf16* p, float v) { *p = f2b(v); }

// runtime-dtype weight load: isf32 ? f32 buffer : packed bf16 buffer
__device__ inline float wload(const void* W, size_t idx, int isf32) {
  return isf32 ? ((const float*)W)[idx] : b2f(((const bf16*)W)[idx]);
}

// ---------------------------------------------------------------------------
// Threefry-2x32 (JAX-compatible) — host+device
// ---------------------------------------------------------------------------
__host__ __device__ inline void tf2x32(uint32_t k0, uint32_t k1,
                                       uint32_t x0, uint32_t x1,
                                       uint32_t* o0, uint32_t* o1) {
  uint32_t ks2 = k0 ^ k1 ^ 0x1BD11BDAu;
  x0 += k0; x1 += k1;
#define TFR(d) do { x0 += x1; x1 = (x1 << (d)) | (x1 >> (32 - (d))); x1 ^= x0; } while (0)
  TFR(13); TFR(15); TFR(26); TFR(6);
  x0 += k1;  x1 += ks2 + 1u;
  TFR(17); TFR(29); TFR(16); TFR(24);
  x0 += ks2; x1 += k0 + 2u;
  TFR(13); TFR(15); TFR(26); TFR(6);
  x0 += k0;  x1 += k1 + 3u;
  TFR(17); TFR(29); TFR(16); TFR(24);
  x0 += k1;  x1 += ks2 + 4u;
  TFR(13); TFR(15); TFR(26); TFR(6);
  x0 += ks2; x1 += k0 + 5u;
#undef TFR
  *o0 = x0; *o1 = x1;
}

// JAX >=0.4.30 default (threefry_partitionable=True):
// random_bits(32) element e: (h1,h2)=threefry(key, 0, e); bits=h1^h2.
__device__ inline uint32_t part_bits(uint32_t ka, uint32_t kb, uint32_t e) {
  uint32_t h1, h2;
  tf2x32(ka, kb, 0u, e, &h1, &h2);
  return h1 ^ h2;
}

// XLA ErfInv32 polynomial (Giles)
__device__ inline float erfinv_f32(float x) {
  float w = -log1pf(-x * x);
  float p;
  if (w < 5.0f) {
    w -= 2.5f;
    p = 2.81022636e-08f;
    p = fmaf(p, w, 3.43273939e-07f);
    p = fmaf(p, w, -3.5233877e-06f);
    p = fmaf(p, w, -4.39150654e-06f);
    p = fmaf(p, w, 0.00021858087f);
    p = fmaf(p, w, -0.00125372503f);
    p = fmaf(p, w, -0.00417768164f);
    p = fmaf(p, w, 0.246640727f);
    p = fmaf(p, w, 1.50140941f);
  } else {
    w = sqrtf(w) - 3.0f;
    p = -0.000200214257f;
    p = fmaf(p, w, 0.000100950558f);
    p = fmaf(p, w, 0.00134934322f);
    p = fmaf(p, w, -0.00367342844f);
    p = fmaf(p, w, 0.00573950773f);
    p = fmaf(p, w, -0.0076224613f);
    p = fmaf(p, w, 0.00943887047f);
    p = fmaf(p, w, 1.00167406f);
    p = fmaf(p, w, 2.83297682f);
  }
  return p * x;
}

__device__ inline float normal_from_bits(uint32_t bits) {
  float u01 = __uint_as_float((bits >> 9) | 0x3f800000u) - 1.0f;  // [0,1)
  const float lo = -0.99999994f;
  float u = u01 * 2.0f + lo;
  u = fmaxf(lo, u);
  return 1.41421356f * erfinv_f32(u);
}

__device__ inline float softplusf(float x) {
  return (x > 0.0f) ? x + log1pf(expf(-x)) : log1pf(expf(x));
}

// ---------------------------------------------------------------------------
// Utility kernels
// ---------------------------------------------------------------------------
__global__ void fill_f32(float* p, size_t n, float v) {
  size_t i = (size_t)blockIdx.x * blockDim.x + threadIdx.x;
  size_t stride = (size_t)gridDim.x * blockDim.x;
  for (; i < n; i += stride) p[i] = v;
}
__global__ void fill_u32(uint32_t* p, size_t n, uint32_t v) {
  size_t i = (size_t)blockIdx.x * blockDim.x + threadIdx.x;
  size_t stride = (size_t)gridDim.x * blockDim.x;
  for (; i < n; i += stride) p[i] = v;
}
__global__ void fill_b16(bf16* p, size_t n, float v) {
  size_t i = (size_t)blockIdx.x * blockDim.x + threadIdx.x;
  size_t stride = (size_t)gridDim.x * blockDim.x;
  bf16 b = f2b(v);
  for (; i < n; i += stride) p[i] = b;
}

// Detect weight dtype (R8-verified): bf16-packed -> low u16 exponent in
// [0x70,0x80); f32 -> mantissa noise. flag=1 -> f32, flag=0 -> bf16.
__global__ void detect_dtype_kernel(const uint32_t* __restrict__ w, int* __restrict__ flag) {
  if (blockIdx.x == 0 && threadIdx.x == 0) {
    int votes = 0;
    for (int i = 0; i < 16; i++) {
      uint32_t lo = w[i] & 0xFFFFu;
      uint32_t e = (lo >> 7) & 0xFFu;
      if (e >= 0x70u && e < 0x80u) votes++;
    }
    *flag = (votes >= 12) ? 0 : 1;
  }
}

// Pack W (runtime dtype) into MFMA B-fragment order (bf16):
// out[((kt*MT+nt)*64+lane)*8+j] = W[kt*32+(lane>>4)*8+j][wcol0 + nt*16+(lane&15)]
// rows k >= srow0 scaled by sscale; rows k >= realK zeroed (K padding).
__global__ void pack_w_kernel(const void* __restrict__ W, const int* __restrict__ flagp,
                              int realK, int Kpad, int M, int Wld, int wcol0,
                              int srow0, float sscale, bf16* __restrict__ out) {
  int idx = blockIdx.x * 256 + threadIdx.x;
  if (idx >= Kpad * M) return;
  int j = idx & 7;
  int lane = (idx >> 3) & 63;
  int t = idx >> 9;
  int MT = M / 16;
  int kt = t / MT, nt = t - kt * MT;
  int k = kt * 32 + (lane >> 4) * 8 + j;
  int n = nt * 16 + (lane & 15);
  float v = 0.0f;
  if (k < realK) {
    v = wload(W, (size_t)k * Wld + wcol0 + n, *flagp);
    if (k >= srow0) v *= sscale;
  }
  out[idx] = f2b(v);
}

__global__ void count_deg_kernel(const int* __restrict__ lit, int* __restrict__ deg) {
  int e = blockIdx.x * 256 + threadIdx.x;
  if (e < E_N) atomicAdd(&deg[lit[e]], 1);
}

__global__ void hist32_kernel(const int* __restrict__ gid, int n, int* __restrict__ out) {
  __shared__ int bins[NGR];
  int t = threadIdx.x;
  if (t < NGR) bins[t] = 0;
  __syncthreads();
  int i = blockIdx.x * 256 + t;
  if (i < n) atomicAdd(&bins[gid[i]], 1);
  __syncthreads();
  if (t < NGR && bins[t] > 0) atomicAdd(&out[t], bins[t]);
}

__global__ void weights_kernel(const int* __restrict__ deg,
                               float* __restrict__ dw, float* __restrict__ vdw) {
  int l = blockIdx.x * 256 + threadIdx.x;
  if (l < L_N) dw[l] = rsqrtf(fmaxf((float)deg[l], 1.0f));
  if (l < V_N) vdw[l] = 4.0f * rsqrtf(fmaxf((float)(deg[l] + deg[l + V_N]), 1.0f));
}

// single-block exclusive scan of L_N degrees -> offs[L_N+1]
__global__ void scan_kernel(const int* __restrict__ deg, int* __restrict__ offs) {
  __shared__ int part[256];
  __shared__ int base[257];
  int t = threadIdx.x;
  const int CH = (L_N + 255) / 256;
  int i0 = t * CH, i1 = min(L_N, i0 + CH);
  int s = 0;
  for (int i = i0; i < i1; i++) s += deg[i];
  part[t] = s;
  __syncthreads();
  if (t == 0) {
    int acc = 0;
    for (int j = 0; j < 256; j++) { base[j] = acc; acc += part[j]; }
    base[256] = acc;
  }
  __syncthreads();
  int acc = base[t];
  for (int i = i0; i < i1; i++) { offs[i] = acc; acc += deg[i]; }
  if (t == 255) offs[L_N] = base[256];
}

__global__ void csr_fill_kernel(const int* __restrict__ lit,
                                const int* __restrict__ offs, int* __restrict__ cursor,
                                int* __restrict__ csr) {
  int e = blockIdx.x * 256 + threadIdx.x;
  if (e < E_N) {
    int l = lit[e];
    int p = atomicAdd(&cursor[l], 1);
    csr[offs[l] + p] = e / 3;   // clause index (clause_idx = repeat(arange(C),3))
  }
}

// noise into bf16, padded to 32 cols (cols 4..31 zero for K-padded vq GEMM)
__global__ void noise_kernel(bf16* __restrict__ Zb, uint32_t ka, uint32_t kb) {
  int idx = blockIdx.x * 256 + threadIdx.x;
  if (idx >= V_N * 32) return;
  int v = idx >> 5, j = idx & 31;
  float val = 0.0f;
  if (j < 4) val = normal_from_bits(part_bits(ka, kb, (uint32_t)(v * 4 + j)));
  Zb[idx] = f2b(val);
}

// ---------------------------------------------------------------------------
// MFMA GEMM: Y[N,M] = act( concat(X1,X2,X3) @ W + b ), all X bf16 row-major.
// 256 thr = 4 waves; wave w handles rows [blk*64+16w, +16), full M (MT tiles).
// Wp pre-packed B-fragments. K1,K1+K2 must be multiples of 8; K mult of 32.
// ---------------------------------------------------------------------------
template<int MT, typename TO>
__global__ __launch_bounds__(256) void gemm_mfma(
    const bf16* __restrict__ X1, int ld1, int K1,
    const bf16* __restrict__ X2, int ld2, int K2,
    const bf16* __restrict__ X3, int ld3, int K3,
    const bf16* __restrict__ Wp,
    const void* __restrict__ bias, int bias0, const int* __restrict__ flagp,
    int relu, TO* __restrict__ Y, int ldy, int N) {
  int tid = threadIdx.x;
  int wave = tid >> 6, lane = tid & 63;
  int quad = lane >> 4, m16 = lane & 15;
  int row = blockIdx.x * 64 + wave * 16 + m16;
  int rowc = min(row, N - 1);   // clamp: garbage rows only pollute their own m
  int K = K1 + K2 + K3;
  float4v acc[MT];
#pragma unroll
  for (int nt = 0; nt < MT; nt++) acc[nt] = (float4v){0.f, 0.f, 0.f, 0.f};
  const short8* wp8 = (const short8*)Wp;
  for (int k0 = 0; k0 < K; k0 += 32) {
    int ks = k0 + quad * 8;
    const bf16* src;
    if (ks < K1)            src = X1 + (size_t)rowc * ld1 + ks;
    else if (ks < K1 + K2)  src = X2 + (size_t)rowc * ld2 + (ks - K1);
    else                    src = X3 + (size_t)rowc * ld3 + (ks - K1 - K2);
    short8 a = *(const short8*)src;
#pragma unroll
    for (int nt = 0; nt < MT; nt++) {
      short8 b = wp8[((k0 >> 5) * MT + nt) * 64 + lane];
      acc[nt] = __builtin_amdgcn_mfma_f32_16x16x32_bf16(a, b, acc[nt], 0, 0, 0);
    }
  }
  int isf32 = *flagp;
  int rbase = blockIdx.x * 64 + wave * 16 + quad * 4;
#pragma unroll
  for (int nt = 0; nt < MT; nt++) {
    int col = nt * 16 + m16;
    float bv = wload(bias, bias0 + col, isf32);
#pragma unroll
    for (int i = 0; i < 4; i++) {
      int r = rbase + i;
      if (r < N) {
        float v = acc[nt][i] + bv;
        if (relu) v = fmaxf(v, 0.0f);
        storeT(&Y[(size_t)r * ldy + col], v);
      }
    }
  }
}

// ---------------------------------------------------------------------------
// Edge / node kernels (wave = 64 lanes = feature dim)
// ---------------------------------------------------------------------------
__global__ void cl_kernel(const bf16* __restrict__ Q, const int* __restrict__ lit,
                          bf16* __restrict__ cl) {
  int c = blockIdx.x * 4 + threadIdx.y;
  if (c >= C_N) return;
  int k = threadIdx.x;
  float cv = 0.0f;
#pragma unroll
  for (int j = 0; j < 3; j++) {
    int l = lit[3 * c + j];
    float q = (l < V_N) ? b2f(Q[(size_t)l * 64 + k]) : -b2f(Q[(size_t)(l - V_N) * 64 + k]);
    cv += softplusf(q);
  }
  cl[(size_t)c * 64 + k] = f2b(expf(-cv));
}

// fused: G gathers (CSR) + q-grad; QG = (-sig(q)*Gpos + sig(-q)*Gneg) * vdw
__global__ void qgrad_kernel(const bf16* __restrict__ Q, const bf16* __restrict__ clb,
                             const int* __restrict__ csr, const int* __restrict__ offs,
                             const float* __restrict__ vdw, bf16* __restrict__ QG) {
  int v = blockIdx.x * 4 + threadIdx.y;
  if (v >= V_N) return;
  int k = threadIdx.x;
  float gp = 0.0f, gn = 0.0f;
  int p0 = offs[v], p1 = offs[v + 1];
  for (int p = p0; p < p1; p++) gp += b2f(clb[(size_t)csr[p] * 64 + k]);
  p0 = offs[v + V_N]; p1 = offs[v + V_N + 1];
  for (int p = p0; p < p1; p++) gn += b2f(clb[(size_t)csr[p] * 64 + k]);
  float q = b2f(Q[(size_t)v * 64 + k]);
  float sp = 1.0f / (1.0f + expf(-q));
  float sn = 1.0f / (1.0f + expf(q));
  QG[(size_t)v * 64 + k] = f2b((-sp * gp + sn * gn) * vdw[v]);
}

// scatter a Dl chunk into per-literal accumulator VL (f32 atomics)
__global__ void scatter_vl_kernel(const float* __restrict__ Dl, const int* __restrict__ lit,
                                  int e0, int e1, int r0, float* __restrict__ VL) {
  int e = e0 + blockIdx.x * 4 + threadIdx.y;
  if (e >= e1) return;
  int k = threadIdx.x;
  int l = lit[e];
  int c = e / 3;
  atomicAdd(&VL[(size_t)l * 64 + k], Dl[(size_t)(c - r0) * 64 + k]);
}

// VLb[v, 0:64] = VL[v]*dw[v]; VLb[v, 64:128] = VL[v+V]*dw[v+V]  (bf16)
__global__ void vlb_kernel(const float* __restrict__ VL, const float* __restrict__ dw,
                           bf16* __restrict__ VLb) {
  int idx = blockIdx.x * 256 + threadIdx.x;
  if (idx >= V_N * 128) return;
  int v = idx >> 7, c = idx & 127;
  float val = (c < 64) ? VL[(size_t)v * 64 + c] * dw[v]
                       : VL[(size_t)(v + V_N) * 64 + (c - 64)] * dw[v + V_N];
  VLb[idx] = f2b(val);
}

// ---------------------------------------------------------------------------
// PairNorm (3 passes; gid sorted -> run-accumulate, flush on change)
// ---------------------------------------------------------------------------
template<typename TX>
__global__ void pn_mean_kernel(const TX* __restrict__ X,
                               const int* __restrict__ gid, int n,
                               float* __restrict__ meansum) {
  int wave = blockIdx.x * blockDim.y + threadIdx.y;
  int nw = gridDim.x * blockDim.y;
  int chunk = (n + nw - 1) / nw;
  int i0 = wave * chunk;
  if (i0 >= n) return;
  int i1 = min(n, i0 + chunk);
  int k = threadIdx.x;
  int g = gid[i0];
  float acc = 0.0f;
  for (int i = i0; i < i1; i++) {
    int gi = gid[i];
    if (gi != g) { atomicAdd(&meansum[g * 64 + k], acc); acc = 0.0f; g = gi; }
    acc += loadT(&X[(size_t)i * 64 + k]);
  }
  atomicAdd(&meansum[g * 64 + k], acc);
}

template<typename TX>
__global__ void pn_var_kernel(const TX* __restrict__ X,
                              const int* __restrict__ gid, int n,
                              const int* __restrict__ cnt, const float* __restrict__ meansum,
                              float* __restrict__ varsum) {
  int wave = blockIdx.x * blockDim.y + threadIdx.y;
  int nw = gridDim.x * blockDim.y;
  int chunk = (n + nw - 1) / nw;
  int i0 = wave * chunk;
  if (i0 >= n) return;
  int i1 = min(n, i0 + chunk);
  int k = threadIdx.x;
  int g = gid[i0];
  float vacc = 0.0f;
  float invc = 1.0f / fmaxf((float)cnt[g], 1.0f);
  for (int i = i0; i < i1; i++) {
    int gi = gid[i];
    if (gi != g) {
      if (k == 0) atomicAdd(&varsum[g], vacc);
      vacc = 0.0f; g = gi;
      invc = 1.0f / fmaxf((float)cnt[g], 1.0f);
    }
    float mean = meansum[g * 64 + k] * invc;
    float d = loadT(&X[(size_t)i * 64 + k]) - mean;
    float s = d * d;
#pragma unroll
    for (int o = 32; o > 0; o >>= 1) s += __shfl_down(s, o);
    if (k == 0) vacc += s * (1.0f / 64.0f);
  }
  if (k == 0) atomicAdd(&varsum[g], vacc);
}

// state = (pairnorm(X)*0.25 + 0.1*state) * post
template<typename TX>
__global__ void pn_apply_kernel(const TX* __restrict__ X,
                                const int* __restrict__ gid, int n,
                                const int* __restrict__ cnt, const float* __restrict__ meansum,
                                const float* __restrict__ varsum, bf16* __restrict__ state,
                                float post) {
  int i = blockIdx.x * 4 + threadIdx.y;
  if (i >= n) return;
  int k = threadIdx.x;
  int g = gid[i];
  float c = fmaxf((float)cnt[g], 1.0f);
  float mean = meansum[g * 64 + k] / c;
  float var = varsum[g] / c;
  float xn = (loadT(&X[(size_t)i * 64 + k]) - mean) * rsqrtf(var + 1e-6f);
  size_t o = (size_t)i * 64 + k;
  state[o] = f2b((xn * 0.25f + 0.1f * b2f(state[o])) * post);
}

// fused co MLP: logits[c] = relu(x@W0+b0)@W1 + b1
__global__ __launch_bounds__(256) void co_kernel(
    const bf16* __restrict__ clauses, const void* __restrict__ W0,
    const void* __restrict__ b0, const void* __restrict__ W1,
    const void* __restrict__ b1, const int* __restrict__ flagp,
    float* __restrict__ logits) {
  __shared__ float w0s[64 * 64];
  int isf32 = *flagp;
  int tid = threadIdx.y * 64 + threadIdx.x;
  for (int i = tid; i < 64 * 64; i += 256) w0s[i] = wload(W0, i, isf32);
  __syncthreads();
  int c = blockIdx.x * 4 + threadIdx.y;
  if (c >= C_N) return;
  int k = threadIdx.x;
  float x = b2f(clauses[(size_t)c * 64 + k]);
  float h = wload(b0, k, isf32);
#pragma unroll 8
  for (int j = 0; j < 64; j++) h = fmaf(__shfl(x, j), w0s[j * 64 + k], h);
  h = fmaxf(h, 0.0f);
  float v = h * wload(W1, k, isf32);
#pragma unroll
  for (int o = 32; o > 0; o >>= 1) v += __shfl_down(v, o);
  if (k == 0) logits[c] = v + wload(b1, 0, isf32);
}

// out[c] = sigmoid(logit[c] + normal(keys[8])[c])
__global__ void final_kernel(const float* __restrict__ logits, float* __restrict__ out,
                             uint32_t ka, uint32_t kb) {
  int c = blockIdx.x * 256 + threadIdx.x;
  if (c >= C_N) return;
  float x = logits[c] + normal_from_bits(part_bits(ka, kb, (uint32_t)c));
  out[c] = 1.0f / (1.0f + expf(-x));
}

// ---------------------------------------------------------------------------
// Launch
// ---------------------------------------------------------------------------
extern "C" void kernel_launch(void* const* d_in, const int* in_sizes, int n_in,
                              void* d_out, int out_size, void* d_ws, size_t ws_size,
                              hipStream_t stream) {
  (void)in_sizes; (void)n_in; (void)out_size;
  const int* lit_idx    = (const int*)d_in[0];
  const int* var_gid    = (const int*)d_in[2];
  const int* clause_gid = (const int*)d_in[3];
  const void* vq_W0 = d_in[4];
  const void* vq_b0 = d_in[5];
  const void* vq_W1 = d_in[6];
  const void* vq_b1 = d_in[7];
  const void* cm_W0 = d_in[8];
  const void* cm_b0 = d_in[9];
  const void* cm_W1 = d_in[10];
  const void* cm_b1 = d_in[11];
  const void* ug_W0 = d_in[12];
  const void* ug_b0 = d_in[13];
  const void* ug_W1 = d_in[14];
  const void* ug_b1 = d_in[15];
  const void* ug_W2 = d_in[16];
  const void* ug_b2 = d_in[17];
  const void* co_W0 = d_in[18];
  const void* co_b0 = d_in[19];
  const void* co_W1 = d_in[20];
  const void* co_b1 = d_in[21];
  float* out = (float*)d_out;

  // ---- workspace layout (~229 MB peak; ws known >= ~232 MB) ----
  char* ws = (char*)d_ws;
  size_t off = 0;
  auto alloc = [&](size_t bytes) -> void* {
    void* p = ws + off;
    off = (off + bytes + 255) & ~(size_t)255;
    return p;
  };
  bf16* variables = (bf16*)alloc((size_t)V_N * 64 * 2);   // persistent state
  bf16* clauses   = (bf16*)alloc((size_t)C_N * 64 * 2);   // persistent state
  // ZE (C*64*2 = 53.8MB): clb -> Dn (chunk-reverse overlay) -> [VLb | Hu -> NV]
  char* ZE        = (char*)alloc((size_t)C_N * 64 * 2);
  // ZVL (L*64*4 = 51.2MB): Hv (bf16 V*64) -> VL (f32 L*64) -> Hu2 (bf16 V*128)
  float* ZVL      = (float*)alloc((size_t)L_N * 64 * 4);
  bf16* QG        = (bf16*)alloc((size_t)V_N * 64 * 2);
  bf16* Q         = (bf16*)alloc((size_t)V_N * 64 * 2);
  bf16* Zb        = (bf16*)alloc((size_t)V_N * 32 * 2);
  bf16* Hc        = (bf16*)alloc((size_t)CM_CHUNK * 128 * 2);
  float* DlC      = (float*)alloc((size_t)CM_CHUNK * 64 * 4);
  float* logits   = (float*)alloc((size_t)C_N * 4);
  int*  izone     = (int*)alloc((size_t)(2 * L_N + 64) * 4);
  int*  offs      = (int*)alloc((size_t)(L_N + 1) * 4);
  int*  csr       = (int*)alloc((size_t)E_N * 4);
  float* deg_f    = (float*)alloc((size_t)L_N * 4);
  float* vdw      = (float*)alloc((size_t)V_N * 4);
  float* stats    = (float*)alloc((size_t)(2048 + 64) * 4);
  int*   wflag    = (int*)alloc(256);
  // packed MFMA weights (bf16)
  bf16* vq_W0p = (bf16*)alloc((size_t)96 * 64 * 2);
  bf16* vq_W1p = (bf16*)alloc((size_t)64 * 64 * 2);
  bf16* cm_W0p = (bf16*)alloc((size_t)128 * 128 * 2);
  bf16* cm_W1a = (bf16*)alloc((size_t)128 * 64 * 2);
  bf16* cm_W1b = (bf16*)alloc((size_t)128 * 64 * 2);
  bf16* ug_W0p = (bf16*)alloc((size_t)256 * 128 * 2);
  bf16* ug_W1p = (bf16*)alloc((size_t)128 * 128 * 2);
  bf16* ug_W2p = (bf16*)alloc((size_t)128 * 64 * 2);
  size_t need = off;

  auto nb = [](int n, int per) { return (n + per - 1) / per; };

  if (ws_size < need) {
    fill_f32<<<nb(C_N, 256), 256, 0, stream>>>(out, (size_t)C_N, 0.5f);
    return;
  }

  bf16* clb = (bf16*)ZE;                          // C x 64
  bf16* Dn  = (bf16*)ZE;                          // C x 64 (overlay of clb)
  bf16* VLb = (bf16*)ZE;                          // V x 128 (after Dn consumed)
  bf16* Hu  = (bf16*)(ZE + (size_t)V_N * 128 * 2);// V x 128 (after Dn consumed)
  float* NV = (float*)(ZE + (size_t)V_N * 128 * 2);// V x 64 f32 (after Hu dead)
  bf16* Hv  = (bf16*)ZVL;                         // V x 64
  float* VL = ZVL;                                // L x 64 f32 (Hv dead)
  bf16* Hu2 = (bf16*)ZVL;                         // V x 128 (VL dead)

  int* deg_i  = izone;
  int* cursor = izone + L_N;
  int* cntv   = izone + 2 * L_N;
  int* cntc   = cntv + 32;
  float* meansum = stats;        // 32 x 64
  float* varsum  = stats + 2048; // 32

  // JAX keys = split(key(42), 9), partitionable: subkey_i = threefry(key,0,i)
  uint32_t kw0[9], kw1[9];
  for (int i = 0; i < 9; i++) tf2x32(0u, 42u, 0u, (uint32_t)i, &kw0[i], &kw1[i]);

  dim3 wb(64, 4);
  const int BIG = 1 << 30;

  // ---- setup (re-done every call) ----
  detect_dtype_kernel<<<1, 64, 0, stream>>>((const uint32_t*)vq_W0, wflag);
  fill_u32<<<nb(2 * L_N + 64, 256), 256, 0, stream>>>((uint32_t*)izone, (size_t)(2 * L_N + 64), 0u);
  count_deg_kernel<<<nb(E_N, 256), 256, 0, stream>>>(lit_idx, deg_i);
  hist32_kernel<<<nb(V_N, 256), 256, 0, stream>>>(var_gid, V_N, cntv);
  hist32_kernel<<<nb(C_N, 256), 256, 0, stream>>>(clause_gid, C_N, cntc);
  weights_kernel<<<nb(L_N, 256), 256, 0, stream>>>(deg_i, deg_f, vdw);
  scan_kernel<<<1, 256, 0, stream>>>(deg_i, offs);
  csr_fill_kernel<<<nb(E_N, 256), 256, 0, stream>>>(lit_idx, offs, cursor, csr);
  fill_b16<<<2048, 256, 0, stream>>>(variables, (size_t)V_N * 64, 1.0f);
  fill_b16<<<2048, 256, 0, stream>>>(clauses, (size_t)C_N * 64, 1.0f);
  // pack weights into MFMA B-fragment order
  pack_w_kernel<<<nb(96 * 64, 256), 256, 0, stream>>>(vq_W0, wflag, 68, 96, 64, 64, 0, BIG, 1.f, vq_W0p);
  pack_w_kernel<<<nb(64 * 64, 256), 256, 0, stream>>>(vq_W1, wflag, 64, 64, 64, 64, 0, BIG, 1.f, vq_W1p);
  pack_w_kernel<<<nb(128 * 128, 256), 256, 0, stream>>>(cm_W0, wflag, 128, 128, 128, 128, 0, 64, 4.f, cm_W0p);
  pack_w_kernel<<<nb(128 * 64, 256), 256, 0, stream>>>(cm_W1, wflag, 128, 128, 64, 128, 0, BIG, 1.f, cm_W1a);
  pack_w_kernel<<<nb(128 * 64, 256), 256, 0, stream>>>(cm_W1, wflag, 128, 128, 64, 128, 64, BIG, 1.f, cm_W1b);
  pack_w_kernel<<<nb(256 * 128, 256), 256, 0, stream>>>(ug_W0, wflag, 256, 256, 128, 128, 0, BIG, 1.f, ug_W0p);
  pack_w_kernel<<<nb(128 * 128, 256), 256, 0, stream>>>(ug_W1, wflag, 128, 128, 128, 128, 0, BIG, 1.f, ug_W1p);
  pack_w_kernel<<<nb(128 * 64, 256), 256, 0, stream>>>(ug_W2, wflag, 128, 128, 64, 64, 0, BIG, 1.f, ug_W2p);

  // ---- rounds ----
  for (int r = 0; r < NROUNDS; r++) {
    noise_kernel<<<nb(V_N * 32, 256), 256, 0, stream>>>(Zb, kw0[r], kw1[r]);
    // vq MLP (K = 64 + 32-pad)
    gemm_mfma<4, bf16><<<nb(V_N, 64), 256, 0, stream>>>(
        variables, 64, 64, Zb, 32, 32, (const bf16*)nullptr, 0, 0,
        vq_W0p, vq_b0, 0, wflag, 1, Hv, 64, V_N);
    gemm_mfma<4, bf16><<<nb(V_N, 64), 256, 0, stream>>>(
        Hv, 64, 64, (const bf16*)nullptr, 0, 0, (const bf16*)nullptr, 0, 0,
        vq_W1p, vq_b1, 0, wflag, 0, Q, 64, V_N);
    cl_kernel<<<nb(C_N, 4), wb, 0, stream>>>(Q, lit_idx, clb);
    qgrad_kernel<<<nb(V_N, 4), wb, 0, stream>>>(Q, clb, csr, offs, vdw, QG);
    // zero VL (Hv dead), cm MLP chunk-REVERSE (Dn overlays clb; safe as before)
    fill_f32<<<2048, 256, 0, stream>>>(VL, (size_t)L_N * 64, 0.0f);
    for (int c = CM_NCHUNK - 1; c >= 0; c--) {
      int r0 = c * CM_CHUNK;
      int rows = min(CM_CHUNK, C_N - r0);
      gemm_mfma<8, bf16><<<nb(rows, 64), 256, 0, stream>>>(
          clauses + (size_t)r0 * 64, 64, 64, clb + (size_t)r0 * 64, 64, 64,
          (const bf16*)nullptr, 0, 0, cm_W0p, cm_b0, 0, wflag, 1, Hc, 128, rows);
      gemm_mfma<4, float><<<nb(rows, 64), 256, 0, stream>>>(
          Hc, 128, 128, (const bf16*)nullptr, 0, 0, (const bf16*)nullptr, 0, 0,
          cm_W1a, cm_b1, 0, wflag, 0, DlC, 64, rows);
      gemm_mfma<4, bf16><<<nb(rows, 64), 256, 0, stream>>>(
          Hc, 128, 128, (const bf16*)nullptr, 0, 0, (const bf16*)nullptr, 0, 0,
          cm_W1b, cm_b1, 64, wflag, 0, Dn + (size_t)r0 * 64, 64, rows);
      scatter_vl_kernel<<<nb(3 * rows, 4), wb, 0, stream>>>(
          DlC, lit_idx, 3 * r0, 3 * (r0 + rows), r0, VL);
    }
    // clause pairnorm + blend
    fill_f32<<<1, 256, 0, stream>>>(stats, 2048 + 64, 0.0f);
    pn_mean_kernel<bf16><<<512, wb, 0, stream>>>(Dn, clause_gid, C_N, meansum);
    pn_var_kernel<bf16><<<512, wb, 0, stream>>>(Dn, clause_gid, C_N, cntc, meansum, varsum);
    pn_apply_kernel<bf16><<<nb(C_N, 4), wb, 0, stream>>>(Dn, clause_gid, C_N, cntc, meansum,
                                                         varsum, clauses,
                                                         (r == NROUNDS - 1) ? 1.0f : 0.2f);
    // ug MLP (Dn consumed -> VLb+Hu in ZE; VL -> VLb then dead -> Hu2 in ZVL)
    vlb_kernel<<<nb(V_N * 128, 256), 256, 0, stream>>>(VL, deg_f, VLb);
    gemm_mfma<8, bf16><<<nb(V_N, 64), 256, 0, stream>>>(
        QG, 64, 64, variables, 64, 64, VLb, 128, 128,
        ug_W0p, ug_b0, 0, wflag, 1, Hu, 128, V_N);
    gemm_mfma<8, bf16><<<nb(V_N, 64), 256, 0, stream>>>(
        Hu, 128, 128, (const bf16*)nullptr, 0, 0, (const bf16*)nullptr, 0, 0,
        ug_W1p, ug_b1, 0, wflag, 1, Hu2, 128, V_N);
    gemm_mfma<4, float><<<nb(V_N, 64), 256, 0, stream>>>(
        Hu2, 128, 128, (const bf16*)nullptr, 0, 0, (const bf16*)nullptr, 0, 0,
        ug_W2p, ug_b2, 0, wflag, 0, NV, 64, V_N);
    // variable pairnorm + blend
    fill_f32<<<1, 256, 0, stream>>>(stats, 2048 + 64, 0.0f);
    pn_mean_kernel<float><<<512, wb, 0, stream>>>(NV, var_gid, V_N, meansum);
    pn_var_kernel<float><<<512, wb, 0, stream>>>(NV, var_gid, V_N, cntv, meansum, varsum);
    pn_apply_kernel<float><<<nb(V_N, 4), wb, 0, stream>>>(NV, var_gid, V_N, cntv, meansum,
                                                          varsum, variables, 1.0f);
  }
  co_kernel<<<nb(C_N, 4), wb, 0, stream>>>(clauses, co_W0, co_b0, co_W1, co_b1, wflag, logits);
  final_kernel<<<nb(C_N, 256), 256, 0, stream>>>(logits, out, kw0[8], kw1[8]);
}

// Round 10
// 10886.252 us; speedup vs baseline: 2.1443x; 1.4460x over previous
//
#include <hip/hip_runtime.h>
#include <hip/hip_bf16.h>
#include <cstdint>
#include <cstddef>

// ---------------------------------------------------------------------------
// Problem constants
// ---------------------------------------------------------------------------
constexpr int V_N = 100000;   // variables
constexpr int C_N = 420000;   // clauses
constexpr int L_N = 2 * V_N;  // literals
constexpr int E_N = 3 * C_N;  // nnz edges
constexpr int NGR = 32;       // graphs
constexpr int NROUNDS = 8;
constexpr int CM_CHUNK = 60000;   // clause rows per cm-MLP chunk
constexpr int CM_NCHUNK = 7;      // 7 * 60000 = 420000

using bf16 = __hip_bfloat16;
typedef __attribute__((ext_vector_type(8))) short short8;   // 8 bf16 (4 VGPRs)
typedef __attribute__((ext_vector_type(4))) float float4v;  // 4 fp32 acc

__device__ inline float b2f(bf16 h) { return __bfloat162float(h); }
__device__ inline bf16 f2b(float f) { return __float2bfloat16(f); }

template<typename T> __device__ inline float loadT(const T* p);
template<> __device__ inline float loadT<float>(const float* p) { return *p; }
template<> __device__ inline float loadT<bf16>(const bf16* p) { return b2f(*p); }

template<typename T> __device__ inline void storeT(T* p, float v);
template<> __device__ inline void storeT<float>(float* p, float v) { *p = v; }
template<> __device__ inline void storeT<bf16>(bf16* p, float v) { *p = f2b(v); }

// runtime-dtype weight load: isf32 ? f32 buffer : packed bf16 buffer
__device__ inline float wload(const void* W, size_t idx, int isf32) {
  return isf32 ? ((const float*)W)[idx] : b2f(((const bf16*)W)[idx]);
}

// ---------------------------------------------------------------------------
// Threefry-2x32 (JAX-compatible, partitionable) — host+device
// ---------------------------------------------------------------------------
__host__ __device__ inline void tf2x32(uint32_t k0, uint32_t k1,
                                       uint32_t x0, uint32_t x1,
                                       uint32_t* o0, uint32_t* o1) {
  uint32_t ks2 = k0 ^ k1 ^ 0x1BD11BDAu;
  x0 += k0; x1 += k1;
#define TFR(d) do { x0 += x1; x1 = (x1 << (d)) | (x1 >> (32 - (d))); x1 ^= x0; } while (0)
  TFR(13); TFR(15); TFR(26); TFR(6);
  x0 += k1;  x1 += ks2 + 1u;
  TFR(17); TFR(29); TFR(16); TFR(24);
  x0 += ks2; x1 += k0 + 2u;
  TFR(13); TFR(15); TFR(26); TFR(6);
  x0 += k0;  x1 += k1 + 3u;
  TFR(17); TFR(29); TFR(16); TFR(24);
  x0 += k1;  x1 += ks2 + 4u;
  TFR(13); TFR(15); TFR(26); TFR(6);
  x0 += ks2; x1 += k0 + 5u;
#undef TFR
  *o0 = x0; *o1 = x1;
}

__device__ inline uint32_t part_bits(uint32_t ka, uint32_t kb, uint32_t e) {
  uint32_t h1, h2;
  tf2x32(ka, kb, 0u, e, &h1, &h2);
  return h1 ^ h2;
}

// XLA ErfInv32 polynomial (Giles)
__device__ inline float erfinv_f32(float x) {
  float w = -log1pf(-x * x);
  float p;
  if (w < 5.0f) {
    w -= 2.5f;
    p = 2.81022636e-08f;
    p = fmaf(p, w, 3.43273939e-07f);
    p = fmaf(p, w, -3.5233877e-06f);
    p = fmaf(p, w, -4.39150654e-06f);
    p = fmaf(p, w, 0.00021858087f);
    p = fmaf(p, w, -0.00125372503f);
    p = fmaf(p, w, -0.00417768164f);
    p = fmaf(p, w, 0.246640727f);
    p = fmaf(p, w, 1.50140941f);
  } else {
    w = sqrtf(w) - 3.0f;
    p = -0.000200214257f;
    p = fmaf(p, w, 0.000100950558f);
    p = fmaf(p, w, 0.00134934322f);
    p = fmaf(p, w, -0.00367342844f);
    p = fmaf(p, w, 0.00573950773f);
    p = fmaf(p, w, -0.0076224613f);
    p = fmaf(p, w, 0.00943887047f);
    p = fmaf(p, w, 1.00167406f);
    p = fmaf(p, w, 2.83297682f);
  }
  return p * x;
}

__device__ inline float normal_from_bits(uint32_t bits) {
  float u01 = __uint_as_float((bits >> 9) | 0x3f800000u) - 1.0f;  // [0,1)
  const float lo = -0.99999994f;
  float u = u01 * 2.0f + lo;
  u = fmaxf(lo, u);
  return 1.41421356f * erfinv_f32(u);
}

__device__ inline float softplusf(float x) {
  return (x > 0.0f) ? x + log1pf(expf(-x)) : log1pf(expf(x));
}

// ---------------------------------------------------------------------------
// Utility kernels
// ---------------------------------------------------------------------------
__global__ void fill_f32(float* p, size_t n, float v) {
  size_t i = (size_t)blockIdx.x * blockDim.x + threadIdx.x;
  size_t stride = (size_t)gridDim.x * blockDim.x;
  for (; i < n; i += stride) p[i] = v;
}
__global__ void fill_u32(uint32_t* p, size_t n, uint32_t v) {
  size_t i = (size_t)blockIdx.x * blockDim.x + threadIdx.x;
  size_t stride = (size_t)gridDim.x * blockDim.x;
  for (; i < n; i += stride) p[i] = v;
}
__global__ void fill_b16(bf16* p, size_t n, float v) {
  size_t i = (size_t)blockIdx.x * blockDim.x + threadIdx.x;
  size_t stride = (size_t)gridDim.x * blockDim.x;
  bf16 b = f2b(v);
  for (; i < n; i += stride) p[i] = b;
}

// Detect weight dtype (R8-verified): bf16-packed -> low u16 exponent in
// [0x70,0x80); f32 -> mantissa noise. flag=1 -> f32, flag=0 -> bf16.
__global__ void detect_dtype_kernel(const uint32_t* __restrict__ w, int* __restrict__ flag) {
  if (blockIdx.x == 0 && threadIdx.x == 0) {
    int votes = 0;
    for (int i = 0; i < 16; i++) {
      uint32_t lo = w[i] & 0xFFFFu;
      uint32_t e = (lo >> 7) & 0xFFu;
      if (e >= 0x70u && e < 0x80u) votes++;
    }
    *flag = (votes >= 12) ? 0 : 1;
  }
}

// Pack W into MFMA B-fragment order (bf16):
// out[((kt*MT+nt)*64+lane)*8+j] = W[kt*32+(lane>>4)*8+j][wcol0 + nt*16+(lane&15)]
// rows k >= srow0 scaled by sscale; rows k >= realK zeroed (K padding).
__global__ void pack_w_kernel(const void* __restrict__ W, const int* __restrict__ flagp,
                              int realK, int Kpad, int M, int Wld, int wcol0,
                              int srow0, float sscale, bf16* __restrict__ out) {
  int idx = blockIdx.x * 256 + threadIdx.x;
  if (idx >= Kpad * M) return;
  int j = idx & 7;
  int lane = (idx >> 3) & 63;
  int t = idx >> 9;
  int MT = M / 16;
  int kt = t / MT, nt = t - kt * MT;
  int k = kt * 32 + (lane >> 4) * 8 + j;
  int n = nt * 16 + (lane & 15);
  float v = 0.0f;
  if (k < realK) {
    v = wload(W, (size_t)k * Wld + wcol0 + n, *flagp);
    if (k >= srow0) v *= sscale;
  }
  out[idx] = f2b(v);
}

__global__ void count_deg_kernel(const int* __restrict__ lit, int* __restrict__ deg) {
  int e = blockIdx.x * 256 + threadIdx.x;
  if (e < E_N) atomicAdd(&deg[lit[e]], 1);
}

__global__ void hist32_kernel(const int* __restrict__ gid, int n, int* __restrict__ out) {
  __shared__ int bins[NGR];
  int t = threadIdx.x;
  if (t < NGR) bins[t] = 0;
  __syncthreads();
  int i = blockIdx.x * 256 + t;
  if (i < n) atomicAdd(&bins[gid[i]], 1);
  __syncthreads();
  if (t < NGR && bins[t] > 0) atomicAdd(&out[t], bins[t]);
}

__global__ void weights_kernel(const int* __restrict__ deg,
                               float* __restrict__ dw, float* __restrict__ vdw) {
  int l = blockIdx.x * 256 + threadIdx.x;
  if (l < L_N) dw[l] = rsqrtf(fmaxf((float)deg[l], 1.0f));
  if (l < V_N) vdw[l] = 4.0f * rsqrtf(fmaxf((float)(deg[l] + deg[l + V_N]), 1.0f));
}

// single-block exclusive scan of L_N degrees -> offs[L_N+1]
__global__ void scan_kernel(const int* __restrict__ deg, int* __restrict__ offs) {
  __shared__ int part[256];
  __shared__ int base[257];
  int t = threadIdx.x;
  const int CH = (L_N + 255) / 256;
  int i0 = t * CH, i1 = min(L_N, i0 + CH);
  int s = 0;
  for (int i = i0; i < i1; i++) s += deg[i];
  part[t] = s;
  __syncthreads();
  if (t == 0) {
    int acc = 0;
    for (int j = 0; j < 256; j++) { base[j] = acc; acc += part[j]; }
    base[256] = acc;
  }
  __syncthreads();
  int acc = base[t];
  for (int i = i0; i < i1; i++) { offs[i] = acc; acc += deg[i]; }
  if (t == 255) offs[L_N] = base[256];
}

__global__ void csr_fill_kernel(const int* __restrict__ lit,
                                const int* __restrict__ offs, int* __restrict__ cursor,
                                int* __restrict__ csr) {
  int e = blockIdx.x * 256 + threadIdx.x;
  if (e < E_N) {
    int l = lit[e];
    int p = atomicAdd(&cursor[l], 1);
    csr[offs[l] + p] = e / 3;   // clause index (clause_idx = repeat(arange(C),3))
  }
}

// per-round: write only the 4 real noise columns (pad zeroed once at setup)
__global__ void noise4_kernel(bf16* __restrict__ Zb, uint32_t ka, uint32_t kb) {
  int idx = blockIdx.x * 256 + threadIdx.x;
  if (idx >= V_N * 4) return;
  int v = idx >> 2, j = idx & 3;
  Zb[(size_t)v * 32 + j] = f2b(normal_from_bits(part_bits(ka, kb, (uint32_t)idx)));
}

// ---------------------------------------------------------------------------
// MFMA GEMM: Y[N,M] = act( concat(X1,X2,X3) @ W + b ), all X bf16 row-major.
// 256 thr = 4 waves; wave w handles rows [blk*64+16w, +16), full M (MT tiles).
// ---------------------------------------------------------------------------
template<int MT, typename TO>
__global__ __launch_bounds__(256) void gemm_mfma(
    const bf16* __restrict__ X1, int ld1, int K1,
    const bf16* __restrict__ X2, int ld2, int K2,
    const bf16* __restrict__ X3, int ld3, int K3,
    const bf16* __restrict__ Wp,
    const void* __restrict__ bias, int bias0, const int* __restrict__ flagp,
    int relu, TO* __restrict__ Y, int ldy, int N) {
  int tid = threadIdx.x;
  int wave = tid >> 6, lane = tid & 63;
  int quad = lane >> 4, m16 = lane & 15;
  int row = blockIdx.x * 64 + wave * 16 + m16;
  int rowc = min(row, N - 1);
  int K = K1 + K2 + K3;
  float4v acc[MT];
#pragma unroll
  for (int nt = 0; nt < MT; nt++) acc[nt] = (float4v){0.f, 0.f, 0.f, 0.f};
  const short8* wp8 = (const short8*)Wp;
  for (int k0 = 0; k0 < K; k0 += 32) {
    int ks = k0 + quad * 8;
    const bf16* src;
    if (ks < K1)            src = X1 + (size_t)rowc * ld1 + ks;
    else if (ks < K1 + K2)  src = X2 + (size_t)rowc * ld2 + (ks - K1);
    else                    src = X3 + (size_t)rowc * ld3 + (ks - K1 - K2);
    short8 a = *(const short8*)src;
#pragma unroll
    for (int nt = 0; nt < MT; nt++) {
      short8 b = wp8[((k0 >> 5) * MT + nt) * 64 + lane];
      acc[nt] = __builtin_amdgcn_mfma_f32_16x16x32_bf16(a, b, acc[nt], 0, 0, 0);
    }
  }
  int isf32 = *flagp;
  int rbase = blockIdx.x * 64 + wave * 16 + quad * 4;
#pragma unroll
  for (int nt = 0; nt < MT; nt++) {
    int col = nt * 16 + m16;
    float bv = wload(bias, bias0 + col, isf32);
#pragma unroll
    for (int i = 0; i < 4; i++) {
      int r = rbase + i;
      if (r < N) {
        float v = acc[nt][i] + bv;
        if (relu) v = fmaxf(v, 0.0f);
        storeT(&Y[(size_t)r * ldy + col], v);
      }
    }
  }
}

// Dual-output variant: D = X1 @ W + b (K=128, M=128); cols 0..63 -> Ya (Dl),
// cols 64..127 -> Yb (Dn). Both bf16, ldy=64.
__global__ __launch_bounds__(256) void gemm_mfma_dual(
    const bf16* __restrict__ X1, int ld1,
    const bf16* __restrict__ Wp,
    const void* __restrict__ bias, const int* __restrict__ flagp,
    bf16* __restrict__ Ya, bf16* __restrict__ Yb, int N) {
  constexpr int MT = 8;
  int tid = threadIdx.x;
  int wave = tid >> 6, lane = tid & 63;
  int quad = lane >> 4, m16 = lane & 15;
  int row = blockIdx.x * 64 + wave * 16 + m16;
  int rowc = min(row, N - 1);
  float4v acc[MT];
#pragma unroll
  for (int nt = 0; nt < MT; nt++) acc[nt] = (float4v){0.f, 0.f, 0.f, 0.f};
  const short8* wp8 = (const short8*)Wp;
  for (int k0 = 0; k0 < 128; k0 += 32) {
    short8 a = *(const short8*)(X1 + (size_t)rowc * ld1 + k0 + quad * 8);
#pragma unroll
    for (int nt = 0; nt < MT; nt++) {
      short8 b = wp8[((k0 >> 5) * MT + nt) * 64 + lane];
      acc[nt] = __builtin_amdgcn_mfma_f32_16x16x32_bf16(a, b, acc[nt], 0, 0, 0);
    }
  }
  int isf32 = *flagp;
  int rbase = blockIdx.x * 64 + wave * 16 + quad * 4;
#pragma unroll
  for (int nt = 0; nt < MT; nt++) {
    int col = nt * 16 + m16;
    float bv = wload(bias, col, isf32);
#pragma unroll
    for (int i = 0; i < 4; i++) {
      int r = rbase + i;
      if (r < N) {
        float v = acc[nt][i] + bv;
        if (col < 64) Ya[(size_t)r * 64 + col] = f2b(v);
        else          Yb[(size_t)r * 64 + (col - 64)] = f2b(v);
      }
    }
  }
}

// ---------------------------------------------------------------------------
// Edge / node kernels (wave = 64 lanes = feature dim)
// ---------------------------------------------------------------------------
__global__ void cl_kernel(const bf16* __restrict__ Q, const int* __restrict__ lit,
                          bf16* __restrict__ cl) {
  int c = blockIdx.x * 4 + threadIdx.y;
  if (c >= C_N) return;
  int k = threadIdx.x;
  float cv = 0.0f;
#pragma unroll
  for (int j = 0; j < 3; j++) {
    int l = lit[3 * c + j];
    float q = (l < V_N) ? b2f(Q[(size_t)l * 64 + k]) : -b2f(Q[(size_t)(l - V_N) * 64 + k]);
    cv += softplusf(q);
  }
  cl[(size_t)c * 64 + k] = f2b(expf(-cv));
}

// fused: G gathers (CSR) + q-grad; QG = (-sig(q)*Gpos + sig(-q)*Gneg) * vdw
__global__ void qgrad_kernel(const bf16* __restrict__ Q, const bf16* __restrict__ clb,
                             const int* __restrict__ csr, const int* __restrict__ offs,
                             const float* __restrict__ vdw, bf16* __restrict__ QG) {
  int v = blockIdx.x * 4 + threadIdx.y;
  if (v >= V_N) return;
  int k = threadIdx.x;
  float gp = 0.0f, gn = 0.0f;
  int p0 = offs[v], p1 = offs[v + 1];
  for (int p = p0; p < p1; p++) gp += b2f(clb[(size_t)csr[p] * 64 + k]);
  p0 = offs[v + V_N]; p1 = offs[v + V_N + 1];
  for (int p = p0; p < p1; p++) gn += b2f(clb[(size_t)csr[p] * 64 + k]);
  float q = b2f(Q[(size_t)v * 64 + k]);
  float sp = 1.0f / (1.0f + expf(-q));
  float sn = 1.0f / (1.0f + expf(q));
  QG[(size_t)v * 64 + k] = f2b((-sp * gp + sn * gn) * vdw[v]);
}

// VLb via CSR gather of Dl (replaces scatter atomics + fill + vlb pass):
// literal l: s = dw[l] * sum_{c in csr(l)} Dl[c][k];
// row v = l mod V; col = k (pos) or 64+k (neg).
__global__ void vlb_gather_kernel(const bf16* __restrict__ Dl, const int* __restrict__ csr,
                                  const int* __restrict__ offs, const float* __restrict__ dw,
                                  bf16* __restrict__ VLb) {
  int l = blockIdx.x * 4 + threadIdx.y;
  if (l >= L_N) return;
  int k = threadIdx.x;
  float s = 0.0f;
  int p0 = offs[l], p1 = offs[l + 1];
  for (int p = p0; p < p1; p++) s += b2f(Dl[(size_t)csr[p] * 64 + k]);
  s *= dw[l];
  size_t v = (l < V_N) ? (size_t)l : (size_t)(l - V_N);
  int col = (l < V_N) ? 0 : 64;
  VLb[v * 128 + col + k] = f2b(s);
}

// ---------------------------------------------------------------------------
// PairNorm — one stats pass (S1,S2), finish, apply.
// ---------------------------------------------------------------------------
template<typename TX>
__global__ void pn_stats_kernel(const TX* __restrict__ X,
                                const int* __restrict__ gid, int n,
                                float* __restrict__ S1, float* __restrict__ S2) {
  int wave = blockIdx.x * blockDim.y + threadIdx.y;
  int nw = gridDim.x * blockDim.y;
  int chunk = (n + nw - 1) / nw;
  int i0 = wave * chunk;
  if (i0 >= n) return;
  int i1 = min(n, i0 + chunk);
  int k = threadIdx.x;
  int g = gid[i0];
  float a1 = 0.0f, a2 = 0.0f;
  for (int i = i0; i < i1; i++) {
    int gi = gid[i];
    if (gi != g) {
      atomicAdd(&S1[g * 64 + k], a1);
      atomicAdd(&S2[g * 64 + k], a2);
      a1 = 0.0f; a2 = 0.0f; g = gi;
    }
    float x = loadT(&X[(size_t)i * 64 + k]);
    a1 += x;
    a2 += x * x;
  }
  atomicAdd(&S1[g * 64 + k], a1);
  atomicAdd(&S2[g * 64 + k], a2);
}

// varsum[g] = (1/64) sum_k (S2/c - (S1/c)^2)
__global__ void pn_finish_kernel(const float* __restrict__ S1, const float* __restrict__ S2,
                                 const int* __restrict__ cnt, float* __restrict__ varsum) {
  int g = blockIdx.x;
  int k = threadIdx.x;
  float c = fmaxf((float)cnt[g], 1.0f);
  float m = S1[g * 64 + k] / c;
  float t = S2[g * 64 + k] / c - m * m;
#pragma unroll
  for (int o = 32; o > 0; o >>= 1) t += __shfl_down(t, o);
  if (k == 0) varsum[g] = fmaxf(t, 0.0f) * (1.0f / 64.0f);
}

// state = (pairnorm(X)*0.25 + 0.1*state) * post   (var precomputed)
template<typename TX>
__global__ void pn_apply_kernel(const TX* __restrict__ X,
                                const int* __restrict__ gid, int n,
                                const int* __restrict__ cnt, const float* __restrict__ S1,
                                const float* __restrict__ varsum, bf16* __restrict__ state,
                                float post) {
  int i = blockIdx.x * 4 + threadIdx.y;
  if (i >= n) return;
  int k = threadIdx.x;
  int g = gid[i];
  float c = fmaxf((float)cnt[g], 1.0f);
  float mean = S1[g * 64 + k] / c;
  float var = varsum[g];
  float xn = (loadT(&X[(size_t)i * 64 + k]) - mean) * rsqrtf(var + 1e-6f);
  size_t o = (size_t)i * 64 + k;
  state[o] = f2b((xn * 0.25f + 0.1f * b2f(state[o])) * post);
}

// fused co MLP: logits[c] = relu(x@W0+b0)@W1 + b1
__global__ __launch_bounds__(256) void co_kernel(
    const bf16* __restrict__ clauses, const void* __restrict__ W0,
    const void* __restrict__ b0, const void* __restrict__ W1,
    const void* __restrict__ b1, const int* __restrict__ flagp,
    float* __restrict__ logits) {
  __shared__ float w0s[64 * 64];
  int isf32 = *flagp;
  int tid = threadIdx.y * 64 + threadIdx.x;
  for (int i = tid; i < 64 * 64; i += 256) w0s[i] = wload(W0, i, isf32);
  __syncthreads();
  int c = blockIdx.x * 4 + threadIdx.y;
  if (c >= C_N) return;
  int k = threadIdx.x;
  float x = b2f(clauses[(size_t)c * 64 + k]);
  float h = wload(b0, k, isf32);
#pragma unroll 8
  for (int j = 0; j < 64; j++) h = fmaf(__shfl(x, j), w0s[j * 64 + k], h);
  h = fmaxf(h, 0.0f);
  float v = h * wload(W1, k, isf32);
#pragma unroll
  for (int o = 32; o > 0; o >>= 1) v += __shfl_down(v, o);
  if (k == 0) logits[c] = v + wload(b1, 0, isf32);
}

// out[c] = sigmoid(logit[c] + normal(keys[8])[c])
__global__ void final_kernel(const float* __restrict__ logits, float* __restrict__ out,
                             uint32_t ka, uint32_t kb) {
  int c = blockIdx.x * 256 + threadIdx.x;
  if (c >= C_N) return;
  float x = logits[c] + normal_from_bits(part_bits(ka, kb, (uint32_t)c));
  out[c] = 1.0f / (1.0f + expf(-x));
}

// ---------------------------------------------------------------------------
// Launch
// ---------------------------------------------------------------------------
extern "C" void kernel_launch(void* const* d_in, const int* in_sizes, int n_in,
                              void* d_out, int out_size, void* d_ws, size_t ws_size,
                              hipStream_t stream) {
  (void)in_sizes; (void)n_in; (void)out_size;
  const int* lit_idx    = (const int*)d_in[0];
  const int* var_gid    = (const int*)d_in[2];
  const int* clause_gid = (const int*)d_in[3];
  const void* vq_W0 = d_in[4];
  const void* vq_b0 = d_in[5];
  const void* vq_W1 = d_in[6];
  const void* vq_b1 = d_in[7];
  const void* cm_W0 = d_in[8];
  const void* cm_b0 = d_in[9];
  const void* cm_W1 = d_in[10];
  const void* cm_b1 = d_in[11];
  const void* ug_W0 = d_in[12];
  const void* ug_b0 = d_in[13];
  const void* ug_W1 = d_in[14];
  const void* ug_b1 = d_in[15];
  const void* ug_W2 = d_in[16];
  const void* ug_b2 = d_in[17];
  const void* co_W0 = d_in[18];
  const void* co_b0 = d_in[19];
  const void* co_W1 = d_in[20];
  const void* co_b1 = d_in[21];
  float* out = (float*)d_out;

  // ---- workspace layout (~232 MB peak; <= R3's proven 233 MB) ----
  char* ws = (char*)d_ws;
  size_t off = 0;
  auto alloc = [&](size_t bytes) -> void* {
    void* p = ws + off;
    off = (off + bytes + 255) & ~(size_t)255;
    return p;
  };
  bf16* variables = (bf16*)alloc((size_t)V_N * 64 * 2);   // persistent state
  bf16* clauses   = (bf16*)alloc((size_t)C_N * 64 * 2);   // persistent state
  // ZE (C*64*2): clb -> Dn (chunk-reverse overlay) -> VLb (V*128)
  char* ZE        = (char*)alloc((size_t)C_N * 64 * 2);
  // ZD (C*64*2): Hv (V*64) -> Dl (C*64) -> Hu (V*128) | Hu2 (V*128) -> NV f32 (V*64)
  char* ZD        = (char*)alloc((size_t)C_N * 64 * 2);
  bf16* QG        = (bf16*)alloc((size_t)V_N * 64 * 2);
  bf16* Q         = (bf16*)alloc((size_t)V_N * 64 * 2);
  bf16* Zb        = (bf16*)alloc((size_t)V_N * 32 * 2);
  bf16* Hc        = (bf16*)alloc((size_t)CM_CHUNK * 128 * 2);
  float* logits   = (float*)alloc((size_t)C_N * 4);
  int*  izone     = (int*)alloc((size_t)(2 * L_N + 64) * 4);
  int*  offs      = (int*)alloc((size_t)(L_N + 1) * 4);
  int*  csr       = (int*)alloc((size_t)E_N * 4);
  float* deg_f    = (float*)alloc((size_t)L_N * 4);
  float* vdw      = (float*)alloc((size_t)V_N * 4);
  float* stats    = (float*)alloc((size_t)(4096 + 64) * 4);
  int*   wflag    = (int*)alloc(256);
  // packed MFMA weights (bf16)
  bf16* vq_W0p = (bf16*)alloc((size_t)96 * 64 * 2);
  bf16* vq_W1p = (bf16*)alloc((size_t)64 * 64 * 2);
  bf16* cm_W0p = (bf16*)alloc((size_t)128 * 128 * 2);
  bf16* cm_W1p = (bf16*)alloc((size_t)128 * 128 * 2);
  bf16* ug_W0p = (bf16*)alloc((size_t)256 * 128 * 2);
  bf16* ug_W1p = (bf16*)alloc((size_t)128 * 128 * 2);
  bf16* ug_W2p = (bf16*)alloc((size_t)128 * 64 * 2);
  size_t need = off;

  auto nb = [](int n, int per) { return (n + per - 1) / per; };

  if (ws_size < need) {
    fill_f32<<<nb(C_N, 256), 256, 0, stream>>>(out, (size_t)C_N, 0.5f);
    return;
  }

  bf16* clb = (bf16*)ZE;                           // C x 64
  bf16* Dn  = (bf16*)ZE;                           // C x 64 (overlay of clb)
  bf16* VLb = (bf16*)ZE;                           // V x 128 (after Dn consumed)
  bf16* Hv  = (bf16*)ZD;                           // V x 64  (vq phase; Dl dead)
  bf16* Dl  = (bf16*)ZD;                           // C x 64  (cm -> gather)
  bf16* Hu  = (bf16*)ZD;                           // V x 128 (after Dl consumed)
  bf16* Hu2 = (bf16*)(ZD + (size_t)V_N * 128 * 2); // V x 128
  float* NV = (float*)ZD;                          // V x 64 f32 (after Hu dead)

  int* deg_i  = izone;
  int* cursor = izone + L_N;
  int* cntv   = izone + 2 * L_N;
  int* cntc   = cntv + 32;
  float* S1 = stats;              // 32 x 64
  float* S2 = stats + 2048;       // 32 x 64
  float* varsum = stats + 4096;   // 32

  // JAX keys = split(key(42), 9), partitionable: subkey_i = threefry(key,0,i)
  uint32_t kw0[9], kw1[9];
  for (int i = 0; i < 9; i++) tf2x32(0u, 42u, 0u, (uint32_t)i, &kw0[i], &kw1[i]);

  dim3 wb(64, 4);
  const int BIG = 1 << 30;

  // ---- setup (re-done every call) ----
  detect_dtype_kernel<<<1, 64, 0, stream>>>((const uint32_t*)vq_W0, wflag);
  fill_u32<<<nb(2 * L_N + 64, 256), 256, 0, stream>>>((uint32_t*)izone, (size_t)(2 * L_N + 64), 0u);
  count_deg_kernel<<<nb(E_N, 256), 256, 0, stream>>>(lit_idx, deg_i);
  hist32_kernel<<<nb(V_N, 256), 256, 0, stream>>>(var_gid, V_N, cntv);
  hist32_kernel<<<nb(C_N, 256), 256, 0, stream>>>(clause_gid, C_N, cntc);
  weights_kernel<<<nb(L_N, 256), 256, 0, stream>>>(deg_i, deg_f, vdw);
  scan_kernel<<<1, 256, 0, stream>>>(deg_i, offs);
  csr_fill_kernel<<<nb(E_N, 256), 256, 0, stream>>>(lit_idx, offs, cursor, csr);
  fill_b16<<<2048, 256, 0, stream>>>(variables, (size_t)V_N * 64, 1.0f);
  fill_b16<<<2048, 256, 0, stream>>>(clauses, (size_t)C_N * 64, 1.0f);
  fill_b16<<<2048, 256, 0, stream>>>(Zb, (size_t)V_N * 32, 0.0f);   // zero pad cols once
  // pack weights into MFMA B-fragment order
  pack_w_kernel<<<nb(96 * 64, 256), 256, 0, stream>>>(vq_W0, wflag, 68, 96, 64, 64, 0, BIG, 1.f, vq_W0p);
  pack_w_kernel<<<nb(64 * 64, 256), 256, 0, stream>>>(vq_W1, wflag, 64, 64, 64, 64, 0, BIG, 1.f, vq_W1p);
  pack_w_kernel<<<nb(128 * 128, 256), 256, 0, stream>>>(cm_W0, wflag, 128, 128, 128, 128, 0, 64, 4.f, cm_W0p);
  pack_w_kernel<<<nb(128 * 128, 256), 256, 0, stream>>>(cm_W1, wflag, 128, 128, 128, 128, 0, BIG, 1.f, cm_W1p);
  pack_w_kernel<<<nb(256 * 128, 256), 256, 0, stream>>>(ug_W0, wflag, 256, 256, 128, 128, 0, BIG, 1.f, ug_W0p);
  pack_w_kernel<<<nb(128 * 128, 256), 256, 0, stream>>>(ug_W1, wflag, 128, 128, 128, 128, 0, BIG, 1.f, ug_W1p);
  pack_w_kernel<<<nb(128 * 64, 256), 256, 0, stream>>>(ug_W2, wflag, 128, 128, 64, 64, 0, BIG, 1.f, ug_W2p);

  // ---- rounds ----
  for (int r = 0; r < NROUNDS; r++) {
    noise4_kernel<<<nb(V_N * 4, 256), 256, 0, stream>>>(Zb, kw0[r], kw1[r]);
    // vq MLP (K = 64 + 32-pad); Hv lives in ZD (Dl dead here)
    gemm_mfma<4, bf16><<<nb(V_N, 64), 256, 0, stream>>>(
        variables, 64, 64, Zb, 32, 32, (const bf16*)nullptr, 0, 0,
        vq_W0p, vq_b0, 0, wflag, 1, Hv, 64, V_N);
    gemm_mfma<4, bf16><<<nb(V_N, 64), 256, 0, stream>>>(
        Hv, 64, 64, (const bf16*)nullptr, 0, 0, (const bf16*)nullptr, 0, 0,
        vq_W1p, vq_b1, 0, wflag, 0, Q, 64, V_N);
    cl_kernel<<<nb(C_N, 4), wb, 0, stream>>>(Q, lit_idx, clb);
    qgrad_kernel<<<nb(V_N, 4), wb, 0, stream>>>(Q, clb, csr, offs, vdw, QG);
    // cm MLP chunk-REVERSE (Dn overlays clb; Dl separate buffer in ZD)
    for (int c = CM_NCHUNK - 1; c >= 0; c--) {
      int r0 = c * CM_CHUNK;
      int rows = min(CM_CHUNK, C_N - r0);
      gemm_mfma<8, bf16><<<nb(rows, 64), 256, 0, stream>>>(
          clauses + (size_t)r0 * 64, 64, 64, clb + (size_t)r0 * 64, 64, 64,
          (const bf16*)nullptr, 0, 0, cm_W0p, cm_b0, 0, wflag, 1, Hc, 128, rows);
      gemm_mfma_dual<<<nb(rows, 64), 256, 0, stream>>>(
          Hc, 128, cm_W1p, cm_b1, wflag,
          Dl + (size_t)r0 * 64, Dn + (size_t)r0 * 64, rows);
    }
    // clause pairnorm + blend (one-pass stats)
    fill_f32<<<1, 256, 0, stream>>>(stats, 4096 + 64, 0.0f);
    pn_stats_kernel<bf16><<<512, wb, 0, stream>>>(Dn, clause_gid, C_N, S1, S2);
    pn_finish_kernel<<<NGR, 64, 0, stream>>>(S1, S2, cntc, varsum);
    pn_apply_kernel<bf16><<<nb(C_N, 4), wb, 0, stream>>>(Dn, clause_gid, C_N, cntc, S1,
                                                         varsum, clauses,
                                                         (r == NROUNDS - 1) ? 1.0f : 0.2f);
    // VLb by CSR gather of Dl (Dn dead -> VLb in ZE)
    vlb_gather_kernel<<<nb(L_N, 4), wb, 0, stream>>>(Dl, csr, offs, deg_f, VLb);
    // ug MLP (Dl dead -> Hu/Hu2 in ZD; Hu dead -> NV)
    gemm_mfma<8, bf16><<<nb(V_N, 64), 256, 0, stream>>>(
        QG, 64, 64, variables, 64, 64, VLb, 128, 128,
        ug_W0p, ug_b0, 0, wflag, 1, Hu, 128, V_N);
    gemm_mfma<8, bf16><<<nb(V_N, 64), 256, 0, stream>>>(
        Hu, 128, 128, (const bf16*)nullptr, 0, 0, (const bf16*)nullptr, 0, 0,
        ug_W1p, ug_b1, 0, wflag, 1, Hu2, 128, V_N);
    gemm_mfma<4, float><<<nb(V_N, 64), 256, 0, stream>>>(
        Hu2, 128, 128, (const bf16*)nullptr, 0, 0, (const bf16*)nullptr, 0, 0,
        ug_W2p, ug_b2, 0, wflag, 0, NV, 64, V_N);
    // variable pairnorm + blend
    fill_f32<<<1, 256, 0, stream>>>(stats, 4096 + 64, 0.0f);
    pn_stats_kernel<float><<<512, wb, 0, stream>>>(NV, var_gid, V_N, S1, S2);
    pn_finish_kernel<<<NGR, 64, 0, stream>>>(S1, S2, cntv, varsum);
    pn_apply_kernel<float><<<nb(V_N, 4), wb, 0, stream>>>(NV, var_gid, V_N, cntv, S1,
                                                          varsum, variables, 1.0f);
  }
  co_kernel<<<nb(C_N, 4), wb, 0, stream>>>(clauses, co_W0, co_b0, co_W1, co_b1, wflag, logits);
  final_kernel<<<nb(C_N, 256), 256, 0, stream>>>(logits, out, kw0[8], kw1[8]);
}

// Round 11
// 9825.886 us; speedup vs baseline: 2.3757x; 1.1079x over previous
//
#include <hip/hip_runtime.h>
#include <hip/hip_bf16.h>
#include <cstdint>
#include <cstddef>

// ---------------------------------------------------------------------------
// Problem constants
// ---------------------------------------------------------------------------
constexpr int V_N = 100000;   // variables
constexpr int C_N = 420000;   // clauses
constexpr int L_N = 2 * V_N;  // literals
constexpr int E_N = 3 * C_N;  // nnz edges
constexpr int NGR = 32;       // graphs
constexpr int NROUNDS = 8;

using bf16 = __hip_bfloat16;
typedef __attribute__((ext_vector_type(8))) short short8;   // 8 bf16 (4 VGPRs)
typedef __attribute__((ext_vector_type(4))) float float4v;  // 4 fp32 acc

__device__ inline float b2f(bf16 h) { return __bfloat162float(h); }
__device__ inline bf16 f2b(float f) { return __float2bfloat16(f); }

template<typename T> __device__ inline float loadT(const T* p);
template<> __device__ inline float loadT<float>(const float* p) { return *p; }
template<> __device__ inline float loadT<bf16>(const bf16* p) { return b2f(*p); }

// runtime-dtype weight load: isf32 ? f32 buffer : packed bf16 buffer
__device__ inline float wload(const void* W, size_t idx, int isf32) {
  return isf32 ? ((const float*)W)[idx] : b2f(((const bf16*)W)[idx]);
}

// ---------------------------------------------------------------------------
// Threefry-2x32 (JAX-compatible, partitionable) — host+device
// ---------------------------------------------------------------------------
__host__ __device__ inline void tf2x32(uint32_t k0, uint32_t k1,
                                       uint32_t x0, uint32_t x1,
                                       uint32_t* o0, uint32_t* o1) {
  uint32_t ks2 = k0 ^ k1 ^ 0x1BD11BDAu;
  x0 += k0; x1 += k1;
#define TFR(d) do { x0 += x1; x1 = (x1 << (d)) | (x1 >> (32 - (d))); x1 ^= x0; } while (0)
  TFR(13); TFR(15); TFR(26); TFR(6);
  x0 += k1;  x1 += ks2 + 1u;
  TFR(17); TFR(29); TFR(16); TFR(24);
  x0 += ks2; x1 += k0 + 2u;
  TFR(13); TFR(15); TFR(26); TFR(6);
  x0 += k0;  x1 += k1 + 3u;
  TFR(17); TFR(29); TFR(16); TFR(24);
  x0 += k1;  x1 += ks2 + 4u;
  TFR(13); TFR(15); TFR(26); TFR(6);
  x0 += ks2; x1 += k0 + 5u;
#undef TFR
  *o0 = x0; *o1 = x1;
}

__device__ inline uint32_t part_bits(uint32_t ka, uint32_t kb, uint32_t e) {
  uint32_t h1, h2;
  tf2x32(ka, kb, 0u, e, &h1, &h2);
  return h1 ^ h2;
}

// XLA ErfInv32 polynomial (Giles)
__device__ inline float erfinv_f32(float x) {
  float w = -log1pf(-x * x);
  float p;
  if (w < 5.0f) {
    w -= 2.5f;
    p = 2.81022636e-08f;
    p = fmaf(p, w, 3.43273939e-07f);
    p = fmaf(p, w, -3.5233877e-06f);
    p = fmaf(p, w, -4.39150654e-06f);
    p = fmaf(p, w, 0.00021858087f);
    p = fmaf(p, w, -0.00125372503f);
    p = fmaf(p, w, -0.00417768164f);
    p = fmaf(p, w, 0.246640727f);
    p = fmaf(p, w, 1.50140941f);
  } else {
    w = sqrtf(w) - 3.0f;
    p = -0.000200214257f;
    p = fmaf(p, w, 0.000100950558f);
    p = fmaf(p, w, 0.00134934322f);
    p = fmaf(p, w, -0.00367342844f);
    p = fmaf(p, w, 0.00573950773f);
    p = fmaf(p, w, -0.0076224613f);
    p = fmaf(p, w, 0.00943887047f);
    p = fmaf(p, w, 1.00167406f);
    p = fmaf(p, w, 2.83297682f);
  }
  return p * x;
}

__device__ inline float normal_from_bits(uint32_t bits) {
  float u01 = __uint_as_float((bits >> 9) | 0x3f800000u) - 1.0f;  // [0,1)
  const float lo = -0.99999994f;
  float u = u01 * 2.0f + lo;
  u = fmaxf(lo, u);
  return 1.41421356f * erfinv_f32(u);
}

__device__ inline float softplusf(float x) {
  return (x > 0.0f) ? x + log1pf(expf(-x)) : log1pf(expf(x));
}

// ---------------------------------------------------------------------------
// Utility kernels
// ---------------------------------------------------------------------------
__global__ void fill_f32(float* p, size_t n, float v) {
  size_t i = (size_t)blockIdx.x * blockDim.x + threadIdx.x;
  size_t stride = (size_t)gridDim.x * blockDim.x;
  for (; i < n; i += stride) p[i] = v;
}
__global__ void fill_u32(uint32_t* p, size_t n, uint32_t v) {
  size_t i = (size_t)blockIdx.x * blockDim.x + threadIdx.x;
  size_t stride = (size_t)gridDim.x * blockDim.x;
  for (; i < n; i += stride) p[i] = v;
}
__global__ void fill_b16(bf16* p, size_t n, float v) {
  size_t i = (size_t)blockIdx.x * blockDim.x + threadIdx.x;
  size_t stride = (size_t)gridDim.x * blockDim.x;
  bf16 b = f2b(v);
  for (; i < n; i += stride) p[i] = b;
}

// Detect weight dtype (R8-verified). flag=1 -> f32, flag=0 -> bf16.
__global__ void detect_dtype_kernel(const uint32_t* __restrict__ w, int* __restrict__ flag) {
  if (blockIdx.x == 0 && threadIdx.x == 0) {
    int votes = 0;
    for (int i = 0; i < 16; i++) {
      uint32_t lo = w[i] & 0xFFFFu;
      uint32_t e = (lo >> 7) & 0xFFu;
      if (e >= 0x70u && e < 0x80u) votes++;
    }
    *flag = (votes >= 12) ? 0 : 1;
  }
}

// Pack W into MFMA B-fragment order (bf16):
// out[((kt*MT+nt)*64+lane)*8+j] = W[kt*32+(lane>>4)*8+j][wcol0 + nt*16+(lane&15)]
// rows k >= srow0 scaled by sscale; rows k >= realK zeroed (K padding).
__global__ void pack_w_kernel(const void* __restrict__ W, const int* __restrict__ flagp,
                              int realK, int Kpad, int M, int Wld, int wcol0,
                              int srow0, float sscale, bf16* __restrict__ out) {
  int idx = blockIdx.x * 256 + threadIdx.x;
  if (idx >= Kpad * M) return;
  int j = idx & 7;
  int lane = (idx >> 3) & 63;
  int t = idx >> 9;
  int MT = M / 16;
  int kt = t / MT, nt = t - kt * MT;
  int k = kt * 32 + (lane >> 4) * 8 + j;
  int n = nt * 16 + (lane & 15);
  float v = 0.0f;
  if (k < realK) {
    v = wload(W, (size_t)k * Wld + wcol0 + n, *flagp);
    if (k >= srow0) v *= sscale;
  }
  out[idx] = f2b(v);
}

__global__ void count_deg_kernel(const int* __restrict__ lit, int* __restrict__ deg) {
  int e = blockIdx.x * 256 + threadIdx.x;
  if (e < E_N) atomicAdd(&deg[lit[e]], 1);
}

__global__ void hist32_kernel(const int* __restrict__ gid, int n, int* __restrict__ out) {
  __shared__ int bins[NGR];
  int t = threadIdx.x;
  if (t < NGR) bins[t] = 0;
  __syncthreads();
  int i = blockIdx.x * 256 + t;
  if (i < n) atomicAdd(&bins[gid[i]], 1);
  __syncthreads();
  if (t < NGR && bins[t] > 0) atomicAdd(&out[t], bins[t]);
}

__global__ void weights_kernel(const int* __restrict__ deg,
                               float* __restrict__ dw, float* __restrict__ vdw) {
  int l = blockIdx.x * 256 + threadIdx.x;
  if (l < L_N) dw[l] = rsqrtf(fmaxf((float)deg[l], 1.0f));
  if (l < V_N) vdw[l] = 4.0f * rsqrtf(fmaxf((float)(deg[l] + deg[l + V_N]), 1.0f));
}

// single-block exclusive scan of L_N degrees -> offs[L_N+1]
__global__ void scan_kernel(const int* __restrict__ deg, int* __restrict__ offs) {
  __shared__ int part[256];
  __shared__ int base[257];
  int t = threadIdx.x;
  const int CH = (L_N + 255) / 256;
  int i0 = t * CH, i1 = min(L_N, i0 + CH);
  int s = 0;
  for (int i = i0; i < i1; i++) s += deg[i];
  part[t] = s;
  __syncthreads();
  if (t == 0) {
    int acc = 0;
    for (int j = 0; j < 256; j++) { base[j] = acc; acc += part[j]; }
    base[256] = acc;
  }
  __syncthreads();
  int acc = base[t];
  for (int i = i0; i < i1; i++) { offs[i] = acc; acc += deg[i]; }
  if (t == 255) offs[L_N] = base[256];
}

__global__ void csr_fill_kernel(const int* __restrict__ lit,
                                const int* __restrict__ offs, int* __restrict__ cursor,
                                int* __restrict__ csr) {
  int e = blockIdx.x * 256 + threadIdx.x;
  if (e < E_N) {
    int l = lit[e];
    int p = atomicAdd(&cursor[l], 1);
    csr[offs[l] + p] = e / 3;   // clause index (clause_idx = repeat(arange(C),3))
  }
}

// per-round: write only the 4 real noise columns (pad zeroed once at setup)
__global__ void noise4_kernel(bf16* __restrict__ Zb, uint32_t ka, uint32_t kb) {
  int idx = blockIdx.x * 256 + threadIdx.x;
  if (idx >= V_N * 4) return;
  int v = idx >> 2, j = idx & 3;
  Zb[(size_t)v * 32 + j] = f2b(normal_from_bits(part_bits(ka, kb, (uint32_t)idx)));
}

// ---------------------------------------------------------------------------
// Fused MLP kernels. 256 thr = 4 waves; wave w owns rows [blk*64+16w, +16).
// Hidden tiles staged in LDS (C-layout write -> A-layout read, wave-private
// rows; +8-col pad gives 4-bank row shift -> 2-way conflicts only).
// ---------------------------------------------------------------------------

// vq: Q = (relu([variables|Z] @ W0 + b0)) @ W1 + b1   (K=96 padded, M=64)
__global__ __launch_bounds__(256) void vq_fused_kernel(
    const bf16* __restrict__ variables, const bf16* __restrict__ Zb,
    const bf16* __restrict__ W0p, const void* __restrict__ b0,
    const bf16* __restrict__ W1p, const void* __restrict__ b1,
    const int* __restrict__ flagp, bf16* __restrict__ Q, int N) {
  __shared__ bf16 hs[64][72];
  int tid = threadIdx.x;
  int wave = tid >> 6, lane = tid & 63, quad = lane >> 4, m16 = lane & 15;
  int row = blockIdx.x * 64 + wave * 16 + m16;
  int rowc = min(row, N - 1);
  int isf32 = *flagp;
  float4v acc[4];
#pragma unroll
  for (int nt = 0; nt < 4; nt++) acc[nt] = (float4v){0.f, 0.f, 0.f, 0.f};
  const short8* w0 = (const short8*)W0p;
  for (int k0 = 0; k0 < 96; k0 += 32) {
    int ks = k0 + quad * 8;
    const bf16* src = (ks < 64) ? variables + (size_t)rowc * 64 + ks
                                : Zb + (size_t)rowc * 32 + (ks - 64);
    short8 a = *(const short8*)src;
#pragma unroll
    for (int nt = 0; nt < 4; nt++) {
      short8 b = w0[((k0 >> 5) * 4 + nt) * 64 + lane];
      acc[nt] = __builtin_amdgcn_mfma_f32_16x16x32_bf16(a, b, acc[nt], 0, 0, 0);
    }
  }
  int rl = wave * 16 + quad * 4;
#pragma unroll
  for (int nt = 0; nt < 4; nt++) {
    int col = nt * 16 + m16;
    float bv = wload(b0, col, isf32);
#pragma unroll
    for (int i = 0; i < 4; i++)
      hs[rl + i][col] = f2b(fmaxf(acc[nt][i] + bv, 0.0f));
  }
  __syncthreads();
  float4v acc2[4];
#pragma unroll
  for (int nt = 0; nt < 4; nt++) acc2[nt] = (float4v){0.f, 0.f, 0.f, 0.f};
  const short8* w1 = (const short8*)W1p;
  for (int k0 = 0; k0 < 64; k0 += 32) {
    short8 a = *(const short8*)&hs[wave * 16 + m16][k0 + quad * 8];
#pragma unroll
    for (int nt = 0; nt < 4; nt++) {
      short8 b = w1[((k0 >> 5) * 4 + nt) * 64 + lane];
      acc2[nt] = __builtin_amdgcn_mfma_f32_16x16x32_bf16(a, b, acc2[nt], 0, 0, 0);
    }
  }
  int rbase = blockIdx.x * 64 + wave * 16 + quad * 4;
#pragma unroll
  for (int nt = 0; nt < 4; nt++) {
    int col = nt * 16 + m16;
    float bv = wload(b1, col, isf32);
#pragma unroll
    for (int i = 0; i < 4; i++) {
      int r = rbase + i;
      if (r < N) Q[(size_t)r * 64 + col] = f2b(acc2[nt][i] + bv);
    }
  }
}

// cm: H = relu([clauses|clb] @ W0 + b0); D = H @ W1 + b1; Dl=D[:, :64],
// Dn=D[:, 64:]. Dn overlays clb in-place: each block reads only its own rows'
// clb (all before barrier) and writes Dn after -> safe, NO chunking.
__global__ __launch_bounds__(256) void cm_fused_kernel(
    const bf16* __restrict__ clauses, const bf16* __restrict__ clb,
    const bf16* __restrict__ W0p, const void* __restrict__ b0,
    const bf16* __restrict__ W1p, const void* __restrict__ b1,
    const int* __restrict__ flagp,
    bf16* __restrict__ Dl, bf16* __restrict__ Dn, int N) {
  __shared__ bf16 hs[64][136];
  int tid = threadIdx.x;
  int wave = tid >> 6, lane = tid & 63, quad = lane >> 4, m16 = lane & 15;
  int row = blockIdx.x * 64 + wave * 16 + m16;
  int rowc = min(row, N - 1);
  int isf32 = *flagp;
  float4v acc[8];
#pragma unroll
  for (int nt = 0; nt < 8; nt++) acc[nt] = (float4v){0.f, 0.f, 0.f, 0.f};
  const short8* w0 = (const short8*)W0p;
  for (int k0 = 0; k0 < 128; k0 += 32) {
    int ks = k0 + quad * 8;
    const bf16* src = (ks < 64) ? clauses + (size_t)rowc * 64 + ks
                                : clb + (size_t)rowc * 64 + (ks - 64);
    short8 a = *(const short8*)src;
#pragma unroll
    for (int nt = 0; nt < 8; nt++) {
      short8 b = w0[((k0 >> 5) * 8 + nt) * 64 + lane];
      acc[nt] = __builtin_amdgcn_mfma_f32_16x16x32_bf16(a, b, acc[nt], 0, 0, 0);
    }
  }
  int rl = wave * 16 + quad * 4;
#pragma unroll
  for (int nt = 0; nt < 8; nt++) {
    int col = nt * 16 + m16;
    float bv = wload(b0, col, isf32);
#pragma unroll
    for (int i = 0; i < 4; i++)
      hs[rl + i][col] = f2b(fmaxf(acc[nt][i] + bv, 0.0f));
  }
  __syncthreads();
#pragma unroll
  for (int nt = 0; nt < 8; nt++) acc[nt] = (float4v){0.f, 0.f, 0.f, 0.f};
  const short8* w1 = (const short8*)W1p;
  for (int k0 = 0; k0 < 128; k0 += 32) {
    short8 a = *(const short8*)&hs[wave * 16 + m16][k0 + quad * 8];
#pragma unroll
    for (int nt = 0; nt < 8; nt++) {
      short8 b = w1[((k0 >> 5) * 8 + nt) * 64 + lane];
      acc[nt] = __builtin_amdgcn_mfma_f32_16x16x32_bf16(a, b, acc[nt], 0, 0, 0);
    }
  }
  int rbase = blockIdx.x * 64 + wave * 16 + quad * 4;
#pragma unroll
  for (int nt = 0; nt < 8; nt++) {
    int col = nt * 16 + m16;
    float bv = wload(b1, col, isf32);
#pragma unroll
    for (int i = 0; i < 4; i++) {
      int r = rbase + i;
      if (r < N) {
        float v = acc[nt][i] + bv;
        if (col < 64) Dl[(size_t)r * 64 + col] = f2b(v);
        else          Dn[(size_t)r * 64 + (col - 64)] = f2b(v);
      }
    }
  }
}

// ug: 3-layer MLP [QG|variables|VLb](K=256) ->128 ->128 ->64, NV f32 out.
__global__ __launch_bounds__(256) void ug_fused_kernel(
    const bf16* __restrict__ QG, const bf16* __restrict__ variables,
    const bf16* __restrict__ VLb,
    const bf16* __restrict__ W0p, const void* __restrict__ b0,
    const bf16* __restrict__ W1p, const void* __restrict__ b1,
    const bf16* __restrict__ W2p, const void* __restrict__ b2,
    const int* __restrict__ flagp, float* __restrict__ NV, int N) {
  __shared__ bf16 h1[64][136];
  __shared__ bf16 h2[64][136];
  int tid = threadIdx.x;
  int wave = tid >> 6, lane = tid & 63, quad = lane >> 4, m16 = lane & 15;
  int row = blockIdx.x * 64 + wave * 16 + m16;
  int rowc = min(row, N - 1);
  int isf32 = *flagp;
  int rl = wave * 16 + quad * 4;
  float4v acc[8];
#pragma unroll
  for (int nt = 0; nt < 8; nt++) acc[nt] = (float4v){0.f, 0.f, 0.f, 0.f};
  const short8* w0 = (const short8*)W0p;
  for (int k0 = 0; k0 < 256; k0 += 32) {
    int ks = k0 + quad * 8;
    const bf16* src;
    if (ks < 64)       src = QG + (size_t)rowc * 64 + ks;
    else if (ks < 128) src = variables + (size_t)rowc * 64 + (ks - 64);
    else               src = VLb + (size_t)rowc * 128 + (ks - 128);
    short8 a = *(const short8*)src;
#pragma unroll
    for (int nt = 0; nt < 8; nt++) {
      short8 b = w0[((k0 >> 5) * 8 + nt) * 64 + lane];
      acc[nt] = __builtin_amdgcn_mfma_f32_16x16x32_bf16(a, b, acc[nt], 0, 0, 0);
    }
  }
#pragma unroll
  for (int nt = 0; nt < 8; nt++) {
    int col = nt * 16 + m16;
    float bv = wload(b0, col, isf32);
#pragma unroll
    for (int i = 0; i < 4; i++)
      h1[rl + i][col] = f2b(fmaxf(acc[nt][i] + bv, 0.0f));
  }
  __syncthreads();
#pragma unroll
  for (int nt = 0; nt < 8; nt++) acc[nt] = (float4v){0.f, 0.f, 0.f, 0.f};
  const short8* w1 = (const short8*)W1p;
  for (int k0 = 0; k0 < 128; k0 += 32) {
    short8 a = *(const short8*)&h1[wave * 16 + m16][k0 + quad * 8];
#pragma unroll
    for (int nt = 0; nt < 8; nt++) {
      short8 b = w1[((k0 >> 5) * 8 + nt) * 64 + lane];
      acc[nt] = __builtin_amdgcn_mfma_f32_16x16x32_bf16(a, b, acc[nt], 0, 0, 0);
    }
  }
#pragma unroll
  for (int nt = 0; nt < 8; nt++) {
    int col = nt * 16 + m16;
    float bv = wload(b1, col, isf32);
#pragma unroll
    for (int i = 0; i < 4; i++)
      h2[rl + i][col] = f2b(fmaxf(acc[nt][i] + bv, 0.0f));
  }
  __syncthreads();
  float4v acc3[4];
#pragma unroll
  for (int nt = 0; nt < 4; nt++) acc3[nt] = (float4v){0.f, 0.f, 0.f, 0.f};
  const short8* w2 = (const short8*)W2p;
  for (int k0 = 0; k0 < 128; k0 += 32) {
    short8 a = *(const short8*)&h2[wave * 16 + m16][k0 + quad * 8];
#pragma unroll
    for (int nt = 0; nt < 4; nt++) {
      short8 b = w2[((k0 >> 5) * 4 + nt) * 64 + lane];
      acc3[nt] = __builtin_amdgcn_mfma_f32_16x16x32_bf16(a, b, acc3[nt], 0, 0, 0);
    }
  }
  int rbase = blockIdx.x * 64 + wave * 16 + quad * 4;
#pragma unroll
  for (int nt = 0; nt < 4; nt++) {
    int col = nt * 16 + m16;
    float bv = wload(b2, col, isf32);
#pragma unroll
    for (int i = 0; i < 4; i++) {
      int r = rbase + i;
      if (r < N) NV[(size_t)r * 64 + col] = acc3[nt][i] + bv;
    }
  }
}

// ---------------------------------------------------------------------------
// Edge / node kernels (wave = 64 lanes = feature dim)
// ---------------------------------------------------------------------------
// cl + stats-zero (block 0 zeros S1/S2 for the upcoming clause pairnorm)
__global__ void cl_kernel(const bf16* __restrict__ Q, const int* __restrict__ lit,
                          bf16* __restrict__ cl, float* __restrict__ stats) {
  if (blockIdx.x == 0) {
    int t = threadIdx.y * 64 + threadIdx.x;
    for (int i = t; i < 4096; i += 256) stats[i] = 0.0f;
  }
  int c = blockIdx.x * 4 + threadIdx.y;
  if (c >= C_N) return;
  int k = threadIdx.x;
  float cv = 0.0f;
#pragma unroll
  for (int j = 0; j < 3; j++) {
    int l = lit[3 * c + j];
    float q = (l < V_N) ? b2f(Q[(size_t)l * 64 + k]) : -b2f(Q[(size_t)(l - V_N) * 64 + k]);
    cv += softplusf(q);
  }
  cl[(size_t)c * 64 + k] = f2b(expf(-cv));
}

// fused: G gathers (CSR) + q-grad; QG = (-sig(q)*Gpos + sig(-q)*Gneg) * vdw
__global__ void qgrad_kernel(const bf16* __restrict__ Q, const bf16* __restrict__ clb,
                             const int* __restrict__ csr, const int* __restrict__ offs,
                             const float* __restrict__ vdw, bf16* __restrict__ QG) {
  int v = blockIdx.x * 4 + threadIdx.y;
  if (v >= V_N) return;
  int k = threadIdx.x;
  float gp = 0.0f, gn = 0.0f;
  int p0 = offs[v], p1 = offs[v + 1];
  for (int p = p0; p < p1; p++) gp += b2f(clb[(size_t)csr[p] * 64 + k]);
  p0 = offs[v + V_N]; p1 = offs[v + V_N + 1];
  for (int p = p0; p < p1; p++) gn += b2f(clb[(size_t)csr[p] * 64 + k]);
  float q = b2f(Q[(size_t)v * 64 + k]);
  float sp = 1.0f / (1.0f + expf(-q));
  float sn = 1.0f / (1.0f + expf(q));
  QG[(size_t)v * 64 + k] = f2b((-sp * gp + sn * gn) * vdw[v]);
}

// VLb via CSR gather of Dl; block 0 zeros S1/S2 for the variable pairnorm.
__global__ void vlb_gather_kernel(const bf16* __restrict__ Dl, const int* __restrict__ csr,
                                  const int* __restrict__ offs, const float* __restrict__ dw,
                                  bf16* __restrict__ VLb, float* __restrict__ stats) {
  if (blockIdx.x == 0) {
    int t = threadIdx.y * 64 + threadIdx.x;
    for (int i = t; i < 4096; i += 256) stats[i] = 0.0f;
  }
  int l = blockIdx.x * 4 + threadIdx.y;
  if (l >= L_N) return;
  int k = threadIdx.x;
  float s = 0.0f;
  int p0 = offs[l], p1 = offs[l + 1];
  for (int p = p0; p < p1; p++) s += b2f(Dl[(size_t)csr[p] * 64 + k]);
  s *= dw[l];
  size_t v = (l < V_N) ? (size_t)l : (size_t)(l - V_N);
  int col = (l < V_N) ? 0 : 64;
  VLb[v * 128 + col + k] = f2b(s);
}

// ---------------------------------------------------------------------------
// PairNorm — one stats pass (S1,S2); apply recomputes mean/var inline.
// ---------------------------------------------------------------------------
template<typename TX>
__global__ void pn_stats_kernel(const TX* __restrict__ X,
                                const int* __restrict__ gid, int n,
                                float* __restrict__ S1, float* __restrict__ S2) {
  int wave = blockIdx.x * blockDim.y + threadIdx.y;
  int nw = gridDim.x * blockDim.y;
  int chunk = (n + nw - 1) / nw;
  int i0 = wave * chunk;
  if (i0 >= n) return;
  int i1 = min(n, i0 + chunk);
  int k = threadIdx.x;
  int g = gid[i0];
  float a1 = 0.0f, a2 = 0.0f;
  for (int i = i0; i < i1; i++) {
    int gi = gid[i];
    if (gi != g) {
      atomicAdd(&S1[g * 64 + k], a1);
      atomicAdd(&S2[g * 64 + k], a2);
      a1 = 0.0f; a2 = 0.0f; g = gi;
    }
    float x = loadT(&X[(size_t)i * 64 + k]);
    a1 += x;
    a2 += x * x;
  }
  atomicAdd(&S1[g * 64 + k], a1);
  atomicAdd(&S2[g * 64 + k], a2);
}

// state = (pairnorm(X)*0.25 + 0.1*state) * post ; var computed inline
template<typename TX>
__global__ void pn_apply_kernel(const TX* __restrict__ X,
                                const int* __restrict__ gid, int n,
                                const int* __restrict__ cnt, const float* __restrict__ S1,
                                const float* __restrict__ S2, bf16* __restrict__ state,
                                float post) {
  int i = blockIdx.x * 4 + threadIdx.y;
  if (i >= n) return;
  int k = threadIdx.x;
  int g = gid[i];
  float c = fmaxf((float)cnt[g], 1.0f);
  float mean = S1[g * 64 + k] / c;
  float t = S2[g * 64 + k] / c - mean * mean;
#pragma unroll
  for (int o = 32; o > 0; o >>= 1) t += __shfl_down(t, o);
  float var = fmaxf(__shfl(t, 0), 0.0f) * (1.0f / 64.0f);
  float xn = (loadT(&X[(size_t)i * 64 + k]) - mean) * rsqrtf(var + 1e-6f);
  size_t o = (size_t)i * 64 + k;
  state[o] = f2b((xn * 0.25f + 0.1f * b2f(state[o])) * post);
}

// fused co MLP + noise + sigmoid: out[c] = sigmoid(relu(x@W0+b0)@W1 + b1 + N_c)
__global__ __launch_bounds__(256) void co_final_kernel(
    const bf16* __restrict__ clauses, const void* __restrict__ W0,
    const void* __restrict__ b0, const void* __restrict__ W1,
    const void* __restrict__ b1, const int* __restrict__ flagp,
    uint32_t ka, uint32_t kb, float* __restrict__ out) {
  __shared__ float w0s[64 * 64];
  int isf32 = *flagp;
  int tid = threadIdx.y * 64 + threadIdx.x;
  for (int i = tid; i < 64 * 64; i += 256) w0s[i] = wload(W0, i, isf32);
  __syncthreads();
  int c = blockIdx.x * 4 + threadIdx.y;
  if (c >= C_N) return;
  int k = threadIdx.x;
  float x = b2f(clauses[(size_t)c * 64 + k]);
  float h = wload(b0, k, isf32);
#pragma unroll 8
  for (int j = 0; j < 64; j++) h = fmaf(__shfl(x, j), w0s[j * 64 + k], h);
  h = fmaxf(h, 0.0f);
  float v = h * wload(W1, k, isf32);
#pragma unroll
  for (int o = 32; o > 0; o >>= 1) v += __shfl_down(v, o);
  if (k == 0) {
    float lg = v + wload(b1, 0, isf32) + normal_from_bits(part_bits(ka, kb, (uint32_t)c));
    out[c] = 1.0f / (1.0f + expf(-lg));
  }
}

// ---------------------------------------------------------------------------
// Launch
// ---------------------------------------------------------------------------
extern "C" void kernel_launch(void* const* d_in, const int* in_sizes, int n_in,
                              void* d_out, int out_size, void* d_ws, size_t ws_size,
                              hipStream_t stream) {
  (void)in_sizes; (void)n_in; (void)out_size;
  const int* lit_idx    = (const int*)d_in[0];
  const int* var_gid    = (const int*)d_in[2];
  const int* clause_gid = (const int*)d_in[3];
  const void* vq_W0 = d_in[4];
  const void* vq_b0 = d_in[5];
  const void* vq_W1 = d_in[6];
  const void* vq_b1 = d_in[7];
  const void* cm_W0 = d_in[8];
  const void* cm_b0 = d_in[9];
  const void* cm_W1 = d_in[10];
  const void* cm_b1 = d_in[11];
  const void* ug_W0 = d_in[12];
  const void* ug_b0 = d_in[13];
  const void* ug_W1 = d_in[14];
  const void* ug_b1 = d_in[15];
  const void* ug_W2 = d_in[16];
  const void* ug_b2 = d_in[17];
  const void* co_W0 = d_in[18];
  const void* co_b0 = d_in[19];
  const void* co_W1 = d_in[20];
  const void* co_b1 = d_in[21];
  float* out = (float*)d_out;

  // ---- workspace layout (~216 MB peak) ----
  char* ws = (char*)d_ws;
  size_t off = 0;
  auto alloc = [&](size_t bytes) -> void* {
    void* p = ws + off;
    off = (off + bytes + 255) & ~(size_t)255;
    return p;
  };
  bf16* variables = (bf16*)alloc((size_t)V_N * 64 * 2);   // persistent state
  bf16* clauses   = (bf16*)alloc((size_t)C_N * 64 * 2);   // persistent state
  // ZE (C*64*2): clb -> Dn (in-place overlay in cm_fused) -> VLb (V*128)
  char* ZE        = (char*)alloc((size_t)C_N * 64 * 2);
  // ZD (C*64*2): Dl (C*64) -> NV f32 (V*64)
  char* ZD        = (char*)alloc((size_t)C_N * 64 * 2);
  bf16* QG        = (bf16*)alloc((size_t)V_N * 64 * 2);
  bf16* Q         = (bf16*)alloc((size_t)V_N * 64 * 2);
  bf16* Zb        = (bf16*)alloc((size_t)V_N * 32 * 2);
  int*  izone     = (int*)alloc((size_t)(2 * L_N + 64) * 4);
  int*  offs      = (int*)alloc((size_t)(L_N + 1) * 4);
  int*  csr       = (int*)alloc((size_t)E_N * 4);
  float* deg_f    = (float*)alloc((size_t)L_N * 4);
  float* vdw      = (float*)alloc((size_t)V_N * 4);
  float* stats    = (float*)alloc((size_t)4096 * 4);
  int*   wflag    = (int*)alloc(256);
  // packed MFMA weights (bf16)
  bf16* vq_W0p = (bf16*)alloc((size_t)96 * 64 * 2);
  bf16* vq_W1p = (bf16*)alloc((size_t)64 * 64 * 2);
  bf16* cm_W0p = (bf16*)alloc((size_t)128 * 128 * 2);
  bf16* cm_W1p = (bf16*)alloc((size_t)128 * 128 * 2);
  bf16* ug_W0p = (bf16*)alloc((size_t)256 * 128 * 2);
  bf16* ug_W1p = (bf16*)alloc((size_t)128 * 128 * 2);
  bf16* ug_W2p = (bf16*)alloc((size_t)128 * 64 * 2);
  size_t need = off;

  auto nb = [](int n, int per) { return (n + per - 1) / per; };

  if (ws_size < need) {
    fill_f32<<<nb(C_N, 256), 256, 0, stream>>>(out, (size_t)C_N, 0.5f);
    return;
  }

  bf16* clb = (bf16*)ZE;                 // C x 64
  bf16* Dn  = (bf16*)ZE;                 // C x 64 (in-place overlay)
  bf16* VLb = (bf16*)ZE;                 // V x 128 (after Dn consumed)
  bf16* Dl  = (bf16*)ZD;                 // C x 64
  float* NV = (float*)ZD;                // V x 64 f32 (after Dl consumed)

  int* deg_i  = izone;
  int* cursor = izone + L_N;
  int* cntv   = izone + 2 * L_N;
  int* cntc   = cntv + 32;
  float* S1 = stats;              // 32 x 64
  float* S2 = stats + 2048;       // 32 x 64

  // JAX keys = split(key(42), 9), partitionable: subkey_i = threefry(key,0,i)
  uint32_t kw0[9], kw1[9];
  for (int i = 0; i < 9; i++) tf2x32(0u, 42u, 0u, (uint32_t)i, &kw0[i], &kw1[i]);

  dim3 wb(64, 4);
  const int BIG = 1 << 30;

  // ---- setup (re-done every call) ----
  detect_dtype_kernel<<<1, 64, 0, stream>>>((const uint32_t*)vq_W0, wflag);
  fill_u32<<<nb(2 * L_N + 64, 256), 256, 0, stream>>>((uint32_t*)izone, (size_t)(2 * L_N + 64), 0u);
  count_deg_kernel<<<nb(E_N, 256), 256, 0, stream>>>(lit_idx, deg_i);
  hist32_kernel<<<nb(V_N, 256), 256, 0, stream>>>(var_gid, V_N, cntv);
  hist32_kernel<<<nb(C_N, 256), 256, 0, stream>>>(clause_gid, C_N, cntc);
  weights_kernel<<<nb(L_N, 256), 256, 0, stream>>>(deg_i, deg_f, vdw);
  scan_kernel<<<1, 256, 0, stream>>>(deg_i, offs);
  csr_fill_kernel<<<nb(E_N, 256), 256, 0, stream>>>(lit_idx, offs, cursor, csr);
  fill_b16<<<2048, 256, 0, stream>>>(variables, (size_t)V_N * 64, 1.0f);
  fill_b16<<<2048, 256, 0, stream>>>(clauses, (size_t)C_N * 64, 1.0f);
  fill_b16<<<2048, 256, 0, stream>>>(Zb, (size_t)V_N * 32, 0.0f);   // zero pad cols once
  // pack weights into MFMA B-fragment order
  pack_w_kernel<<<nb(96 * 64, 256), 256, 0, stream>>>(vq_W0, wflag, 68, 96, 64, 64, 0, BIG, 1.f, vq_W0p);
  pack_w_kernel<<<nb(64 * 64, 256), 256, 0, stream>>>(vq_W1, wflag, 64, 64, 64, 64, 0, BIG, 1.f, vq_W1p);
  pack_w_kernel<<<nb(128 * 128, 256), 256, 0, stream>>>(cm_W0, wflag, 128, 128, 128, 128, 0, 64, 4.f, cm_W0p);
  pack_w_kernel<<<nb(128 * 128, 256), 256, 0, stream>>>(cm_W1, wflag, 128, 128, 128, 128, 0, BIG, 1.f, cm_W1p);
  pack_w_kernel<<<nb(256 * 128, 256), 256, 0, stream>>>(ug_W0, wflag, 256, 256, 128, 128, 0, BIG, 1.f, ug_W0p);
  pack_w_kernel<<<nb(128 * 128, 256), 256, 0, stream>>>(ug_W1, wflag, 128, 128, 128, 128, 0, BIG, 1.f, ug_W1p);
  pack_w_kernel<<<nb(128 * 64, 256), 256, 0, stream>>>(ug_W2, wflag, 128, 128, 64, 64, 0, BIG, 1.f, ug_W2p);

  // ---- rounds (11 launches each) ----
  for (int r = 0; r < NROUNDS; r++) {
    noise4_kernel<<<nb(V_N * 4, 256), 256, 0, stream>>>(Zb, kw0[r], kw1[r]);
    vq_fused_kernel<<<nb(V_N, 64), 256, 0, stream>>>(
        variables, Zb, vq_W0p, vq_b0, vq_W1p, vq_b1, wflag, Q, V_N);
    cl_kernel<<<nb(C_N, 4), wb, 0, stream>>>(Q, lit_idx, clb, stats);
    qgrad_kernel<<<nb(V_N, 4), wb, 0, stream>>>(Q, clb, csr, offs, vdw, QG);
    cm_fused_kernel<<<nb(C_N, 64), 256, 0, stream>>>(
        clauses, clb, cm_W0p, cm_b0, cm_W1p, cm_b1, wflag, Dl, Dn, C_N);
    pn_stats_kernel<bf16><<<512, wb, 0, stream>>>(Dn, clause_gid, C_N, S1, S2);
    pn_apply_kernel<bf16><<<nb(C_N, 4), wb, 0, stream>>>(
        Dn, clause_gid, C_N, cntc, S1, S2, clauses, (r == NROUNDS - 1) ? 1.0f : 0.2f);
    vlb_gather_kernel<<<nb(L_N, 4), wb, 0, stream>>>(Dl, csr, offs, deg_f, VLb, stats);
    ug_fused_kernel<<<nb(V_N, 64), 256, 0, stream>>>(
        QG, variables, VLb, ug_W0p, ug_b0, ug_W1p, ug_b1, ug_W2p, ug_b2,
        wflag, NV, V_N);
    pn_stats_kernel<float><<<512, wb, 0, stream>>>(NV, var_gid, V_N, S1, S2);
    pn_apply_kernel<float><<<nb(V_N, 4), wb, 0, stream>>>(
        NV, var_gid, V_N, cntv, S1, S2, variables, 1.0f);
  }
  co_final_kernel<<<nb(C_N, 4), wb, 0, stream>>>(
      clauses, co_W0, co_b0, co_W1, co_b1, wflag, kw0[8], kw1[8], out);
}

// Round 12
// 7207.732 us; speedup vs baseline: 3.2387x; 1.3632x over previous
//
#include <hip/hip_runtime.h>
#include <hip/hip_bf16.h>
#include <cstdint>
#include <cstddef>

// ---------------------------------------------------------------------------
// Problem constants
// ---------------------------------------------------------------------------
constexpr int V_N = 100000;   // variables
constexpr int C_N = 420000;   // clauses
constexpr int L_N = 2 * V_N;  // literals
constexpr int E_N = 3 * C_N;  // nnz edges
constexpr int NGR = 32;       // graphs
constexpr int NROUNDS = 8;

using bf16 = __hip_bfloat16;
typedef __attribute__((ext_vector_type(8))) short short8;   // 8 bf16 (4 VGPRs)
typedef __attribute__((ext_vector_type(4))) float float4v;  // 4 fp32 acc

__device__ inline float b2f(bf16 h) { return __bfloat162float(h); }
__device__ inline bf16 f2b(float f) { return __float2bfloat16(f); }

template<typename T> __device__ inline float loadT(const T* p);
template<> __device__ inline float loadT<float>(const float* p) { return *p; }
template<> __device__ inline float loadT<bf16>(const bf16* p) { return b2f(*p); }

// runtime-dtype weight load: isf32 ? f32 buffer : packed bf16 buffer
__device__ inline float wload(const void* W, size_t idx, int isf32) {
  return isf32 ? ((const float*)W)[idx] : b2f(((const bf16*)W)[idx]);
}

// ---------------------------------------------------------------------------
// Threefry-2x32 (JAX-compatible, partitionable) — host+device
// ---------------------------------------------------------------------------
__host__ __device__ inline void tf2x32(uint32_t k0, uint32_t k1,
                                       uint32_t x0, uint32_t x1,
                                       uint32_t* o0, uint32_t* o1) {
  uint32_t ks2 = k0 ^ k1 ^ 0x1BD11BDAu;
  x0 += k0; x1 += k1;
#define TFR(d) do { x0 += x1; x1 = (x1 << (d)) | (x1 >> (32 - (d))); x1 ^= x0; } while (0)
  TFR(13); TFR(15); TFR(26); TFR(6);
  x0 += k1;  x1 += ks2 + 1u;
  TFR(17); TFR(29); TFR(16); TFR(24);
  x0 += ks2; x1 += k0 + 2u;
  TFR(13); TFR(15); TFR(26); TFR(6);
  x0 += k0;  x1 += k1 + 3u;
  TFR(17); TFR(29); TFR(16); TFR(24);
  x0 += k1;  x1 += ks2 + 4u;
  TFR(13); TFR(15); TFR(26); TFR(6);
  x0 += ks2; x1 += k0 + 5u;
#undef TFR
  *o0 = x0; *o1 = x1;
}

__device__ inline uint32_t part_bits(uint32_t ka, uint32_t kb, uint32_t e) {
  uint32_t h1, h2;
  tf2x32(ka, kb, 0u, e, &h1, &h2);
  return h1 ^ h2;
}

// XLA ErfInv32 polynomial (Giles)
__device__ inline float erfinv_f32(float x) {
  float w = -log1pf(-x * x);
  float p;
  if (w < 5.0f) {
    w -= 2.5f;
    p = 2.81022636e-08f;
    p = fmaf(p, w, 3.43273939e-07f);
    p = fmaf(p, w, -3.5233877e-06f);
    p = fmaf(p, w, -4.39150654e-06f);
    p = fmaf(p, w, 0.00021858087f);
    p = fmaf(p, w, -0.00125372503f);
    p = fmaf(p, w, -0.00417768164f);
    p = fmaf(p, w, 0.246640727f);
    p = fmaf(p, w, 1.50140941f);
  } else {
    w = sqrtf(w) - 3.0f;
    p = -0.000200214257f;
    p = fmaf(p, w, 0.000100950558f);
    p = fmaf(p, w, 0.00134934322f);
    p = fmaf(p, w, -0.00367342844f);
    p = fmaf(p, w, 0.00573950773f);
    p = fmaf(p, w, -0.0076224613f);
    p = fmaf(p, w, 0.00943887047f);
    p = fmaf(p, w, 1.00167406f);
    p = fmaf(p, w, 2.83297682f);
  }
  return p * x;
}

__device__ inline float normal_from_bits(uint32_t bits) {
  float u01 = __uint_as_float((bits >> 9) | 0x3f800000u) - 1.0f;  // [0,1)
  const float lo = -0.99999994f;
  float u = u01 * 2.0f + lo;
  u = fmaxf(lo, u);
  return 1.41421356f * erfinv_f32(u);
}

__device__ inline float softplusf(float x) {
  return (x > 0.0f) ? x + log1pf(expf(-x)) : log1pf(expf(x));
}

// ---------------------------------------------------------------------------
// Utility kernels
// ---------------------------------------------------------------------------
__global__ void fill_f32(float* p, size_t n, float v) {
  size_t i = (size_t)blockIdx.x * blockDim.x + threadIdx.x;
  size_t stride = (size_t)gridDim.x * blockDim.x;
  for (; i < n; i += stride) p[i] = v;
}
__global__ void fill_u32(uint32_t* p, size_t n, uint32_t v) {
  size_t i = (size_t)blockIdx.x * blockDim.x + threadIdx.x;
  size_t stride = (size_t)gridDim.x * blockDim.x;
  for (; i < n; i += stride) p[i] = v;
}
__global__ void fill_b16(bf16* p, size_t n, float v) {
  size_t i = (size_t)blockIdx.x * blockDim.x + threadIdx.x;
  size_t stride = (size_t)gridDim.x * blockDim.x;
  bf16 b = f2b(v);
  for (; i < n; i += stride) p[i] = b;
}

// Detect weight dtype (R8-verified). flag=1 -> f32, flag=0 -> bf16.
__global__ void detect_dtype_kernel(const uint32_t* __restrict__ w, int* __restrict__ flag) {
  if (blockIdx.x == 0 && threadIdx.x == 0) {
    int votes = 0;
    for (int i = 0; i < 16; i++) {
      uint32_t lo = w[i] & 0xFFFFu;
      uint32_t e = (lo >> 7) & 0xFFu;
      if (e >= 0x70u && e < 0x80u) votes++;
    }
    *flag = (votes >= 12) ? 0 : 1;
  }
}

// Pack W into MFMA B-fragment order (bf16):
// out[((kt*MT+nt)*64+lane)*8+j] = W[kt*32+(lane>>4)*8+j][wcol0 + nt*16+(lane&15)]
// rows k >= srow0 scaled by sscale; rows k >= realK zeroed (K padding).
__global__ void pack_w_kernel(const void* __restrict__ W, const int* __restrict__ flagp,
                              int realK, int Kpad, int M, int Wld, int wcol0,
                              int srow0, float sscale, bf16* __restrict__ out) {
  int idx = blockIdx.x * 256 + threadIdx.x;
  if (idx >= Kpad * M) return;
  int j = idx & 7;
  int lane = (idx >> 3) & 63;
  int t = idx >> 9;
  int MT = M / 16;
  int kt = t / MT, nt = t - kt * MT;
  int k = kt * 32 + (lane >> 4) * 8 + j;
  int n = nt * 16 + (lane & 15);
  float v = 0.0f;
  if (k < realK) {
    v = wload(W, (size_t)k * Wld + wcol0 + n, *flagp);
    if (k >= srow0) v *= sscale;
  }
  out[idx] = f2b(v);
}

__global__ void count_deg_kernel(const int* __restrict__ lit, int* __restrict__ deg) {
  int e = blockIdx.x * 256 + threadIdx.x;
  if (e < E_N) atomicAdd(&deg[lit[e]], 1);
}

__global__ void hist32_kernel(const int* __restrict__ gid, int n, int* __restrict__ out) {
  __shared__ int bins[NGR];
  int t = threadIdx.x;
  if (t < NGR) bins[t] = 0;
  __syncthreads();
  int i = blockIdx.x * 256 + t;
  if (i < n) atomicAdd(&bins[gid[i]], 1);
  __syncthreads();
  if (t < NGR && bins[t] > 0) atomicAdd(&out[t], bins[t]);
}

__global__ void weights_kernel(const int* __restrict__ deg,
                               float* __restrict__ dw, float* __restrict__ vdw) {
  int l = blockIdx.x * 256 + threadIdx.x;
  if (l < L_N) dw[l] = rsqrtf(fmaxf((float)deg[l], 1.0f));
  if (l < V_N) vdw[l] = 4.0f * rsqrtf(fmaxf((float)(deg[l] + deg[l + V_N]), 1.0f));
}

// single-block exclusive scan of L_N degrees -> offs[L_N+1]
__global__ void scan_kernel(const int* __restrict__ deg, int* __restrict__ offs) {
  __shared__ int part[256];
  __shared__ int base[257];
  int t = threadIdx.x;
  const int CH = (L_N + 255) / 256;
  int i0 = t * CH, i1 = min(L_N, i0 + CH);
  int s = 0;
  for (int i = i0; i < i1; i++) s += deg[i];
  part[t] = s;
  __syncthreads();
  if (t == 0) {
    int acc = 0;
    for (int j = 0; j < 256; j++) { base[j] = acc; acc += part[j]; }
    base[256] = acc;
  }
  __syncthreads();
  int acc = base[t];
  for (int i = i0; i < i1; i++) { offs[i] = acc; acc += deg[i]; }
  if (t == 255) offs[L_N] = base[256];
}

__global__ void csr_fill_kernel(const int* __restrict__ lit,
                                const int* __restrict__ offs, int* __restrict__ cursor,
                                int* __restrict__ csr) {
  int e = blockIdx.x * 256 + threadIdx.x;
  if (e < E_N) {
    int l = lit[e];
    int p = atomicAdd(&cursor[l], 1);
    csr[offs[l] + p] = e / 3;   // clause index (clause_idx = repeat(arange(C),3))
  }
}

// per-round: write only the 4 real noise columns (pad zeroed once at setup)
__global__ void noise4_kernel(bf16* __restrict__ Zb, uint32_t ka, uint32_t kb) {
  int idx = blockIdx.x * 256 + threadIdx.x;
  if (idx >= V_N * 4) return;
  int v = idx >> 2, j = idx & 3;
  Zb[(size_t)v * 32 + j] = f2b(normal_from_bits(part_bits(ka, kb, (uint32_t)idx)));
}

// ---------------------------------------------------------------------------
// Fused MLP kernels. 256 thr = 4 waves; wave w owns rows [blk*64+16w, +16).
// Hidden tiles staged in LDS (C-layout write -> A-layout read, wave-private).
// ---------------------------------------------------------------------------

// vq: Q = (relu([variables|Z] @ W0 + b0)) @ W1 + b1   (K=96 padded, M=64)
// ALSO writes per-literal softplus table: SP[v] = sp(q), SP[v+V] = sp(-q)
// (hoists the per-edge softplus out of cl_kernel: 6.3x fewer transcendentals)
__global__ __launch_bounds__(256) void vq_fused_kernel(
    const bf16* __restrict__ variables, const bf16* __restrict__ Zb,
    const bf16* __restrict__ W0p, const void* __restrict__ b0,
    const bf16* __restrict__ W1p, const void* __restrict__ b1,
    const int* __restrict__ flagp, bf16* __restrict__ Q,
    bf16* __restrict__ SP, int N) {
  __shared__ bf16 hs[64][72];
  int tid = threadIdx.x;
  int wave = tid >> 6, lane = tid & 63, quad = lane >> 4, m16 = lane & 15;
  int row = blockIdx.x * 64 + wave * 16 + m16;
  int rowc = min(row, N - 1);
  int isf32 = *flagp;
  float4v acc[4];
#pragma unroll
  for (int nt = 0; nt < 4; nt++) acc[nt] = (float4v){0.f, 0.f, 0.f, 0.f};
  const short8* w0 = (const short8*)W0p;
  for (int k0 = 0; k0 < 96; k0 += 32) {
    int ks = k0 + quad * 8;
    const bf16* src = (ks < 64) ? variables + (size_t)rowc * 64 + ks
                                : Zb + (size_t)rowc * 32 + (ks - 64);
    short8 a = *(const short8*)src;
#pragma unroll
    for (int nt = 0; nt < 4; nt++) {
      short8 b = w0[((k0 >> 5) * 4 + nt) * 64 + lane];
      acc[nt] = __builtin_amdgcn_mfma_f32_16x16x32_bf16(a, b, acc[nt], 0, 0, 0);
    }
  }
  int rl = wave * 16 + quad * 4;
#pragma unroll
  for (int nt = 0; nt < 4; nt++) {
    int col = nt * 16 + m16;
    float bv = wload(b0, col, isf32);
#pragma unroll
    for (int i = 0; i < 4; i++)
      hs[rl + i][col] = f2b(fmaxf(acc[nt][i] + bv, 0.0f));
  }
  __syncthreads();
  float4v acc2[4];
#pragma unroll
  for (int nt = 0; nt < 4; nt++) acc2[nt] = (float4v){0.f, 0.f, 0.f, 0.f};
  const short8* w1 = (const short8*)W1p;
  for (int k0 = 0; k0 < 64; k0 += 32) {
    short8 a = *(const short8*)&hs[wave * 16 + m16][k0 + quad * 8];
#pragma unroll
    for (int nt = 0; nt < 4; nt++) {
      short8 b = w1[((k0 >> 5) * 4 + nt) * 64 + lane];
      acc2[nt] = __builtin_amdgcn_mfma_f32_16x16x32_bf16(a, b, acc2[nt], 0, 0, 0);
    }
  }
  int rbase = blockIdx.x * 64 + wave * 16 + quad * 4;
#pragma unroll
  for (int nt = 0; nt < 4; nt++) {
    int col = nt * 16 + m16;
    float bv = wload(b1, col, isf32);
#pragma unroll
    for (int i = 0; i < 4; i++) {
      int r = rbase + i;
      if (r < N) {
        float q = acc2[nt][i] + bv;
        Q[(size_t)r * 64 + col] = f2b(q);
        SP[(size_t)r * 64 + col] = f2b(softplusf(q));
        SP[(size_t)(r + V_N) * 64 + col] = f2b(softplusf(-q));
      }
    }
  }
}

// cm: H = relu([clauses|clb] @ W0 + b0); D = H @ W1 + b1; Dl=D[:, :64],
// Dn=D[:, 64:]. Dn overlays clb in-place (block reads its rows pre-barrier).
__global__ __launch_bounds__(256) void cm_fused_kernel(
    const bf16* __restrict__ clauses, const bf16* __restrict__ clb,
    const bf16* __restrict__ W0p, const void* __restrict__ b0,
    const bf16* __restrict__ W1p, const void* __restrict__ b1,
    const int* __restrict__ flagp,
    bf16* __restrict__ Dl, bf16* __restrict__ Dn, int N) {
  __shared__ bf16 hs[64][136];
  int tid = threadIdx.x;
  int wave = tid >> 6, lane = tid & 63, quad = lane >> 4, m16 = lane & 15;
  int row = blockIdx.x * 64 + wave * 16 + m16;
  int rowc = min(row, N - 1);
  int isf32 = *flagp;
  float4v acc[8];
#pragma unroll
  for (int nt = 0; nt < 8; nt++) acc[nt] = (float4v){0.f, 0.f, 0.f, 0.f};
  const short8* w0 = (const short8*)W0p;
  for (int k0 = 0; k0 < 128; k0 += 32) {
    int ks = k0 + quad * 8;
    const bf16* src = (ks < 64) ? clauses + (size_t)rowc * 64 + ks
                                : clb + (size_t)rowc * 64 + (ks - 64);
    short8 a = *(const short8*)src;
#pragma unroll
    for (int nt = 0; nt < 8; nt++) {
      short8 b = w0[((k0 >> 5) * 8 + nt) * 64 + lane];
      acc[nt] = __builtin_amdgcn_mfma_f32_16x16x32_bf16(a, b, acc[nt], 0, 0, 0);
    }
  }
  int rl = wave * 16 + quad * 4;
#pragma unroll
  for (int nt = 0; nt < 8; nt++) {
    int col = nt * 16 + m16;
    float bv = wload(b0, col, isf32);
#pragma unroll
    for (int i = 0; i < 4; i++)
      hs[rl + i][col] = f2b(fmaxf(acc[nt][i] + bv, 0.0f));
  }
  __syncthreads();
#pragma unroll
  for (int nt = 0; nt < 8; nt++) acc[nt] = (float4v){0.f, 0.f, 0.f, 0.f};
  const short8* w1 = (const short8*)W1p;
  for (int k0 = 0; k0 < 128; k0 += 32) {
    short8 a = *(const short8*)&hs[wave * 16 + m16][k0 + quad * 8];
#pragma unroll
    for (int nt = 0; nt < 8; nt++) {
      short8 b = w1[((k0 >> 5) * 8 + nt) * 64 + lane];
      acc[nt] = __builtin_amdgcn_mfma_f32_16x16x32_bf16(a, b, acc[nt], 0, 0, 0);
    }
  }
  int rbase = blockIdx.x * 64 + wave * 16 + quad * 4;
#pragma unroll
  for (int nt = 0; nt < 8; nt++) {
    int col = nt * 16 + m16;
    float bv = wload(b1, col, isf32);
#pragma unroll
    for (int i = 0; i < 4; i++) {
      int r = rbase + i;
      if (r < N) {
        float v = acc[nt][i] + bv;
        if (col < 64) Dl[(size_t)r * 64 + col] = f2b(v);
        else          Dn[(size_t)r * 64 + (col - 64)] = f2b(v);
      }
    }
  }
}

// ug: 3-layer MLP [QG|variables|VLb](K=256) ->128 ->128 ->64, NV f32 out.
__global__ __launch_bounds__(256) void ug_fused_kernel(
    const bf16* __restrict__ QG, const bf16* __restrict__ variables,
    const bf16* __restrict__ VLb,
    const bf16* __restrict__ W0p, const void* __restrict__ b0,
    const bf16* __restrict__ W1p, const void* __restrict__ b1,
    const bf16* __restrict__ W2p, const void* __restrict__ b2,
    const int* __restrict__ flagp, float* __restrict__ NV, int N) {
  __shared__ bf16 h1[64][136];
  __shared__ bf16 h2[64][136];
  int tid = threadIdx.x;
  int wave = tid >> 6, lane = tid & 63, quad = lane >> 4, m16 = lane & 15;
  int row = blockIdx.x * 64 + wave * 16 + m16;
  int rowc = min(row, N - 1);
  int isf32 = *flagp;
  int rl = wave * 16 + quad * 4;
  float4v acc[8];
#pragma unroll
  for (int nt = 0; nt < 8; nt++) acc[nt] = (float4v){0.f, 0.f, 0.f, 0.f};
  const short8* w0 = (const short8*)W0p;
  for (int k0 = 0; k0 < 256; k0 += 32) {
    int ks = k0 + quad * 8;
    const bf16* src;
    if (ks < 64)       src = QG + (size_t)rowc * 64 + ks;
    else if (ks < 128) src = variables + (size_t)rowc * 64 + (ks - 64);
    else               src = VLb + (size_t)rowc * 128 + (ks - 128);
    short8 a = *(const short8*)src;
#pragma unroll
    for (int nt = 0; nt < 8; nt++) {
      short8 b = w0[((k0 >> 5) * 8 + nt) * 64 + lane];
      acc[nt] = __builtin_amdgcn_mfma_f32_16x16x32_bf16(a, b, acc[nt], 0, 0, 0);
    }
  }
#pragma unroll
  for (int nt = 0; nt < 8; nt++) {
    int col = nt * 16 + m16;
    float bv = wload(b0, col, isf32);
#pragma unroll
    for (int i = 0; i < 4; i++)
      h1[rl + i][col] = f2b(fmaxf(acc[nt][i] + bv, 0.0f));
  }
  __syncthreads();
#pragma unroll
  for (int nt = 0; nt < 8; nt++) acc[nt] = (float4v){0.f, 0.f, 0.f, 0.f};
  const short8* w1 = (const short8*)W1p;
  for (int k0 = 0; k0 < 128; k0 += 32) {
    short8 a = *(const short8*)&h1[wave * 16 + m16][k0 + quad * 8];
#pragma unroll
    for (int nt = 0; nt < 8; nt++) {
      short8 b = w1[((k0 >> 5) * 8 + nt) * 64 + lane];
      acc[nt] = __builtin_amdgcn_mfma_f32_16x16x32_bf16(a, b, acc[nt], 0, 0, 0);
    }
  }
#pragma unroll
  for (int nt = 0; nt < 8; nt++) {
    int col = nt * 16 + m16;
    float bv = wload(b1, col, isf32);
#pragma unroll
    for (int i = 0; i < 4; i++)
      h2[rl + i][col] = f2b(fmaxf(acc[nt][i] + bv, 0.0f));
  }
  __syncthreads();
  float4v acc3[4];
#pragma unroll
  for (int nt = 0; nt < 4; nt++) acc3[nt] = (float4v){0.f, 0.f, 0.f, 0.f};
  const short8* w2 = (const short8*)W2p;
  for (int k0 = 0; k0 < 128; k0 += 32) {
    short8 a = *(const short8*)&h2[wave * 16 + m16][k0 + quad * 8];
#pragma unroll
    for (int nt = 0; nt < 4; nt++) {
      short8 b = w2[((k0 >> 5) * 4 + nt) * 64 + lane];
      acc3[nt] = __builtin_amdgcn_mfma_f32_16x16x32_bf16(a, b, acc3[nt], 0, 0, 0);
    }
  }
  int rbase = blockIdx.x * 64 + wave * 16 + quad * 4;
#pragma unroll
  for (int nt = 0; nt < 4; nt++) {
    int col = nt * 16 + m16;
    float bv = wload(b2, col, isf32);
#pragma unroll
    for (int i = 0; i < 4; i++) {
      int r = rbase + i;
      if (r < N) NV[(size_t)r * 64 + col] = acc3[nt][i] + bv;
    }
  }
}

// ---------------------------------------------------------------------------
// Edge / node kernels (wave = 64 lanes = feature dim)
// ---------------------------------------------------------------------------
// cl: cv = sum of 3 precomputed SP rows; cl = exp(-cv). + stats-zero (block 0)
__global__ void cl_kernel(const bf16* __restrict__ SP, const int* __restrict__ lit,
                          bf16* __restrict__ cl, float* __restrict__ stats) {
  if (blockIdx.x == 0) {
    int t = threadIdx.y * 64 + threadIdx.x;
    for (int i = t; i < 4096; i += 256) stats[i] = 0.0f;
  }
  int c = blockIdx.x * 4 + threadIdx.y;
  if (c >= C_N) return;
  int k = threadIdx.x;
  int l0 = lit[3 * c], l1 = lit[3 * c + 1], l2 = lit[3 * c + 2];
  float cv = b2f(SP[(size_t)l0 * 64 + k]) + b2f(SP[(size_t)l1 * 64 + k])
           + b2f(SP[(size_t)l2 * 64 + k]);
  cl[(size_t)c * 64 + k] = f2b(expf(-cv));
}

// fused: G gathers (CSR) + q-grad; QG = (-sig(q)*Gpos + sig(-q)*Gneg) * vdw
__global__ void qgrad_kernel(const bf16* __restrict__ Q, const bf16* __restrict__ clb,
                             const int* __restrict__ csr, const int* __restrict__ offs,
                             const float* __restrict__ vdw, bf16* __restrict__ QG) {
  int v = blockIdx.x * 4 + threadIdx.y;
  if (v >= V_N) return;
  int k = threadIdx.x;
  float gp = 0.0f, gn = 0.0f;
  int p0 = offs[v], p1 = offs[v + 1];
  for (int p = p0; p < p1; p++) gp += b2f(clb[(size_t)csr[p] * 64 + k]);
  p0 = offs[v + V_N]; p1 = offs[v + V_N + 1];
  for (int p = p0; p < p1; p++) gn += b2f(clb[(size_t)csr[p] * 64 + k]);
  float q = b2f(Q[(size_t)v * 64 + k]);
  float sp = 1.0f / (1.0f + expf(-q));
  float sn = 1.0f / (1.0f + expf(q));
  QG[(size_t)v * 64 + k] = f2b((-sp * gp + sn * gn) * vdw[v]);
}

// VLb via CSR gather of Dl; block 0 zeros S1/S2 for the variable pairnorm.
__global__ void vlb_gather_kernel(const bf16* __restrict__ Dl, const int* __restrict__ csr,
                                  const int* __restrict__ offs, const float* __restrict__ dw,
                                  bf16* __restrict__ VLb, float* __restrict__ stats) {
  if (blockIdx.x == 0) {
    int t = threadIdx.y * 64 + threadIdx.x;
    for (int i = t; i < 4096; i += 256) stats[i] = 0.0f;
  }
  int l = blockIdx.x * 4 + threadIdx.y;
  if (l >= L_N) return;
  int k = threadIdx.x;
  float s = 0.0f;
  int p0 = offs[l], p1 = offs[l + 1];
  for (int p = p0; p < p1; p++) s += b2f(Dl[(size_t)csr[p] * 64 + k]);
  s *= dw[l];
  size_t v = (l < V_N) ? (size_t)l : (size_t)(l - V_N);
  int col = (l < V_N) ? 0 : 64;
  VLb[v * 128 + col + k] = f2b(s);
}

// ---------------------------------------------------------------------------
// PairNorm — one stats pass (S1,S2); apply recomputes mean/var inline.
// ---------------------------------------------------------------------------
template<typename TX>
__global__ void pn_stats_kernel(const TX* __restrict__ X,
                                const int* __restrict__ gid, int n,
                                float* __restrict__ S1, float* __restrict__ S2) {
  int wave = blockIdx.x * blockDim.y + threadIdx.y;
  int nw = gridDim.x * blockDim.y;
  int chunk = (n + nw - 1) / nw;
  int i0 = wave * chunk;
  if (i0 >= n) return;
  int i1 = min(n, i0 + chunk);
  int k = threadIdx.x;
  int g = gid[i0];
  float a1 = 0.0f, a2 = 0.0f;
  for (int i = i0; i < i1; i++) {
    int gi = gid[i];
    if (gi != g) {
      atomicAdd(&S1[g * 64 + k], a1);
      atomicAdd(&S2[g * 64 + k], a2);
      a1 = 0.0f; a2 = 0.0f; g = gi;
    }
    float x = loadT(&X[(size_t)i * 64 + k]);
    a1 += x;
    a2 += x * x;
  }
  atomicAdd(&S1[g * 64 + k], a1);
  atomicAdd(&S2[g * 64 + k], a2);
}

// state = (pairnorm(X)*0.25 + 0.1*state) * post ; var computed inline
template<typename TX>
__global__ void pn_apply_kernel(const TX* __restrict__ X,
                                const int* __restrict__ gid, int n,
                                const int* __restrict__ cnt, const float* __restrict__ S1,
                                const float* __restrict__ S2, bf16* __restrict__ state,
                                float post) {
  int i = blockIdx.x * 4 + threadIdx.y;
  if (i >= n) return;
  int k = threadIdx.x;
  int g = gid[i];
  float c = fmaxf((float)cnt[g], 1.0f);
  float mean = S1[g * 64 + k] / c;
  float t = S2[g * 64 + k] / c - mean * mean;
#pragma unroll
  for (int o = 32; o > 0; o >>= 1) t += __shfl_down(t, o);
  float var = fmaxf(__shfl(t, 0), 0.0f) * (1.0f / 64.0f);
  float xn = (loadT(&X[(size_t)i * 64 + k]) - mean) * rsqrtf(var + 1e-6f);
  size_t o = (size_t)i * 64 + k;
  state[o] = f2b((xn * 0.25f + 0.1f * b2f(state[o])) * post);
}

// fused co MLP + noise + sigmoid: out[c] = sigmoid(relu(x@W0+b0)@W1 + b1 + N_c)
__global__ __launch_bounds__(256) void co_final_kernel(
    const bf16* __restrict__ clauses, const void* __restrict__ W0,
    const void* __restrict__ b0, const void* __restrict__ W1,
    const void* __restrict__ b1, const int* __restrict__ flagp,
    uint32_t ka, uint32_t kb, float* __restrict__ out) {
  __shared__ float w0s[64 * 64];
  int isf32 = *flagp;
  int tid = threadIdx.y * 64 + threadIdx.x;
  for (int i = tid; i < 64 * 64; i += 256) w0s[i] = wload(W0, i, isf32);
  __syncthreads();
  int c = blockIdx.x * 4 + threadIdx.y;
  if (c >= C_N) return;
  int k = threadIdx.x;
  float x = b2f(clauses[(size_t)c * 64 + k]);
  float h = wload(b0, k, isf32);
#pragma unroll 8
  for (int j = 0; j < 64; j++) h = fmaf(__shfl(x, j), w0s[j * 64 + k], h);
  h = fmaxf(h, 0.0f);
  float v = h * wload(W1, k, isf32);
#pragma unroll
  for (int o = 32; o > 0; o >>= 1) v += __shfl_down(v, o);
  if (k == 0) {
    float lg = v + wload(b1, 0, isf32) + normal_from_bits(part_bits(ka, kb, (uint32_t)c));
    out[c] = 1.0f / (1.0f + expf(-lg));
  }
}

// ---------------------------------------------------------------------------
// Launch
// ---------------------------------------------------------------------------
extern "C" void kernel_launch(void* const* d_in, const int* in_sizes, int n_in,
                              void* d_out, int out_size, void* d_ws, size_t ws_size,
                              hipStream_t stream) {
  (void)in_sizes; (void)n_in; (void)out_size;
  const int* lit_idx    = (const int*)d_in[0];
  const int* var_gid    = (const int*)d_in[2];
  const int* clause_gid = (const int*)d_in[3];
  const void* vq_W0 = d_in[4];
  const void* vq_b0 = d_in[5];
  const void* vq_W1 = d_in[6];
  const void* vq_b1 = d_in[7];
  const void* cm_W0 = d_in[8];
  const void* cm_b0 = d_in[9];
  const void* cm_W1 = d_in[10];
  const void* cm_b1 = d_in[11];
  const void* ug_W0 = d_in[12];
  const void* ug_b0 = d_in[13];
  const void* ug_W1 = d_in[14];
  const void* ug_b1 = d_in[15];
  const void* ug_W2 = d_in[16];
  const void* ug_b2 = d_in[17];
  const void* co_W0 = d_in[18];
  const void* co_b0 = d_in[19];
  const void* co_W1 = d_in[20];
  const void* co_b1 = d_in[21];
  float* out = (float*)d_out;

  // ---- workspace layout (~216 MB peak) ----
  char* ws = (char*)d_ws;
  size_t off = 0;
  auto alloc = [&](size_t bytes) -> void* {
    void* p = ws + off;
    off = (off + bytes + 255) & ~(size_t)255;
    return p;
  };
  bf16* variables = (bf16*)alloc((size_t)V_N * 64 * 2);   // persistent state
  bf16* clauses   = (bf16*)alloc((size_t)C_N * 64 * 2);   // persistent state
  // ZE (C*64*2): clb -> Dn (in-place overlay in cm_fused) -> VLb (V*128)
  char* ZE        = (char*)alloc((size_t)C_N * 64 * 2);
  // ZD (C*64*2): SP (L*64) -> Dl (C*64) -> NV f32 (V*64)
  char* ZD        = (char*)alloc((size_t)C_N * 64 * 2);
  bf16* QG        = (bf16*)alloc((size_t)V_N * 64 * 2);
  bf16* Q         = (bf16*)alloc((size_t)V_N * 64 * 2);
  bf16* Zb        = (bf16*)alloc((size_t)V_N * 32 * 2);
  int*  izone     = (int*)alloc((size_t)(2 * L_N + 64) * 4);
  int*  offs      = (int*)alloc((size_t)(L_N + 1) * 4);
  int*  csr       = (int*)alloc((size_t)E_N * 4);
  float* deg_f    = (float*)alloc((size_t)L_N * 4);
  float* vdw      = (float*)alloc((size_t)V_N * 4);
  float* stats    = (float*)alloc((size_t)4096 * 4);
  int*   wflag    = (int*)alloc(256);
  // packed MFMA weights (bf16)
  bf16* vq_W0p = (bf16*)alloc((size_t)96 * 64 * 2);
  bf16* vq_W1p = (bf16*)alloc((size_t)64 * 64 * 2);
  bf16* cm_W0p = (bf16*)alloc((size_t)128 * 128 * 2);
  bf16* cm_W1p = (bf16*)alloc((size_t)128 * 128 * 2);
  bf16* ug_W0p = (bf16*)alloc((size_t)256 * 128 * 2);
  bf16* ug_W1p = (bf16*)alloc((size_t)128 * 128 * 2);
  bf16* ug_W2p = (bf16*)alloc((size_t)128 * 64 * 2);
  size_t need = off;

  auto nb = [](int n, int per) { return (n + per - 1) / per; };

  if (ws_size < need) {
    fill_f32<<<nb(C_N, 256), 256, 0, stream>>>(out, (size_t)C_N, 0.5f);
    return;
  }

  bf16* clb = (bf16*)ZE;                 // C x 64
  bf16* Dn  = (bf16*)ZE;                 // C x 64 (in-place overlay)
  bf16* VLb = (bf16*)ZE;                 // V x 128 (after Dn consumed)
  bf16* SP  = (bf16*)ZD;                 // L x 64 (vq -> cl; dead before Dl)
  bf16* Dl  = (bf16*)ZD;                 // C x 64 (cm -> vlb_gather)
  float* NV = (float*)ZD;                // V x 64 f32 (after Dl consumed)

  int* deg_i  = izone;
  int* cursor = izone + L_N;
  int* cntv   = izone + 2 * L_N;
  int* cntc   = cntv + 32;
  float* S1 = stats;              // 32 x 64
  float* S2 = stats + 2048;       // 32 x 64

  // JAX keys = split(key(42), 9), partitionable: subkey_i = threefry(key,0,i)
  uint32_t kw0[9], kw1[9];
  for (int i = 0; i < 9; i++) tf2x32(0u, 42u, 0u, (uint32_t)i, &kw0[i], &kw1[i]);

  dim3 wb(64, 4);
  const int BIG = 1 << 30;

  // ---- setup (re-done every call) ----
  detect_dtype_kernel<<<1, 64, 0, stream>>>((const uint32_t*)vq_W0, wflag);
  fill_u32<<<nb(2 * L_N + 64, 256), 256, 0, stream>>>((uint32_t*)izone, (size_t)(2 * L_N + 64), 0u);
  count_deg_kernel<<<nb(E_N, 256), 256, 0, stream>>>(lit_idx, deg_i);
  hist32_kernel<<<nb(V_N, 256), 256, 0, stream>>>(var_gid, V_N, cntv);
  hist32_kernel<<<nb(C_N, 256), 256, 0, stream>>>(clause_gid, C_N, cntc);
  weights_kernel<<<nb(L_N, 256), 256, 0, stream>>>(deg_i, deg_f, vdw);
  scan_kernel<<<1, 256, 0, stream>>>(deg_i, offs);
  csr_fill_kernel<<<nb(E_N, 256), 256, 0, stream>>>(lit_idx, offs, cursor, csr);
  fill_b16<<<2048, 256, 0, stream>>>(variables, (size_t)V_N * 64, 1.0f);
  fill_b16<<<2048, 256, 0, stream>>>(clauses, (size_t)C_N * 64, 1.0f);
  fill_b16<<<2048, 256, 0, stream>>>(Zb, (size_t)V_N * 32, 0.0f);   // zero pad cols once
  // pack weights into MFMA B-fragment order
  pack_w_kernel<<<nb(96 * 64, 256), 256, 0, stream>>>(vq_W0, wflag, 68, 96, 64, 64, 0, BIG, 1.f, vq_W0p);
  pack_w_kernel<<<nb(64 * 64, 256), 256, 0, stream>>>(vq_W1, wflag, 64, 64, 64, 64, 0, BIG, 1.f, vq_W1p);
  pack_w_kernel<<<nb(128 * 128, 256), 256, 0, stream>>>(cm_W0, wflag, 128, 128, 128, 128, 0, 64, 4.f, cm_W0p);
  pack_w_kernel<<<nb(128 * 128, 256), 256, 0, stream>>>(cm_W1, wflag, 128, 128, 128, 128, 0, BIG, 1.f, cm_W1p);
  pack_w_kernel<<<nb(256 * 128, 256), 256, 0, stream>>>(ug_W0, wflag, 256, 256, 128, 128, 0, BIG, 1.f, ug_W0p);
  pack_w_kernel<<<nb(128 * 128, 256), 256, 0, stream>>>(ug_W1, wflag, 128, 128, 128, 128, 0, BIG, 1.f, ug_W1p);
  pack_w_kernel<<<nb(128 * 64, 256), 256, 0, stream>>>(ug_W2, wflag, 128, 128, 64, 64, 0, BIG, 1.f, ug_W2p);

  // ---- rounds (11 launches each) ----
  for (int r = 0; r < NROUNDS; r++) {
    noise4_kernel<<<nb(V_N * 4, 256), 256, 0, stream>>>(Zb, kw0[r], kw1[r]);
    vq_fused_kernel<<<nb(V_N, 64), 256, 0, stream>>>(
        variables, Zb, vq_W0p, vq_b0, vq_W1p, vq_b1, wflag, Q, SP, V_N);
    cl_kernel<<<nb(C_N, 4), wb, 0, stream>>>(SP, lit_idx, clb, stats);
    qgrad_kernel<<<nb(V_N, 4), wb, 0, stream>>>(Q, clb, csr, offs, vdw, QG);
    cm_fused_kernel<<<nb(C_N, 64), 256, 0, stream>>>(
        clauses, clb, cm_W0p, cm_b0, cm_W1p, cm_b1, wflag, Dl, Dn, C_N);
    pn_stats_kernel<bf16><<<512, wb, 0, stream>>>(Dn, clause_gid, C_N, S1, S2);
    pn_apply_kernel<bf16><<<nb(C_N, 4), wb, 0, stream>>>(
        Dn, clause_gid, C_N, cntc, S1, S2, clauses, (r == NROUNDS - 1) ? 1.0f : 0.2f);
    vlb_gather_kernel<<<nb(L_N, 4), wb, 0, stream>>>(Dl, csr, offs, deg_f, VLb, stats);
    ug_fused_kernel<<<nb(V_N, 64), 256, 0, stream>>>(
        QG, variables, VLb, ug_W0p, ug_b0, ug_W1p, ug_b1, ug_W2p, ug_b2,
        wflag, NV, V_N);
    pn_stats_kernel<float><<<512, wb, 0, stream>>>(NV, var_gid, V_N, S1, S2);
    pn_apply_kernel<float><<<nb(V_N, 4), wb, 0, stream>>>(
        NV, var_gid, V_N, cntv, S1, S2, variables, 1.0f);
  }
  co_final_kernel<<<nb(C_N, 4), wb, 0, stream>>>(
      clauses, co_W0, co_b0, co_W1, co_b1, wflag, kw0[8], kw1[8], out);
}

// Round 13
// 4891.421 us; speedup vs baseline: 4.7723x; 1.4735x over previous
//
#include <hip/hip_runtime.h>
#include <hip/hip_bf16.h>
#include <cstdint>
#include <cstddef>

// ---------------------------------------------------------------------------
// Problem constants
// ---------------------------------------------------------------------------
constexpr int V_N = 100000;   // variables
constexpr int C_N = 420000;   // clauses
constexpr int L_N = 2 * V_N;  // literals
constexpr int E_N = 3 * C_N;  // nnz edges
constexpr int NGR = 32;       // graphs
constexpr int NROUNDS = 8;

using bf16 = __hip_bfloat16;
typedef __attribute__((ext_vector_type(8))) short short8;   // 8 bf16 (4 VGPRs)
typedef __attribute__((ext_vector_type(4))) float float4v;  // 4 fp32 acc

__device__ inline float b2f(bf16 h) { return __bfloat162float(h); }
__device__ inline bf16 f2b(float f) { return __float2bfloat16(f); }
__device__ inline float sb2f(short s) { return __uint_as_float(((uint32_t)(uint16_t)s) << 16); }
__device__ inline short f2sb(float f) { bf16 h = f2b(f); return *(short*)&h; }

template<typename T> __device__ inline float loadT(const T* p);
template<> __device__ inline float loadT<float>(const float* p) { return *p; }
template<> __device__ inline float loadT<bf16>(const bf16* p) { return b2f(*p); }

// load 8 consecutive values as f32
template<typename TX> __device__ inline void load8(const TX* p, float* v);
template<> __device__ inline void load8<bf16>(const bf16* p, float* v) {
  short8 s = *(const short8*)p;
#pragma unroll
  for (int e = 0; e < 8; e++) v[e] = sb2f(s[e]);
}
template<> __device__ inline void load8<float>(const float* p, float* v) {
  float4 a = *(const float4*)p;
  float4 b = *(const float4*)(p + 4);
  v[0] = a.x; v[1] = a.y; v[2] = a.z; v[3] = a.w;
  v[4] = b.x; v[5] = b.y; v[6] = b.z; v[7] = b.w;
}

// runtime-dtype weight load: isf32 ? f32 buffer : packed bf16 buffer
__device__ inline float wload(const void* W, size_t idx, int isf32) {
  return isf32 ? ((const float*)W)[idx] : b2f(((const bf16*)W)[idx]);
}

// ---------------------------------------------------------------------------
// Threefry-2x32 (JAX-compatible, partitionable) — host+device
// ---------------------------------------------------------------------------
__host__ __device__ inline void tf2x32(uint32_t k0, uint32_t k1,
                                       uint32_t x0, uint32_t x1,
                                       uint32_t* o0, uint32_t* o1) {
  uint32_t ks2 = k0 ^ k1 ^ 0x1BD11BDAu;
  x0 += k0; x1 += k1;
#define TFR(d) do { x0 += x1; x1 = (x1 << (d)) | (x1 >> (32 - (d))); x1 ^= x0; } while (0)
  TFR(13); TFR(15); TFR(26); TFR(6);
  x0 += k1;  x1 += ks2 + 1u;
  TFR(17); TFR(29); TFR(16); TFR(24);
  x0 += ks2; x1 += k0 + 2u;
  TFR(13); TFR(15); TFR(26); TFR(6);
  x0 += k0;  x1 += k1 + 3u;
  TFR(17); TFR(29); TFR(16); TFR(24);
  x0 += k1;  x1 += ks2 + 4u;
  TFR(13); TFR(15); TFR(26); TFR(6);
  x0 += ks2; x1 += k0 + 5u;
#undef TFR
  *o0 = x0; *o1 = x1;
}

__device__ inline uint32_t part_bits(uint32_t ka, uint32_t kb, uint32_t e) {
  uint32_t h1, h2;
  tf2x32(ka, kb, 0u, e, &h1, &h2);
  return h1 ^ h2;
}

// XLA ErfInv32 polynomial (Giles)
__device__ inline float erfinv_f32(float x) {
  float w = -log1pf(-x * x);
  float p;
  if (w < 5.0f) {
    w -= 2.5f;
    p = 2.81022636e-08f;
    p = fmaf(p, w, 3.43273939e-07f);
    p = fmaf(p, w, -3.5233877e-06f);
    p = fmaf(p, w, -4.39150654e-06f);
    p = fmaf(p, w, 0.00021858087f);
    p = fmaf(p, w, -0.00125372503f);
    p = fmaf(p, w, -0.00417768164f);
    p = fmaf(p, w, 0.246640727f);
    p = fmaf(p, w, 1.50140941f);
  } else {
    w = sqrtf(w) - 3.0f;
    p = -0.000200214257f;
    p = fmaf(p, w, 0.000100950558f);
    p = fmaf(p, w, 0.00134934322f);
    p = fmaf(p, w, -0.00367342844f);
    p = fmaf(p, w, 0.00573950773f);
    p = fmaf(p, w, -0.0076224613f);
    p = fmaf(p, w, 0.00943887047f);
    p = fmaf(p, w, 1.00167406f);
    p = fmaf(p, w, 2.83297682f);
  }
  return p * x;
}

__device__ inline float normal_from_bits(uint32_t bits) {
  float u01 = __uint_as_float((bits >> 9) | 0x3f800000u) - 1.0f;  // [0,1)
  const float lo = -0.99999994f;
  float u = u01 * 2.0f + lo;
  u = fmaxf(lo, u);
  return 1.41421356f * erfinv_f32(u);
}

__device__ inline float softplusf(float x) {
  return (x > 0.0f) ? x + log1pf(expf(-x)) : log1pf(expf(x));
}

// ---------------------------------------------------------------------------
// Utility kernels
// ---------------------------------------------------------------------------
__global__ void fill_f32(float* p, size_t n, float v) {
  size_t i = (size_t)blockIdx.x * blockDim.x + threadIdx.x;
  size_t stride = (size_t)gridDim.x * blockDim.x;
  for (; i < n; i += stride) p[i] = v;
}
__global__ void fill_u32(uint32_t* p, size_t n, uint32_t v) {
  size_t i = (size_t)blockIdx.x * blockDim.x + threadIdx.x;
  size_t stride = (size_t)gridDim.x * blockDim.x;
  for (; i < n; i += stride) p[i] = v;
}
__global__ void fill_b16(bf16* p, size_t n, float v) {
  size_t i = (size_t)blockIdx.x * blockDim.x + threadIdx.x;
  size_t stride = (size_t)gridDim.x * blockDim.x;
  bf16 b = f2b(v);
  for (; i < n; i += stride) p[i] = b;
}

// Detect weight dtype (R8-verified). flag=1 -> f32, flag=0 -> bf16.
__global__ void detect_dtype_kernel(const uint32_t* __restrict__ w, int* __restrict__ flag) {
  if (blockIdx.x == 0 && threadIdx.x == 0) {
    int votes = 0;
    for (int i = 0; i < 16; i++) {
      uint32_t lo = w[i] & 0xFFFFu;
      uint32_t e = (lo >> 7) & 0xFFu;
      if (e >= 0x70u && e < 0x80u) votes++;
    }
    *flag = (votes >= 12) ? 0 : 1;
  }
}

// Pack W into MFMA B-fragment order (bf16).
__global__ void pack_w_kernel(const void* __restrict__ W, const int* __restrict__ flagp,
                              int realK, int Kpad, int M, int Wld, int wcol0,
                              int srow0, float sscale, bf16* __restrict__ out) {
  int idx = blockIdx.x * 256 + threadIdx.x;
  if (idx >= Kpad * M) return;
  int j = idx & 7;
  int lane = (idx >> 3) & 63;
  int t = idx >> 9;
  int MT = M / 16;
  int kt = t / MT, nt = t - kt * MT;
  int k = kt * 32 + (lane >> 4) * 8 + j;
  int n = nt * 16 + (lane & 15);
  float v = 0.0f;
  if (k < realK) {
    v = wload(W, (size_t)k * Wld + wcol0 + n, *flagp);
    if (k >= srow0) v *= sscale;
  }
  out[idx] = f2b(v);
}

__global__ void count_deg_kernel(const int* __restrict__ lit, int* __restrict__ deg) {
  int e = blockIdx.x * 256 + threadIdx.x;
  if (e < E_N) atomicAdd(&deg[lit[e]], 1);
}

__global__ void hist32_kernel(const int* __restrict__ gid, int n, int* __restrict__ out) {
  __shared__ int bins[NGR];
  int t = threadIdx.x;
  if (t < NGR) bins[t] = 0;
  __syncthreads();
  int i = blockIdx.x * 256 + t;
  if (i < n) atomicAdd(&bins[gid[i]], 1);
  __syncthreads();
  if (t < NGR && bins[t] > 0) atomicAdd(&out[t], bins[t]);
}

__global__ void weights_kernel(const int* __restrict__ deg,
                               float* __restrict__ dw, float* __restrict__ vdw) {
  int l = blockIdx.x * 256 + threadIdx.x;
  if (l < L_N) dw[l] = rsqrtf(fmaxf((float)deg[l], 1.0f));
  if (l < V_N) vdw[l] = 4.0f * rsqrtf(fmaxf((float)(deg[l] + deg[l + V_N]), 1.0f));
}

// single-block exclusive scan of L_N degrees -> offs[L_N+1]
__global__ void scan_kernel(const int* __restrict__ deg, int* __restrict__ offs) {
  __shared__ int part[256];
  __shared__ int base[257];
  int t = threadIdx.x;
  const int CH = (L_N + 255) / 256;
  int i0 = t * CH, i1 = min(L_N, i0 + CH);
  int s = 0;
  for (int i = i0; i < i1; i++) s += deg[i];
  part[t] = s;
  __syncthreads();
  if (t == 0) {
    int acc = 0;
    for (int j = 0; j < 256; j++) { base[j] = acc; acc += part[j]; }
    base[256] = acc;
  }
  __syncthreads();
  int acc = base[t];
  for (int i = i0; i < i1; i++) { offs[i] = acc; acc += deg[i]; }
  if (t == 255) offs[L_N] = base[256];
}

__global__ void csr_fill_kernel(const int* __restrict__ lit,
                                const int* __restrict__ offs, int* __restrict__ cursor,
                                int* __restrict__ csr) {
  int e = blockIdx.x * 256 + threadIdx.x;
  if (e < E_N) {
    int l = lit[e];
    int p = atomicAdd(&cursor[l], 1);
    csr[offs[l] + p] = e / 3;
  }
}

// per-round: write only the 4 real noise columns (pad zeroed once at setup)
__global__ void noise4_kernel(bf16* __restrict__ Zb, uint32_t ka, uint32_t kb) {
  int idx = blockIdx.x * 256 + threadIdx.x;
  if (idx >= V_N * 4) return;
  int v = idx >> 2, j = idx & 3;
  Zb[(size_t)v * 32 + j] = f2b(normal_from_bits(part_bits(ka, kb, (uint32_t)idx)));
}

// ---------------------------------------------------------------------------
// Fused MLP kernels (MFMA). 256 thr = 4 waves; wave w owns 16 rows.
// ---------------------------------------------------------------------------

// vq: Q = (relu([variables|Z] @ W0 + b0)) @ W1 + b1; also SP tables.
__global__ __launch_bounds__(256) void vq_fused_kernel(
    const bf16* __restrict__ variables, const bf16* __restrict__ Zb,
    const bf16* __restrict__ W0p, const void* __restrict__ b0,
    const bf16* __restrict__ W1p, const void* __restrict__ b1,
    const int* __restrict__ flagp, bf16* __restrict__ Q,
    bf16* __restrict__ SP, int N) {
  __shared__ bf16 hs[64][72];
  int tid = threadIdx.x;
  int wave = tid >> 6, lane = tid & 63, quad = lane >> 4, m16 = lane & 15;
  int row = blockIdx.x * 64 + wave * 16 + m16;
  int rowc = min(row, N - 1);
  int isf32 = *flagp;
  float4v acc[4];
#pragma unroll
  for (int nt = 0; nt < 4; nt++) acc[nt] = (float4v){0.f, 0.f, 0.f, 0.f};
  const short8* w0 = (const short8*)W0p;
  for (int k0 = 0; k0 < 96; k0 += 32) {
    int ks = k0 + quad * 8;
    const bf16* src = (ks < 64) ? variables + (size_t)rowc * 64 + ks
                                : Zb + (size_t)rowc * 32 + (ks - 64);
    short8 a = *(const short8*)src;
#pragma unroll
    for (int nt = 0; nt < 4; nt++) {
      short8 b = w0[((k0 >> 5) * 4 + nt) * 64 + lane];
      acc[nt] = __builtin_amdgcn_mfma_f32_16x16x32_bf16(a, b, acc[nt], 0, 0, 0);
    }
  }
  int rl = wave * 16 + quad * 4;
#pragma unroll
  for (int nt = 0; nt < 4; nt++) {
    int col = nt * 16 + m16;
    float bv = wload(b0, col, isf32);
#pragma unroll
    for (int i = 0; i < 4; i++)
      hs[rl + i][col] = f2b(fmaxf(acc[nt][i] + bv, 0.0f));
  }
  __syncthreads();
  float4v acc2[4];
#pragma unroll
  for (int nt = 0; nt < 4; nt++) acc2[nt] = (float4v){0.f, 0.f, 0.f, 0.f};
  const short8* w1 = (const short8*)W1p;
  for (int k0 = 0; k0 < 64; k0 += 32) {
    short8 a = *(const short8*)&hs[wave * 16 + m16][k0 + quad * 8];
#pragma unroll
    for (int nt = 0; nt < 4; nt++) {
      short8 b = w1[((k0 >> 5) * 4 + nt) * 64 + lane];
      acc2[nt] = __builtin_amdgcn_mfma_f32_16x16x32_bf16(a, b, acc2[nt], 0, 0, 0);
    }
  }
  int rbase = blockIdx.x * 64 + wave * 16 + quad * 4;
#pragma unroll
  for (int nt = 0; nt < 4; nt++) {
    int col = nt * 16 + m16;
    float bv = wload(b1, col, isf32);
#pragma unroll
    for (int i = 0; i < 4; i++) {
      int r = rbase + i;
      if (r < N) {
        float q = acc2[nt][i] + bv;
        Q[(size_t)r * 64 + col] = f2b(q);
        SP[(size_t)r * 64 + col] = f2b(softplusf(q));
        SP[(size_t)(r + V_N) * 64 + col] = f2b(softplusf(-q));
      }
    }
  }
}

// cm: H = relu([clauses|clb]@W0+b0); D = H@W1+b1; Dl=D[:,:64], Dn=D[:,64:].
__global__ __launch_bounds__(256) void cm_fused_kernel(
    const bf16* __restrict__ clauses, const bf16* __restrict__ clb,
    const bf16* __restrict__ W0p, const void* __restrict__ b0,
    const bf16* __restrict__ W1p, const void* __restrict__ b1,
    const int* __restrict__ flagp,
    bf16* __restrict__ Dl, bf16* __restrict__ Dn, int N) {
  __shared__ bf16 hs[64][136];
  int tid = threadIdx.x;
  int wave = tid >> 6, lane = tid & 63, quad = lane >> 4, m16 = lane & 15;
  int row = blockIdx.x * 64 + wave * 16 + m16;
  int rowc = min(row, N - 1);
  int isf32 = *flagp;
  float4v acc[8];
#pragma unroll
  for (int nt = 0; nt < 8; nt++) acc[nt] = (float4v){0.f, 0.f, 0.f, 0.f};
  const short8* w0 = (const short8*)W0p;
  for (int k0 = 0; k0 < 128; k0 += 32) {
    int ks = k0 + quad * 8;
    const bf16* src = (ks < 64) ? clauses + (size_t)rowc * 64 + ks
                                : clb + (size_t)rowc * 64 + (ks - 64);
    short8 a = *(const short8*)src;
#pragma unroll
    for (int nt = 0; nt < 8; nt++) {
      short8 b = w0[((k0 >> 5) * 8 + nt) * 64 + lane];
      acc[nt] = __builtin_amdgcn_mfma_f32_16x16x32_bf16(a, b, acc[nt], 0, 0, 0);
    }
  }
  int rl = wave * 16 + quad * 4;
#pragma unroll
  for (int nt = 0; nt < 8; nt++) {
    int col = nt * 16 + m16;
    float bv = wload(b0, col, isf32);
#pragma unroll
    for (int i = 0; i < 4; i++)
      hs[rl + i][col] = f2b(fmaxf(acc[nt][i] + bv, 0.0f));
  }
  __syncthreads();
#pragma unroll
  for (int nt = 0; nt < 8; nt++) acc[nt] = (float4v){0.f, 0.f, 0.f, 0.f};
  const short8* w1 = (const short8*)W1p;
  for (int k0 = 0; k0 < 128; k0 += 32) {
    short8 a = *(const short8*)&hs[wave * 16 + m16][k0 + quad * 8];
#pragma unroll
    for (int nt = 0; nt < 8; nt++) {
      short8 b = w1[((k0 >> 5) * 8 + nt) * 64 + lane];
      acc[nt] = __builtin_amdgcn_mfma_f32_16x16x32_bf16(a, b, acc[nt], 0, 0, 0);
    }
  }
  int rbase = blockIdx.x * 64 + wave * 16 + quad * 4;
#pragma unroll
  for (int nt = 0; nt < 8; nt++) {
    int col = nt * 16 + m16;
    float bv = wload(b1, col, isf32);
#pragma unroll
    for (int i = 0; i < 4; i++) {
      int r = rbase + i;
      if (r < N) {
        float v = acc[nt][i] + bv;
        if (col < 64) Dl[(size_t)r * 64 + col] = f2b(v);
        else          Dn[(size_t)r * 64 + (col - 64)] = f2b(v);
      }
    }
  }
}

// ug: 3-layer MLP [QG|variables|VLb](K=256) ->128 ->128 ->64, NV f32 out.
__global__ __launch_bounds__(256) void ug_fused_kernel(
    const bf16* __restrict__ QG, const bf16* __restrict__ variables,
    const bf16* __restrict__ VLb,
    const bf16* __restrict__ W0p, const void* __restrict__ b0,
    const bf16* __restrict__ W1p, const void* __restrict__ b1,
    const bf16* __restrict__ W2p, const void* __restrict__ b2,
    const int* __restrict__ flagp, float* __restrict__ NV, int N) {
  __shared__ bf16 h1[64][136];
  __shared__ bf16 h2[64][136];
  int tid = threadIdx.x;
  int wave = tid >> 6, lane = tid & 63, quad = lane >> 4, m16 = lane & 15;
  int row = blockIdx.x * 64 + wave * 16 + m16;
  int rowc = min(row, N - 1);
  int isf32 = *flagp;
  int rl = wave * 16 + quad * 4;
  float4v acc[8];
#pragma unroll
  for (int nt = 0; nt < 8; nt++) acc[nt] = (float4v){0.f, 0.f, 0.f, 0.f};
  const short8* w0 = (const short8*)W0p;
  for (int k0 = 0; k0 < 256; k0 += 32) {
    int ks = k0 + quad * 8;
    const bf16* src;
    if (ks < 64)       src = QG + (size_t)rowc * 64 + ks;
    else if (ks < 128) src = variables + (size_t)rowc * 64 + (ks - 64);
    else               src = VLb + (size_t)rowc * 128 + (ks - 128);
    short8 a = *(const short8*)src;
#pragma unroll
    for (int nt = 0; nt < 8; nt++) {
      short8 b = w0[((k0 >> 5) * 8 + nt) * 64 + lane];
      acc[nt] = __builtin_amdgcn_mfma_f32_16x16x32_bf16(a, b, acc[nt], 0, 0, 0);
    }
  }
#pragma unroll
  for (int nt = 0; nt < 8; nt++) {
    int col = nt * 16 + m16;
    float bv = wload(b0, col, isf32);
#pragma unroll
    for (int i = 0; i < 4; i++)
      h1[rl + i][col] = f2b(fmaxf(acc[nt][i] + bv, 0.0f));
  }
  __syncthreads();
#pragma unroll
  for (int nt = 0; nt < 8; nt++) acc[nt] = (float4v){0.f, 0.f, 0.f, 0.f};
  const short8* w1 = (const short8*)W1p;
  for (int k0 = 0; k0 < 128; k0 += 32) {
    short8 a = *(const short8*)&h1[wave * 16 + m16][k0 + quad * 8];
#pragma unroll
    for (int nt = 0; nt < 8; nt++) {
      short8 b = w1[((k0 >> 5) * 8 + nt) * 64 + lane];
      acc[nt] = __builtin_amdgcn_mfma_f32_16x16x32_bf16(a, b, acc[nt], 0, 0, 0);
    }
  }
#pragma unroll
  for (int nt = 0; nt < 8; nt++) {
    int col = nt * 16 + m16;
    float bv = wload(b1, col, isf32);
#pragma unroll
    for (int i = 0; i < 4; i++)
      h2[rl + i][col] = f2b(fmaxf(acc[nt][i] + bv, 0.0f));
  }
  __syncthreads();
  float4v acc3[4];
#pragma unroll
  for (int nt = 0; nt < 4; nt++) acc3[nt] = (float4v){0.f, 0.f, 0.f, 0.f};
  const short8* w2 = (const short8*)W2p;
  for (int k0 = 0; k0 < 128; k0 += 32) {
    short8 a = *(const short8*)&h2[wave * 16 + m16][k0 + quad * 8];
#pragma unroll
    for (int nt = 0; nt < 4; nt++) {
      short8 b = w2[((k0 >> 5) * 4 + nt) * 64 + lane];
      acc3[nt] = __builtin_amdgcn_mfma_f32_16x16x32_bf16(a, b, acc3[nt], 0, 0, 0);
    }
  }
  int rbase = blockIdx.x * 64 + wave * 16 + quad * 4;
#pragma unroll
  for (int nt = 0; nt < 4; nt++) {
    int col = nt * 16 + m16;
    float bv = wload(b2, col, isf32);
#pragma unroll
    for (int i = 0; i < 4; i++) {
      int r = rbase + i;
      if (r < N) NV[(size_t)r * 64 + col] = acc3[nt][i] + bv;
    }
  }
}

// ---------------------------------------------------------------------------
// Vectorized edge / node kernels: 8 lanes per row, short8 (16B) per lane.
// ---------------------------------------------------------------------------
// cl: cv = sum of 3 SP rows; cl = exp(-cv). Block 0 zeros pairnorm stats.
__global__ void cl_kernel(const bf16* __restrict__ SP, const int* __restrict__ lit,
                          bf16* __restrict__ cl, float* __restrict__ stats) {
  if (blockIdx.x == 0) {
    for (int i = threadIdx.x; i < 4096; i += 256) stats[i] = 0.0f;
  }
  int t = blockIdx.x * 256 + threadIdx.x;
  int c = t >> 3, j = t & 7;
  if (c >= C_N) return;
  int l0 = lit[3 * c], l1 = lit[3 * c + 1], l2 = lit[3 * c + 2];
  short8 s0 = *(const short8*)&SP[(size_t)l0 * 64 + j * 8];
  short8 s1 = *(const short8*)&SP[(size_t)l1 * 64 + j * 8];
  short8 s2 = *(const short8*)&SP[(size_t)l2 * 64 + j * 8];
  short8 r;
#pragma unroll
  for (int e = 0; e < 8; e++) {
    float cv = sb2f(s0[e]) + sb2f(s1[e]) + sb2f(s2[e]);
    r[e] = f2sb(expf(-cv));
  }
  *(short8*)&cl[(size_t)c * 64 + j * 8] = r;
}

// qgrad: CSR gather of clb over both polarities + gradient combine.
__global__ void qgrad_kernel(const bf16* __restrict__ Q, const bf16* __restrict__ clb,
                             const int* __restrict__ csr, const int* __restrict__ offs,
                             const float* __restrict__ vdw, bf16* __restrict__ QG) {
  int t = blockIdx.x * 256 + threadIdx.x;
  int v = t >> 3, j = t & 7;
  if (v >= V_N) return;
  float gp[8], gn[8];
#pragma unroll
  for (int e = 0; e < 8; e++) { gp[e] = 0.0f; gn[e] = 0.0f; }
  int p0 = offs[v], p1 = offs[v + 1];
  for (int p = p0; p < p1; p++) {
    short8 x = *(const short8*)&clb[(size_t)csr[p] * 64 + j * 8];
#pragma unroll
    for (int e = 0; e < 8; e++) gp[e] += sb2f(x[e]);
  }
  p0 = offs[v + V_N]; p1 = offs[v + V_N + 1];
  for (int p = p0; p < p1; p++) {
    short8 x = *(const short8*)&clb[(size_t)csr[p] * 64 + j * 8];
#pragma unroll
    for (int e = 0; e < 8; e++) gn[e] += sb2f(x[e]);
  }
  short8 qv = *(const short8*)&Q[(size_t)v * 64 + j * 8];
  float w = vdw[v];
  short8 r;
#pragma unroll
  for (int e = 0; e < 8; e++) {
    float q = sb2f(qv[e]);
    float sp = 1.0f / (1.0f + expf(-q));
    float sn = 1.0f / (1.0f + expf(q));
    r[e] = f2sb((-sp * gp[e] + sn * gn[e]) * w);
  }
  *(short8*)&QG[(size_t)v * 64 + j * 8] = r;
}

// VLb via CSR gather of Dl; block 0 zeros stats for variable pairnorm.
__global__ void vlb_gather_kernel(const bf16* __restrict__ Dl, const int* __restrict__ csr,
                                  const int* __restrict__ offs, const float* __restrict__ dw,
                                  bf16* __restrict__ VLb, float* __restrict__ stats) {
  if (blockIdx.x == 0) {
    for (int i = threadIdx.x; i < 4096; i += 256) stats[i] = 0.0f;
  }
  int t = blockIdx.x * 256 + threadIdx.x;
  int l = t >> 3, j = t & 7;
  if (l >= L_N) return;
  float s[8];
#pragma unroll
  for (int e = 0; e < 8; e++) s[e] = 0.0f;
  int p0 = offs[l], p1 = offs[l + 1];
  for (int p = p0; p < p1; p++) {
    short8 x = *(const short8*)&Dl[(size_t)csr[p] * 64 + j * 8];
#pragma unroll
    for (int e = 0; e < 8; e++) s[e] += sb2f(x[e]);
  }
  float w = dw[l];
  size_t v = (l < V_N) ? (size_t)l : (size_t)(l - V_N);
  int col = (l < V_N) ? 0 : 64;
  short8 r;
#pragma unroll
  for (int e = 0; e < 8; e++) r[e] = f2sb(s[e] * w);
  *(short8*)&VLb[v * 128 + col + j * 8] = r;
}

// ---------------------------------------------------------------------------
// PairNorm — vectorized one-pass stats + apply.
// ---------------------------------------------------------------------------
// 8 rows per wave-iteration; lane = sub*8 + j; lane accumulates features j*8..+7
template<typename TX>
__global__ void pn_stats_kernel(const TX* __restrict__ X,
                                const int* __restrict__ gid, int n,
                                float* __restrict__ S1, float* __restrict__ S2) {
  int wave = blockIdx.x * blockDim.y + threadIdx.y;
  int nw = gridDim.x * blockDim.y;
  int chunk = (n + nw - 1) / nw;
  int i0 = wave * chunk;
  if (i0 >= n) return;
  int i1 = min(n, i0 + chunk);
  int lane = threadIdx.x;
  int sub = lane >> 3, j = lane & 7;
  float a1[8], a2[8];
#pragma unroll
  for (int e = 0; e < 8; e++) { a1[e] = 0.0f; a2[e] = 0.0f; }
  int ifirst = i0 + sub;
  if (ifirst >= i1) return;
  int g = gid[ifirst];
  for (int i = ifirst; i < i1; i += 8) {
    int gi = gid[i];
    if (gi != g) {
#pragma unroll
      for (int e = 0; e < 8; e++) {
        atomicAdd(&S1[g * 64 + j * 8 + e], a1[e]);
        atomicAdd(&S2[g * 64 + j * 8 + e], a2[e]);
        a1[e] = 0.0f; a2[e] = 0.0f;
      }
      g = gi;
    }
    float x[8];
    load8(&X[(size_t)i * 64 + j * 8], x);
#pragma unroll
    for (int e = 0; e < 8; e++) { a1[e] += x[e]; a2[e] += x[e] * x[e]; }
  }
#pragma unroll
  for (int e = 0; e < 8; e++) {
    atomicAdd(&S1[g * 64 + j * 8 + e], a1[e]);
    atomicAdd(&S2[g * 64 + j * 8 + e], a2[e]);
  }
}

// state = (pairnorm(X)*0.25 + 0.1*state) * post ; var computed inline
template<typename TX>
__global__ void pn_apply_kernel(const TX* __restrict__ X,
                                const int* __restrict__ gid, int n,
                                const int* __restrict__ cnt, const float* __restrict__ S1,
                                const float* __restrict__ S2, bf16* __restrict__ state,
                                float post) {
  int t = blockIdx.x * 256 + threadIdx.x;
  int i = t >> 3, j = t & 7;
  if (i >= n) return;
  int g = gid[i];
  float c = fmaxf((float)cnt[g], 1.0f);
  float m[8], tv = 0.0f;
#pragma unroll
  for (int e = 0; e < 8; e++) {
    m[e] = S1[g * 64 + j * 8 + e] / c;
    tv += S2[g * 64 + j * 8 + e] / c - m[e] * m[e];
  }
#pragma unroll
  for (int o = 1; o < 8; o <<= 1) tv += __shfl_xor(tv, o);
  float var = fmaxf(tv, 0.0f) * (1.0f / 64.0f);
  float rs = rsqrtf(var + 1e-6f);
  float x[8];
  load8(&X[(size_t)i * 64 + j * 8], x);
  short8 st = *(const short8*)&state[(size_t)i * 64 + j * 8];
  short8 r;
#pragma unroll
  for (int e = 0; e < 8; e++) {
    float xn = (x[e] - m[e]) * rs;
    r[e] = f2sb((xn * 0.25f + 0.1f * sb2f(st[e])) * post);
  }
  *(short8*)&state[(size_t)i * 64 + j * 8] = r;
}

// MFMA co MLP + noise + sigmoid. 64 rows/block; col-reduce via 16-lane shfl.
__global__ __launch_bounds__(256) void co_final_kernel(
    const bf16* __restrict__ clauses, const bf16* __restrict__ W0p,
    const void* __restrict__ b0, const void* __restrict__ W1,
    const void* __restrict__ b1, const int* __restrict__ flagp,
    uint32_t ka, uint32_t kb, float* __restrict__ out) {
  int tid = threadIdx.x;
  int wave = tid >> 6, lane = tid & 63, quad = lane >> 4, m16 = lane & 15;
  int row = blockIdx.x * 64 + wave * 16 + m16;
  int rowc = min(row, C_N - 1);
  int isf32 = *flagp;
  float4v acc[4];
#pragma unroll
  for (int nt = 0; nt < 4; nt++) acc[nt] = (float4v){0.f, 0.f, 0.f, 0.f};
  const short8* w0 = (const short8*)W0p;
  for (int k0 = 0; k0 < 64; k0 += 32) {
    short8 a = *(const short8*)&clauses[(size_t)rowc * 64 + k0 + quad * 8];
#pragma unroll
    for (int nt = 0; nt < 4; nt++) {
      short8 b = w0[((k0 >> 5) * 4 + nt) * 64 + lane];
      acc[nt] = __builtin_amdgcn_mfma_f32_16x16x32_bf16(a, b, acc[nt], 0, 0, 0);
    }
  }
  float s[4] = {0.f, 0.f, 0.f, 0.f};
#pragma unroll
  for (int nt = 0; nt < 4; nt++) {
    int col = nt * 16 + m16;
    float bv = wload(b0, col, isf32);
    float w1v = wload(W1, col, isf32);
#pragma unroll
    for (int i = 0; i < 4; i++) s[i] += fmaxf(acc[nt][i] + bv, 0.0f) * w1v;
  }
#pragma unroll
  for (int o = 1; o < 16; o <<= 1) {
#pragma unroll
    for (int i = 0; i < 4; i++) s[i] += __shfl_xor(s[i], o);
  }
  if (m16 == 0) {
    int rbase = blockIdx.x * 64 + wave * 16 + quad * 4;
    float bb = wload(b1, 0, isf32);
#pragma unroll
    for (int i = 0; i < 4; i++) {
      int r = rbase + i;
      if (r < C_N) {
        float lg = s[i] + bb + normal_from_bits(part_bits(ka, kb, (uint32_t)r));
        out[r] = 1.0f / (1.0f + expf(-lg));
      }
    }
  }
}

// ---------------------------------------------------------------------------
// Launch
// ---------------------------------------------------------------------------
extern "C" void kernel_launch(void* const* d_in, const int* in_sizes, int n_in,
                              void* d_out, int out_size, void* d_ws, size_t ws_size,
                              hipStream_t stream) {
  (void)in_sizes; (void)n_in; (void)out_size;
  const int* lit_idx    = (const int*)d_in[0];
  const int* var_gid    = (const int*)d_in[2];
  const int* clause_gid = (const int*)d_in[3];
  const void* vq_W0 = d_in[4];
  const void* vq_b0 = d_in[5];
  const void* vq_W1 = d_in[6];
  const void* vq_b1 = d_in[7];
  const void* cm_W0 = d_in[8];
  const void* cm_b0 = d_in[9];
  const void* cm_W1 = d_in[10];
  const void* cm_b1 = d_in[11];
  const void* ug_W0 = d_in[12];
  const void* ug_b0 = d_in[13];
  const void* ug_W1 = d_in[14];
  const void* ug_b1 = d_in[15];
  const void* ug_W2 = d_in[16];
  const void* ug_b2 = d_in[17];
  const void* co_W0 = d_in[18];
  const void* co_b0 = d_in[19];
  const void* co_W1 = d_in[20];
  const void* co_b1 = d_in[21];
  float* out = (float*)d_out;

  // ---- workspace layout (~216 MB peak) ----
  char* ws = (char*)d_ws;
  size_t off = 0;
  auto alloc = [&](size_t bytes) -> void* {
    void* p = ws + off;
    off = (off + bytes + 255) & ~(size_t)255;
    return p;
  };
  bf16* variables = (bf16*)alloc((size_t)V_N * 64 * 2);   // persistent state
  bf16* clauses   = (bf16*)alloc((size_t)C_N * 64 * 2);   // persistent state
  // ZE (C*64*2): clb -> Dn (in-place overlay in cm_fused) -> VLb (V*128)
  char* ZE        = (char*)alloc((size_t)C_N * 64 * 2);
  // ZD (C*64*2): SP (L*64) -> Dl (C*64) -> NV f32 (V*64)
  char* ZD        = (char*)alloc((size_t)C_N * 64 * 2);
  bf16* QG        = (bf16*)alloc((size_t)V_N * 64 * 2);
  bf16* Q         = (bf16*)alloc((size_t)V_N * 64 * 2);
  bf16* Zb        = (bf16*)alloc((size_t)V_N * 32 * 2);
  int*  izone     = (int*)alloc((size_t)(2 * L_N + 64) * 4);
  int*  offs      = (int*)alloc((size_t)(L_N + 1) * 4);
  int*  csr       = (int*)alloc((size_t)E_N * 4);
  float* deg_f    = (float*)alloc((size_t)L_N * 4);
  float* vdw      = (float*)alloc((size_t)V_N * 4);
  float* stats    = (float*)alloc((size_t)4096 * 4);
  int*   wflag    = (int*)alloc(256);
  // packed MFMA weights (bf16)
  bf16* vq_W0p = (bf16*)alloc((size_t)96 * 64 * 2);
  bf16* vq_W1p = (bf16*)alloc((size_t)64 * 64 * 2);
  bf16* cm_W0p = (bf16*)alloc((size_t)128 * 128 * 2);
  bf16* cm_W1p = (bf16*)alloc((size_t)128 * 128 * 2);
  bf16* ug_W0p = (bf16*)alloc((size_t)256 * 128 * 2);
  bf16* ug_W1p = (bf16*)alloc((size_t)128 * 128 * 2);
  bf16* ug_W2p = (bf16*)alloc((size_t)128 * 64 * 2);
  bf16* co_W0p = (bf16*)alloc((size_t)64 * 64 * 2);
  size_t need = off;

  auto nb = [](int n, int per) { return (n + per - 1) / per; };

  if (ws_size < need) {
    fill_f32<<<nb(C_N, 256), 256, 0, stream>>>(out, (size_t)C_N, 0.5f);
    return;
  }

  bf16* clb = (bf16*)ZE;                 // C x 64
  bf16* Dn  = (bf16*)ZE;                 // C x 64 (in-place overlay)
  bf16* VLb = (bf16*)ZE;                 // V x 128 (after Dn consumed)
  bf16* SP  = (bf16*)ZD;                 // L x 64 (vq -> cl; dead before Dl)
  bf16* Dl  = (bf16*)ZD;                 // C x 64 (cm -> vlb_gather)
  float* NV = (float*)ZD;                // V x 64 f32 (after Dl consumed)

  int* deg_i  = izone;
  int* cursor = izone + L_N;
  int* cntv   = izone + 2 * L_N;
  int* cntc   = cntv + 32;
  float* S1 = stats;              // 32 x 64
  float* S2 = stats + 2048;       // 32 x 64

  // JAX keys = split(key(42), 9), partitionable: subkey_i = threefry(key,0,i)
  uint32_t kw0[9], kw1[9];
  for (int i = 0; i < 9; i++) tf2x32(0u, 42u, 0u, (uint32_t)i, &kw0[i], &kw1[i]);

  dim3 wb(64, 4);
  const int BIG = 1 << 30;

  // ---- setup (re-done every call) ----
  detect_dtype_kernel<<<1, 64, 0, stream>>>((const uint32_t*)vq_W0, wflag);
  fill_u32<<<nb(2 * L_N + 64, 256), 256, 0, stream>>>((uint32_t*)izone, (size_t)(2 * L_N + 64), 0u);
  count_deg_kernel<<<nb(E_N, 256), 256, 0, stream>>>(lit_idx, deg_i);
  hist32_kernel<<<nb(V_N, 256), 256, 0, stream>>>(var_gid, V_N, cntv);
  hist32_kernel<<<nb(C_N, 256), 256, 0, stream>>>(clause_gid, C_N, cntc);
  weights_kernel<<<nb(L_N, 256), 256, 0, stream>>>(deg_i, deg_f, vdw);
  scan_kernel<<<1, 256, 0, stream>>>(deg_i, offs);
  csr_fill_kernel<<<nb(E_N, 256), 256, 0, stream>>>(lit_idx, offs, cursor, csr);
  fill_b16<<<2048, 256, 0, stream>>>(variables, (size_t)V_N * 64, 1.0f);
  fill_b16<<<2048, 256, 0, stream>>>(clauses, (size_t)C_N * 64, 1.0f);
  fill_b16<<<2048, 256, 0, stream>>>(Zb, (size_t)V_N * 32, 0.0f);
  // pack weights into MFMA B-fragment order
  pack_w_kernel<<<nb(96 * 64, 256), 256, 0, stream>>>(vq_W0, wflag, 68, 96, 64, 64, 0, BIG, 1.f, vq_W0p);
  pack_w_kernel<<<nb(64 * 64, 256), 256, 0, stream>>>(vq_W1, wflag, 64, 64, 64, 64, 0, BIG, 1.f, vq_W1p);
  pack_w_kernel<<<nb(128 * 128, 256), 256, 0, stream>>>(cm_W0, wflag, 128, 128, 128, 128, 0, 64, 4.f, cm_W0p);
  pack_w_kernel<<<nb(128 * 128, 256), 256, 0, stream>>>(cm_W1, wflag, 128, 128, 128, 128, 0, BIG, 1.f, cm_W1p);
  pack_w_kernel<<<nb(256 * 128, 256), 256, 0, stream>>>(ug_W0, wflag, 256, 256, 128, 128, 0, BIG, 1.f, ug_W0p);
  pack_w_kernel<<<nb(128 * 128, 256), 256, 0, stream>>>(ug_W1, wflag, 128, 128, 128, 128, 0, BIG, 1.f, ug_W1p);
  pack_w_kernel<<<nb(128 * 64, 256), 256, 0, stream>>>(ug_W2, wflag, 128, 128, 64, 64, 0, BIG, 1.f, ug_W2p);
  pack_w_kernel<<<nb(64 * 64, 256), 256, 0, stream>>>(co_W0, wflag, 64, 64, 64, 64, 0, BIG, 1.f, co_W0p);

  // ---- rounds (11 launches each) ----
  for (int r = 0; r < NROUNDS; r++) {
    noise4_kernel<<<nb(V_N * 4, 256), 256, 0, stream>>>(Zb, kw0[r], kw1[r]);
    vq_fused_kernel<<<nb(V_N, 64), 256, 0, stream>>>(
        variables, Zb, vq_W0p, vq_b0, vq_W1p, vq_b1, wflag, Q, SP, V_N);
    cl_kernel<<<nb(C_N * 8, 256), 256, 0, stream>>>(SP, lit_idx, clb, stats);
    qgrad_kernel<<<nb(V_N * 8, 256), 256, 0, stream>>>(Q, clb, csr, offs, vdw, QG);
    cm_fused_kernel<<<nb(C_N, 64), 256, 0, stream>>>(
        clauses, clb, cm_W0p, cm_b0, cm_W1p, cm_b1, wflag, Dl, Dn, C_N);
    pn_stats_kernel<bf16><<<128, wb, 0, stream>>>(Dn, clause_gid, C_N, S1, S2);
    pn_apply_kernel<bf16><<<nb(C_N * 8, 256), 256, 0, stream>>>(
        Dn, clause_gid, C_N, cntc, S1, S2, clauses, (r == NROUNDS - 1) ? 1.0f : 0.2f);
    vlb_gather_kernel<<<nb(L_N * 8, 256), 256, 0, stream>>>(Dl, csr, offs, deg_f, VLb, stats);
    ug_fused_kernel<<<nb(V_N, 64), 256, 0, stream>>>(
        QG, variables, VLb, ug_W0p, ug_b0, ug_W1p, ug_b1, ug_W2p, ug_b2,
        wflag, NV, V_N);
    pn_stats_kernel<float><<<128, wb, 0, stream>>>(NV, var_gid, V_N, S1, S2);
    pn_apply_kernel<float><<<nb(V_N * 8, 256), 256, 0, stream>>>(
        NV, var_gid, V_N, cntv, S1, S2, variables, 1.0f);
  }
  co_final_kernel<<<nb(C_N, 64), 256, 0, stream>>>(
      clauses, co_W0p, co_b0, co_W1, co_b1, wflag, kw0[8], kw1[8], out);
}

// Round 14
// 4606.620 us; speedup vs baseline: 5.0674x; 1.0618x over previous
//
#include <hip/hip_runtime.h>
#include <hip/hip_bf16.h>
#include <cstdint>
#include <cstddef>

// ---------------------------------------------------------------------------
// Problem constants
// ---------------------------------------------------------------------------
constexpr int V_N = 100000;   // variables
constexpr int C_N = 420000;   // clauses
constexpr int L_N = 2 * V_N;  // literals
constexpr int E_N = 3 * C_N;  // nnz edges
constexpr int NGR = 32;       // graphs
constexpr int NROUNDS = 8;
constexpr int SCAN_NB = (L_N + 255) / 256;   // 782 scan blocks

using bf16 = __hip_bfloat16;
typedef __attribute__((ext_vector_type(8))) short short8;   // 8 bf16 (4 VGPRs)
typedef __attribute__((ext_vector_type(4))) float float4v;  // 4 fp32 acc

__device__ inline float b2f(bf16 h) { return __bfloat162float(h); }
__device__ inline bf16 f2b(float f) { return __float2bfloat16(f); }
__device__ inline float sb2f(short s) { return __uint_as_float(((uint32_t)(uint16_t)s) << 16); }
__device__ inline short f2sb(float f) { bf16 h = f2b(f); return *(short*)&h; }

template<typename T> __device__ inline float loadT(const T* p);
template<> __device__ inline float loadT<float>(const float* p) { return *p; }
template<> __device__ inline float loadT<bf16>(const bf16* p) { return b2f(*p); }

// load 8 consecutive values as f32
template<typename TX> __device__ inline void load8(const TX* p, float* v);
template<> __device__ inline void load8<bf16>(const bf16* p, float* v) {
  short8 s = *(const short8*)p;
#pragma unroll
  for (int e = 0; e < 8; e++) v[e] = sb2f(s[e]);
}
template<> __device__ inline void load8<float>(const float* p, float* v) {
  float4 a = *(const float4*)p;
  float4 b = *(const float4*)(p + 4);
  v[0] = a.x; v[1] = a.y; v[2] = a.z; v[3] = a.w;
  v[4] = b.x; v[5] = b.y; v[6] = b.z; v[7] = b.w;
}

// runtime-dtype weight load: isf32 ? f32 buffer : packed bf16 buffer
__device__ inline float wload(const void* W, size_t idx, int isf32) {
  return isf32 ? ((const float*)W)[idx] : b2f(((const bf16*)W)[idx]);
}

// ---------------------------------------------------------------------------
// Threefry-2x32 (JAX-compatible, partitionable) — host+device
// ---------------------------------------------------------------------------
__host__ __device__ inline void tf2x32(uint32_t k0, uint32_t k1,
                                       uint32_t x0, uint32_t x1,
                                       uint32_t* o0, uint32_t* o1) {
  uint32_t ks2 = k0 ^ k1 ^ 0x1BD11BDAu;
  x0 += k0; x1 += k1;
#define TFR(d) do { x0 += x1; x1 = (x1 << (d)) | (x1 >> (32 - (d))); x1 ^= x0; } while (0)
  TFR(13); TFR(15); TFR(26); TFR(6);
  x0 += k1;  x1 += ks2 + 1u;
  TFR(17); TFR(29); TFR(16); TFR(24);
  x0 += ks2; x1 += k0 + 2u;
  TFR(13); TFR(15); TFR(26); TFR(6);
  x0 += k0;  x1 += k1 + 3u;
  TFR(17); TFR(29); TFR(16); TFR(24);
  x0 += k1;  x1 += ks2 + 4u;
  TFR(13); TFR(15); TFR(26); TFR(6);
  x0 += ks2; x1 += k0 + 5u;
#undef TFR
  *o0 = x0; *o1 = x1;
}

__device__ inline uint32_t part_bits(uint32_t ka, uint32_t kb, uint32_t e) {
  uint32_t h1, h2;
  tf2x32(ka, kb, 0u, e, &h1, &h2);
  return h1 ^ h2;
}

// XLA ErfInv32 polynomial (Giles)
__device__ inline float erfinv_f32(float x) {
  float w = -log1pf(-x * x);
  float p;
  if (w < 5.0f) {
    w -= 2.5f;
    p = 2.81022636e-08f;
    p = fmaf(p, w, 3.43273939e-07f);
    p = fmaf(p, w, -3.5233877e-06f);
    p = fmaf(p, w, -4.39150654e-06f);
    p = fmaf(p, w, 0.00021858087f);
    p = fmaf(p, w, -0.00125372503f);
    p = fmaf(p, w, -0.00417768164f);
    p = fmaf(p, w, 0.246640727f);
    p = fmaf(p, w, 1.50140941f);
  } else {
    w = sqrtf(w) - 3.0f;
    p = -0.000200214257f;
    p = fmaf(p, w, 0.000100950558f);
    p = fmaf(p, w, 0.00134934322f);
    p = fmaf(p, w, -0.00367342844f);
    p = fmaf(p, w, 0.00573950773f);
    p = fmaf(p, w, -0.0076224613f);
    p = fmaf(p, w, 0.00943887047f);
    p = fmaf(p, w, 1.00167406f);
    p = fmaf(p, w, 2.83297682f);
  }
  return p * x;
}

__device__ inline float normal_from_bits(uint32_t bits) {
  float u01 = __uint_as_float((bits >> 9) | 0x3f800000u) - 1.0f;  // [0,1)
  const float lo = -0.99999994f;
  float u = u01 * 2.0f + lo;
  u = fmaxf(lo, u);
  return 1.41421356f * erfinv_f32(u);
}

__device__ inline float softplusf(float x) {
  return (x > 0.0f) ? x + log1pf(expf(-x)) : log1pf(expf(x));
}

// ---------------------------------------------------------------------------
// Utility kernels
// ---------------------------------------------------------------------------
__global__ void fill_f32(float* p, size_t n, float v) {
  size_t i = (size_t)blockIdx.x * blockDim.x + threadIdx.x;
  size_t stride = (size_t)gridDim.x * blockDim.x;
  for (; i < n; i += stride) p[i] = v;
}
__global__ void fill_u32(uint32_t* p, size_t n, uint32_t v) {
  size_t i = (size_t)blockIdx.x * blockDim.x + threadIdx.x;
  size_t stride = (size_t)gridDim.x * blockDim.x;
  for (; i < n; i += stride) p[i] = v;
}
__global__ void fill_b16(bf16* p, size_t n, float v) {
  size_t i = (size_t)blockIdx.x * blockDim.x + threadIdx.x;
  size_t stride = (size_t)gridDim.x * blockDim.x;
  bf16 b = f2b(v);
  for (; i < n; i += stride) p[i] = b;
}

// Detect weight dtype (R8-verified). flag=1 -> f32, flag=0 -> bf16.
__global__ void detect_dtype_kernel(const uint32_t* __restrict__ w, int* __restrict__ flag) {
  if (blockIdx.x == 0 && threadIdx.x == 0) {
    int votes = 0;
    for (int i = 0; i < 16; i++) {
      uint32_t lo = w[i] & 0xFFFFu;
      uint32_t e = (lo >> 7) & 0xFFu;
      if (e >= 0x70u && e < 0x80u) votes++;
    }
    *flag = (votes >= 12) ? 0 : 1;
  }
}

// Pack W into MFMA B-fragment order (bf16).
__global__ void pack_w_kernel(const void* __restrict__ W, const int* __restrict__ flagp,
                              int realK, int Kpad, int M, int Wld, int wcol0,
                              int srow0, float sscale, bf16* __restrict__ out) {
  int idx = blockIdx.x * 256 + threadIdx.x;
  if (idx >= Kpad * M) return;
  int j = idx & 7;
  int lane = (idx >> 3) & 63;
  int t = idx >> 9;
  int MT = M / 16;
  int kt = t / MT, nt = t - kt * MT;
  int k = kt * 32 + (lane >> 4) * 8 + j;
  int n = nt * 16 + (lane & 15);
  float v = 0.0f;
  if (k < realK) {
    v = wload(W, (size_t)k * Wld + wcol0 + n, *flagp);
    if (k >= srow0) v *= sscale;
  }
  out[idx] = f2b(v);
}

__global__ void count_deg_kernel(const int* __restrict__ lit, int* __restrict__ deg) {
  int e = blockIdx.x * 256 + threadIdx.x;
  if (e < E_N) atomicAdd(&deg[lit[e]], 1);
}

__global__ void hist32_kernel(const int* __restrict__ gid, int n, int* __restrict__ out) {
  __shared__ int bins[NGR];
  int t = threadIdx.x;
  if (t < NGR) bins[t] = 0;
  __syncthreads();
  int i = blockIdx.x * 256 + t;
  if (i < n) atomicAdd(&bins[gid[i]], 1);
  __syncthreads();
  if (t < NGR && bins[t] > 0) atomicAdd(&out[t], bins[t]);
}

__global__ void weights_kernel(const int* __restrict__ deg,
                               float* __restrict__ dw, float* __restrict__ vdw) {
  int l = blockIdx.x * 256 + threadIdx.x;
  if (l < L_N) dw[l] = rsqrtf(fmaxf((float)deg[l], 1.0f));
  if (l < V_N) vdw[l] = 4.0f * rsqrtf(fmaxf((float)(deg[l] + deg[l + V_N]), 1.0f));
}

// ---- parallel 3-phase exclusive scan of L_N degrees -> offs[L_N+1] ----
__global__ void scan_partial_kernel(const int* __restrict__ deg, int* __restrict__ part) {
  __shared__ int red[256];
  int b = blockIdx.x, t = threadIdx.x;
  int i = b * 256 + t;
  red[t] = (i < L_N) ? deg[i] : 0;
  __syncthreads();
  for (int o = 128; o > 0; o >>= 1) {
    if (t < o) red[t] += red[t + o];
    __syncthreads();
  }
  if (t == 0) part[b] = red[0];
}

__global__ void scan_base_kernel(const int* __restrict__ part, int* __restrict__ base) {
  __shared__ int buf[SCAN_NB + 1];
  int t = threadIdx.x;
  for (int i = t; i < SCAN_NB; i += 256) buf[i] = part[i];
  __syncthreads();
  if (t == 0) {
    int acc = 0;
    for (int i = 0; i < SCAN_NB; i++) { int v = buf[i]; buf[i] = acc; acc += v; }
    buf[SCAN_NB] = acc;
  }
  __syncthreads();
  for (int i = t; i <= SCAN_NB; i += 256) base[i] = buf[i];
}

__global__ void scan_write_kernel(const int* __restrict__ deg, const int* __restrict__ base,
                                  int* __restrict__ offs) {
  __shared__ int s[256];
  int b = blockIdx.x, t = threadIdx.x;
  int i = b * 256 + t;
  int v = (i < L_N) ? deg[i] : 0;
  s[t] = v;
  __syncthreads();
  for (int o = 1; o < 256; o <<= 1) {
    int x = (t >= o) ? s[t - o] : 0;
    __syncthreads();
    s[t] += x;
    __syncthreads();
  }
  if (i < L_N) offs[i] = base[b] + s[t] - v;   // exclusive
  if (b == 0 && t == 0) offs[L_N] = base[SCAN_NB];
}

__global__ void csr_fill_kernel(const int* __restrict__ lit,
                                const int* __restrict__ offs, int* __restrict__ cursor,
                                int* __restrict__ csr) {
  int e = blockIdx.x * 256 + threadIdx.x;
  if (e < E_N) {
    int l = lit[e];
    int p = atomicAdd(&cursor[l], 1);
    csr[offs[l] + p] = e / 3;
  }
}

// ---------------------------------------------------------------------------
// Fused MLP kernels (MFMA). 256 thr = 4 waves; wave w owns 16 rows.
// ---------------------------------------------------------------------------

// vq: Q = (relu([variables|Z] @ W0 + b0)) @ W1 + b1; also SP tables.
// Z computed INLINE via partitionable threefry (same bf16 rounding as before).
__global__ __launch_bounds__(256) void vq_fused_kernel(
    const bf16* __restrict__ variables,
    const bf16* __restrict__ W0p, const void* __restrict__ b0,
    const bf16* __restrict__ W1p, const void* __restrict__ b1,
    const int* __restrict__ flagp, uint32_t ka, uint32_t kb,
    bf16* __restrict__ Q, bf16* __restrict__ SP, int N) {
  __shared__ bf16 hs[64][72];
  int tid = threadIdx.x;
  int wave = tid >> 6, lane = tid & 63, quad = lane >> 4, m16 = lane & 15;
  int row = blockIdx.x * 64 + wave * 16 + m16;
  int rowc = min(row, N - 1);
  int isf32 = *flagp;
  float4v acc[4];
#pragma unroll
  for (int nt = 0; nt < 4; nt++) acc[nt] = (float4v){0.f, 0.f, 0.f, 0.f};
  const short8* w0 = (const short8*)W0p;
  for (int k0 = 0; k0 < 96; k0 += 32) {
    int ks = k0 + quad * 8;
    short8 a;
    if (ks < 64) {
      a = *(const short8*)(variables + (size_t)rowc * 64 + ks);
    } else if (ks == 64) {
#pragma unroll
      for (int e = 0; e < 8; e++)
        a[e] = (e < 4)
             ? f2sb(normal_from_bits(part_bits(ka, kb, (uint32_t)(rowc * 4 + e))))
             : (short)0;
    } else {
      a = (short8){0, 0, 0, 0, 0, 0, 0, 0};
    }
#pragma unroll
    for (int nt = 0; nt < 4; nt++) {
      short8 b = w0[((k0 >> 5) * 4 + nt) * 64 + lane];
      acc[nt] = __builtin_amdgcn_mfma_f32_16x16x32_bf16(a, b, acc[nt], 0, 0, 0);
    }
  }
  int rl = wave * 16 + quad * 4;
#pragma unroll
  for (int nt = 0; nt < 4; nt++) {
    int col = nt * 16 + m16;
    float bv = wload(b0, col, isf32);
#pragma unroll
    for (int i = 0; i < 4; i++)
      hs[rl + i][col] = f2b(fmaxf(acc[nt][i] + bv, 0.0f));
  }
  __syncthreads();
  float4v acc2[4];
#pragma unroll
  for (int nt = 0; nt < 4; nt++) acc2[nt] = (float4v){0.f, 0.f, 0.f, 0.f};
  const short8* w1 = (const short8*)W1p;
  for (int k0 = 0; k0 < 64; k0 += 32) {
    short8 a = *(const short8*)&hs[wave * 16 + m16][k0 + quad * 8];
#pragma unroll
    for (int nt = 0; nt < 4; nt++) {
      short8 b = w1[((k0 >> 5) * 4 + nt) * 64 + lane];
      acc2[nt] = __builtin_amdgcn_mfma_f32_16x16x32_bf16(a, b, acc2[nt], 0, 0, 0);
    }
  }
  int rbase = blockIdx.x * 64 + wave * 16 + quad * 4;
#pragma unroll
  for (int nt = 0; nt < 4; nt++) {
    int col = nt * 16 + m16;
    float bv = wload(b1, col, isf32);
#pragma unroll
    for (int i = 0; i < 4; i++) {
      int r = rbase + i;
      if (r < N) {
        float q = acc2[nt][i] + bv;
        Q[(size_t)r * 64 + col] = f2b(q);
        SP[(size_t)r * 64 + col] = f2b(softplusf(q));
        SP[(size_t)(r + V_N) * 64 + col] = f2b(softplusf(-q));
      }
    }
  }
}

// cm: H = relu([clauses|clb]@W0+b0); D = H@W1+b1; Dl=D[:,:64], Dn=D[:,64:].
__global__ __launch_bounds__(256) void cm_fused_kernel(
    const bf16* __restrict__ clauses, const bf16* __restrict__ clb,
    const bf16* __restrict__ W0p, const void* __restrict__ b0,
    const bf16* __restrict__ W1p, const void* __restrict__ b1,
    const int* __restrict__ flagp,
    bf16* __restrict__ Dl, bf16* __restrict__ Dn, int N) {
  __shared__ bf16 hs[64][136];
  int tid = threadIdx.x;
  int wave = tid >> 6, lane = tid & 63, quad = lane >> 4, m16 = lane & 15;
  int row = blockIdx.x * 64 + wave * 16 + m16;
  int rowc = min(row, N - 1);
  int isf32 = *flagp;
  float4v acc[8];
#pragma unroll
  for (int nt = 0; nt < 8; nt++) acc[nt] = (float4v){0.f, 0.f, 0.f, 0.f};
  const short8* w0 = (const short8*)W0p;
  for (int k0 = 0; k0 < 128; k0 += 32) {
    int ks = k0 + quad * 8;
    const bf16* src = (ks < 64) ? clauses + (size_t)rowc * 64 + ks
                                : clb + (size_t)rowc * 64 + (ks - 64);
    short8 a = *(const short8*)src;
#pragma unroll
    for (int nt = 0; nt < 8; nt++) {
      short8 b = w0[((k0 >> 5) * 8 + nt) * 64 + lane];
      acc[nt] = __builtin_amdgcn_mfma_f32_16x16x32_bf16(a, b, acc[nt], 0, 0, 0);
    }
  }
  int rl = wave * 16 + quad * 4;
#pragma unroll
  for (int nt = 0; nt < 8; nt++) {
    int col = nt * 16 + m16;
    float bv = wload(b0, col, isf32);
#pragma unroll
    for (int i = 0; i < 4; i++)
      hs[rl + i][col] = f2b(fmaxf(acc[nt][i] + bv, 0.0f));
  }
  __syncthreads();
#pragma unroll
  for (int nt = 0; nt < 8; nt++) acc[nt] = (float4v){0.f, 0.f, 0.f, 0.f};
  const short8* w1 = (const short8*)W1p;
  for (int k0 = 0; k0 < 128; k0 += 32) {
    short8 a = *(const short8*)&hs[wave * 16 + m16][k0 + quad * 8];
#pragma unroll
    for (int nt = 0; nt < 8; nt++) {
      short8 b = w1[((k0 >> 5) * 8 + nt) * 64 + lane];
      acc[nt] = __builtin_amdgcn_mfma_f32_16x16x32_bf16(a, b, acc[nt], 0, 0, 0);
    }
  }
  int rbase = blockIdx.x * 64 + wave * 16 + quad * 4;
#pragma unroll
  for (int nt = 0; nt < 8; nt++) {
    int col = nt * 16 + m16;
    float bv = wload(b1, col, isf32);
#pragma unroll
    for (int i = 0; i < 4; i++) {
      int r = rbase + i;
      if (r < N) {
        float v = acc[nt][i] + bv;
        if (col < 64) Dl[(size_t)r * 64 + col] = f2b(v);
        else          Dn[(size_t)r * 64 + (col - 64)] = f2b(v);
      }
    }
  }
}

// ug: 3-layer MLP [QG|variables|VLb](K=256) ->128 ->128 ->64, NV f32 out.
__global__ __launch_bounds__(256) void ug_fused_kernel(
    const bf16* __restrict__ QG, const bf16* __restrict__ variables,
    const bf16* __restrict__ VLb,
    const bf16* __restrict__ W0p, const void* __restrict__ b0,
    const bf16* __restrict__ W1p, const void* __restrict__ b1,
    const bf16* __restrict__ W2p, const void* __restrict__ b2,
    const int* __restrict__ flagp, float* __restrict__ NV, int N) {
  __shared__ bf16 h1[64][136];
  __shared__ bf16 h2[64][136];
  int tid = threadIdx.x;
  int wave = tid >> 6, lane = tid & 63, quad = lane >> 4, m16 = lane & 15;
  int row = blockIdx.x * 64 + wave * 16 + m16;
  int rowc = min(row, N - 1);
  int isf32 = *flagp;
  int rl = wave * 16 + quad * 4;
  float4v acc[8];
#pragma unroll
  for (int nt = 0; nt < 8; nt++) acc[nt] = (float4v){0.f, 0.f, 0.f, 0.f};
  const short8* w0 = (const short8*)W0p;
  for (int k0 = 0; k0 < 256; k0 += 32) {
    int ks = k0 + quad * 8;
    const bf16* src;
    if (ks < 64)       src = QG + (size_t)rowc * 64 + ks;
    else if (ks < 128) src = variables + (size_t)rowc * 64 + (ks - 64);
    else               src = VLb + (size_t)rowc * 128 + (ks - 128);
    short8 a = *(const short8*)src;
#pragma unroll
    for (int nt = 0; nt < 8; nt++) {
      short8 b = w0[((k0 >> 5) * 8 + nt) * 64 + lane];
      acc[nt] = __builtin_amdgcn_mfma_f32_16x16x32_bf16(a, b, acc[nt], 0, 0, 0);
    }
  }
#pragma unroll
  for (int nt = 0; nt < 8; nt++) {
    int col = nt * 16 + m16;
    float bv = wload(b0, col, isf32);
#pragma unroll
    for (int i = 0; i < 4; i++)
      h1[rl + i][col] = f2b(fmaxf(acc[nt][i] + bv, 0.0f));
  }
  __syncthreads();
#pragma unroll
  for (int nt = 0; nt < 8; nt++) acc[nt] = (float4v){0.f, 0.f, 0.f, 0.f};
  const short8* w1 = (const short8*)W1p;
  for (int k0 = 0; k0 < 128; k0 += 32) {
    short8 a = *(const short8*)&h1[wave * 16 + m16][k0 + quad * 8];
#pragma unroll
    for (int nt = 0; nt < 8; nt++) {
      short8 b = w1[((k0 >> 5) * 8 + nt) * 64 + lane];
      acc[nt] = __builtin_amdgcn_mfma_f32_16x16x32_bf16(a, b, acc[nt], 0, 0, 0);
    }
  }
#pragma unroll
  for (int nt = 0; nt < 8; nt++) {
    int col = nt * 16 + m16;
    float bv = wload(b1, col, isf32);
#pragma unroll
    for (int i = 0; i < 4; i++)
      h2[rl + i][col] = f2b(fmaxf(acc[nt][i] + bv, 0.0f));
  }
  __syncthreads();
  float4v acc3[4];
#pragma unroll
  for (int nt = 0; nt < 4; nt++) acc3[nt] = (float4v){0.f, 0.f, 0.f, 0.f};
  const short8* w2 = (const short8*)W2p;
  for (int k0 = 0; k0 < 128; k0 += 32) {
    short8 a = *(const short8*)&h2[wave * 16 + m16][k0 + quad * 8];
#pragma unroll
    for (int nt = 0; nt < 4; nt++) {
      short8 b = w2[((k0 >> 5) * 4 + nt) * 64 + lane];
      acc3[nt] = __builtin_amdgcn_mfma_f32_16x16x32_bf16(a, b, acc3[nt], 0, 0, 0);
    }
  }
  int rbase = blockIdx.x * 64 + wave * 16 + quad * 4;
#pragma unroll
  for (int nt = 0; nt < 4; nt++) {
    int col = nt * 16 + m16;
    float bv = wload(b2, col, isf32);
#pragma unroll
    for (int i = 0; i < 4; i++) {
      int r = rbase + i;
      if (r < N) NV[(size_t)r * 64 + col] = acc3[nt][i] + bv;
    }
  }
}

// ---------------------------------------------------------------------------
// Vectorized edge / node kernels: 8 lanes per row, short8 (16B) per lane.
// ---------------------------------------------------------------------------
__global__ void cl_kernel(const bf16* __restrict__ SP, const int* __restrict__ lit,
                          bf16* __restrict__ cl, float* __restrict__ stats) {
  if (blockIdx.x == 0) {
    for (int i = threadIdx.x; i < 4096; i += 256) stats[i] = 0.0f;
  }
  int t = blockIdx.x * 256 + threadIdx.x;
  int c = t >> 3, j = t & 7;
  if (c >= C_N) return;
  int l0 = lit[3 * c], l1 = lit[3 * c + 1], l2 = lit[3 * c + 2];
  short8 s0 = *(const short8*)&SP[(size_t)l0 * 64 + j * 8];
  short8 s1 = *(const short8*)&SP[(size_t)l1 * 64 + j * 8];
  short8 s2 = *(const short8*)&SP[(size_t)l2 * 64 + j * 8];
  short8 r;
#pragma unroll
  for (int e = 0; e < 8; e++) {
    float cv = sb2f(s0[e]) + sb2f(s1[e]) + sb2f(s2[e]);
    r[e] = f2sb(expf(-cv));
  }
  *(short8*)&cl[(size_t)c * 64 + j * 8] = r;
}

__global__ void qgrad_kernel(const bf16* __restrict__ Q, const bf16* __restrict__ clb,
                             const int* __restrict__ csr, const int* __restrict__ offs,
                             const float* __restrict__ vdw, bf16* __restrict__ QG) {
  int t = blockIdx.x * 256 + threadIdx.x;
  int v = t >> 3, j = t & 7;
  if (v >= V_N) return;
  float gp[8], gn[8];
#pragma unroll
  for (int e = 0; e < 8; e++) { gp[e] = 0.0f; gn[e] = 0.0f; }
  int p0 = offs[v], p1 = offs[v + 1];
  for (int p = p0; p < p1; p++) {
    short8 x = *(const short8*)&clb[(size_t)csr[p] * 64 + j * 8];
#pragma unroll
    for (int e = 0; e < 8; e++) gp[e] += sb2f(x[e]);
  }
  p0 = offs[v + V_N]; p1 = offs[v + V_N + 1];
  for (int p = p0; p < p1; p++) {
    short8 x = *(const short8*)&clb[(size_t)csr[p] * 64 + j * 8];
#pragma unroll
    for (int e = 0; e < 8; e++) gn[e] += sb2f(x[e]);
  }
  short8 qv = *(const short8*)&Q[(size_t)v * 64 + j * 8];
  float w = vdw[v];
  short8 r;
#pragma unroll
  for (int e = 0; e < 8; e++) {
    float q = sb2f(qv[e]);
    float sp = 1.0f / (1.0f + expf(-q));
    float sn = 1.0f / (1.0f + expf(q));
    r[e] = f2sb((-sp * gp[e] + sn * gn[e]) * w);
  }
  *(short8*)&QG[(size_t)v * 64 + j * 8] = r;
}

__global__ void vlb_gather_kernel(const bf16* __restrict__ Dl, const int* __restrict__ csr,
                                  const int* __restrict__ offs, const float* __restrict__ dw,
                                  bf16* __restrict__ VLb, float* __restrict__ stats) {
  if (blockIdx.x == 0) {
    for (int i = threadIdx.x; i < 4096; i += 256) stats[i] = 0.0f;
  }
  int t = blockIdx.x * 256 + threadIdx.x;
  int l = t >> 3, j = t & 7;
  if (l >= L_N) return;
  float s[8];
#pragma unroll
  for (int e = 0; e < 8; e++) s[e] = 0.0f;
  int p0 = offs[l], p1 = offs[l + 1];
  for (int p = p0; p < p1; p++) {
    short8 x = *(const short8*)&Dl[(size_t)csr[p] * 64 + j * 8];
#pragma unroll
    for (int e = 0; e < 8; e++) s[e] += sb2f(x[e]);
  }
  float w = dw[l];
  size_t v = (l < V_N) ? (size_t)l : (size_t)(l - V_N);
  int col = (l < V_N) ? 0 : 64;
  short8 r;
#pragma unroll
  for (int e = 0; e < 8; e++) r[e] = f2sb(s[e] * w);
  *(short8*)&VLb[v * 128 + col + j * 8] = r;
}

// ---------------------------------------------------------------------------
// PairNorm — vectorized one-pass stats + apply.
// ---------------------------------------------------------------------------
template<typename TX>
__global__ void pn_stats_kernel(const TX* __restrict__ X,
                                const int* __restrict__ gid, int n,
                                float* __restrict__ S1, float* __restrict__ S2) {
  int wave = blockIdx.x * blockDim.y + threadIdx.y;
  int nw = gridDim.x * blockDim.y;
  int chunk = (n + nw - 1) / nw;
  int i0 = wave * chunk;
  if (i0 >= n) return;
  int i1 = min(n, i0 + chunk);
  int lane = threadIdx.x;
  int sub = lane >> 3, j = lane & 7;
  float a1[8], a2[8];
#pragma unroll
  for (int e = 0; e < 8; e++) { a1[e] = 0.0f; a2[e] = 0.0f; }
  int ifirst = i0 + sub;
  if (ifirst >= i1) return;
  int g = gid[ifirst];
  for (int i = ifirst; i < i1; i += 8) {
    int gi = gid[i];
    if (gi != g) {
#pragma unroll
      for (int e = 0; e < 8; e++) {
        atomicAdd(&S1[g * 64 + j * 8 + e], a1[e]);
        atomicAdd(&S2[g * 64 + j * 8 + e], a2[e]);
        a1[e] = 0.0f; a2[e] = 0.0f;
      }
      g = gi;
    }
    float x[8];
    load8(&X[(size_t)i * 64 + j * 8], x);
#pragma unroll
    for (int e = 0; e < 8; e++) { a1[e] += x[e]; a2[e] += x[e] * x[e]; }
  }
#pragma unroll
  for (int e = 0; e < 8; e++) {
    atomicAdd(&S1[g * 64 + j * 8 + e], a1[e]);
    atomicAdd(&S2[g * 64 + j * 8 + e], a2[e]);
  }
}

template<typename TX>
__global__ void pn_apply_kernel(const TX* __restrict__ X,
                                const int* __restrict__ gid, int n,
                                const int* __restrict__ cnt, const float* __restrict__ S1,
                                const float* __restrict__ S2, bf16* __restrict__ state,
                                float post) {
  int t = blockIdx.x * 256 + threadIdx.x;
  int i = t >> 3, j = t & 7;
  if (i >= n) return;
  int g = gid[i];
  float c = fmaxf((float)cnt[g], 1.0f);
  float m[8], tv = 0.0f;
#pragma unroll
  for (int e = 0; e < 8; e++) {
    m[e] = S1[g * 64 + j * 8 + e] / c;
    tv += S2[g * 64 + j * 8 + e] / c - m[e] * m[e];
  }
#pragma unroll
  for (int o = 1; o < 8; o <<= 1) tv += __shfl_xor(tv, o);
  float var = fmaxf(tv, 0.0f) * (1.0f / 64.0f);
  float rs = rsqrtf(var + 1e-6f);
  float x[8];
  load8(&X[(size_t)i * 64 + j * 8], x);
  short8 st = *(const short8*)&state[(size_t)i * 64 + j * 8];
  short8 r;
#pragma unroll
  for (int e = 0; e < 8; e++) {
    float xn = (x[e] - m[e]) * rs;
    r[e] = f2sb((xn * 0.25f + 0.1f * sb2f(st[e])) * post);
  }
  *(short8*)&state[(size_t)i * 64 + j * 8] = r;
}

// MFMA co MLP + noise + sigmoid. 64 rows/block; col-reduce via 16-lane shfl.
__global__ __launch_bounds__(256) void co_final_kernel(
    const bf16* __restrict__ clauses, const bf16* __restrict__ W0p,
    const void* __restrict__ b0, const void* __restrict__ W1,
    const void* __restrict__ b1, const int* __restrict__ flagp,
    uint32_t ka, uint32_t kb, float* __restrict__ out) {
  int tid = threadIdx.x;
  int wave = tid >> 6, lane = tid & 63, quad = lane >> 4, m16 = lane & 15;
  int row = blockIdx.x * 64 + wave * 16 + m16;
  int rowc = min(row, C_N - 1);
  int isf32 = *flagp;
  float4v acc[4];
#pragma unroll
  for (int nt = 0; nt < 4; nt++) acc[nt] = (float4v){0.f, 0.f, 0.f, 0.f};
  const short8* w0 = (const short8*)W0p;
  for (int k0 = 0; k0 < 64; k0 += 32) {
    short8 a = *(const short8*)&clauses[(size_t)rowc * 64 + k0 + quad * 8];
#pragma unroll
    for (int nt = 0; nt < 4; nt++) {
      short8 b = w0[((k0 >> 5) * 4 + nt) * 64 + lane];
      acc[nt] = __builtin_amdgcn_mfma_f32_16x16x32_bf16(a, b, acc[nt], 0, 0, 0);
    }
  }
  float s[4] = {0.f, 0.f, 0.f, 0.f};
#pragma unroll
  for (int nt = 0; nt < 4; nt++) {
    int col = nt * 16 + m16;
    float bv = wload(b0, col, isf32);
    float w1v = wload(W1, col, isf32);
#pragma unroll
    for (int i = 0; i < 4; i++) s[i] += fmaxf(acc[nt][i] + bv, 0.0f) * w1v;
  }
#pragma unroll
  for (int o = 1; o < 16; o <<= 1) {
#pragma unroll
    for (int i = 0; i < 4; i++) s[i] += __shfl_xor(s[i], o);
  }
  if (m16 == 0) {
    int rbase = blockIdx.x * 64 + wave * 16 + quad * 4;
    float bb = wload(b1, 0, isf32);
#pragma unroll
    for (int i = 0; i < 4; i++) {
      int r = rbase + i;
      if (r < C_N) {
        float lg = s[i] + bb + normal_from_bits(part_bits(ka, kb, (uint32_t)r));
        out[r] = 1.0f / (1.0f + expf(-lg));
      }
    }
  }
}

// ---------------------------------------------------------------------------
// Launch
// ---------------------------------------------------------------------------
extern "C" void kernel_launch(void* const* d_in, const int* in_sizes, int n_in,
                              void* d_out, int out_size, void* d_ws, size_t ws_size,
                              hipStream_t stream) {
  (void)in_sizes; (void)n_in; (void)out_size;
  const int* lit_idx    = (const int*)d_in[0];
  const int* var_gid    = (const int*)d_in[2];
  const int* clause_gid = (const int*)d_in[3];
  const void* vq_W0 = d_in[4];
  const void* vq_b0 = d_in[5];
  const void* vq_W1 = d_in[6];
  const void* vq_b1 = d_in[7];
  const void* cm_W0 = d_in[8];
  const void* cm_b0 = d_in[9];
  const void* cm_W1 = d_in[10];
  const void* cm_b1 = d_in[11];
  const void* ug_W0 = d_in[12];
  const void* ug_b0 = d_in[13];
  const void* ug_W1 = d_in[14];
  const void* ug_b1 = d_in[15];
  const void* ug_W2 = d_in[16];
  const void* ug_b2 = d_in[17];
  const void* co_W0 = d_in[18];
  const void* co_b0 = d_in[19];
  const void* co_W1 = d_in[20];
  const void* co_b1 = d_in[21];
  float* out = (float*)d_out;

  // ---- workspace layout (~216 MB peak) ----
  char* ws = (char*)d_ws;
  size_t off = 0;
  auto alloc = [&](size_t bytes) -> void* {
    void* p = ws + off;
    off = (off + bytes + 255) & ~(size_t)255;
    return p;
  };
  bf16* variables = (bf16*)alloc((size_t)V_N * 64 * 2);   // persistent state
  bf16* clauses   = (bf16*)alloc((size_t)C_N * 64 * 2);   // persistent state
  // ZE (C*64*2): clb -> Dn (in-place overlay in cm_fused) -> VLb (V*128)
  char* ZE        = (char*)alloc((size_t)C_N * 64 * 2);
  // ZD (C*64*2): SP (L*64) -> Dl (C*64) -> NV f32 (V*64)
  char* ZD        = (char*)alloc((size_t)C_N * 64 * 2);
  bf16* QG        = (bf16*)alloc((size_t)V_N * 64 * 2);
  bf16* Q         = (bf16*)alloc((size_t)V_N * 64 * 2);
  int*  izone     = (int*)alloc((size_t)(2 * L_N + 64) * 4);
  int*  offs      = (int*)alloc((size_t)(L_N + 1) * 4);
  int*  csr       = (int*)alloc((size_t)E_N * 4);
  int*  spart     = (int*)alloc((size_t)(2 * SCAN_NB + 2) * 4);
  float* deg_f    = (float*)alloc((size_t)L_N * 4);
  float* vdw      = (float*)alloc((size_t)V_N * 4);
  float* stats    = (float*)alloc((size_t)4096 * 4);
  int*   wflag    = (int*)alloc(256);
  // packed MFMA weights (bf16)
  bf16* vq_W0p = (bf16*)alloc((size_t)96 * 64 * 2);
  bf16* vq_W1p = (bf16*)alloc((size_t)64 * 64 * 2);
  bf16* cm_W0p = (bf16*)alloc((size_t)128 * 128 * 2);
  bf16* cm_W1p = (bf16*)alloc((size_t)128 * 128 * 2);
  bf16* ug_W0p = (bf16*)alloc((size_t)256 * 128 * 2);
  bf16* ug_W1p = (bf16*)alloc((size_t)128 * 128 * 2);
  bf16* ug_W2p = (bf16*)alloc((size_t)128 * 64 * 2);
  bf16* co_W0p = (bf16*)alloc((size_t)64 * 64 * 2);
  size_t need = off;

  auto nb = [](int n, int per) { return (n + per - 1) / per; };

  if (ws_size < need) {
    fill_f32<<<nb(C_N, 256), 256, 0, stream>>>(out, (size_t)C_N, 0.5f);
    return;
  }

  bf16* clb = (bf16*)ZE;                 // C x 64
  bf16* Dn  = (bf16*)ZE;                 // C x 64 (in-place overlay)
  bf16* VLb = (bf16*)ZE;                 // V x 128 (after Dn consumed)
  bf16* SP  = (bf16*)ZD;                 // L x 64 (vq -> cl; dead before Dl)
  bf16* Dl  = (bf16*)ZD;                 // C x 64 (cm -> vlb_gather)
  float* NV = (float*)ZD;                // V x 64 f32 (after Dl consumed)

  int* deg_i  = izone;
  int* cursor = izone + L_N;
  int* cntv   = izone + 2 * L_N;
  int* cntc   = cntv + 32;
  int* sbase  = spart + SCAN_NB;         // SCAN_NB+1 entries
  float* S1 = stats;              // 32 x 64
  float* S2 = stats + 2048;       // 32 x 64

  // JAX keys = split(key(42), 9), partitionable: subkey_i = threefry(key,0,i)
  uint32_t kw0[9], kw1[9];
  for (int i = 0; i < 9; i++) tf2x32(0u, 42u, 0u, (uint32_t)i, &kw0[i], &kw1[i]);

  dim3 wb(64, 4);
  const int BIG = 1 << 30;

  // ---- setup (re-done every call) ----
  detect_dtype_kernel<<<1, 64, 0, stream>>>((const uint32_t*)vq_W0, wflag);
  fill_u32<<<nb(2 * L_N + 64, 256), 256, 0, stream>>>((uint32_t*)izone, (size_t)(2 * L_N + 64), 0u);
  count_deg_kernel<<<nb(E_N, 256), 256, 0, stream>>>(lit_idx, deg_i);
  hist32_kernel<<<nb(V_N, 256), 256, 0, stream>>>(var_gid, V_N, cntv);
  hist32_kernel<<<nb(C_N, 256), 256, 0, stream>>>(clause_gid, C_N, cntc);
  weights_kernel<<<nb(L_N, 256), 256, 0, stream>>>(deg_i, deg_f, vdw);
  scan_partial_kernel<<<SCAN_NB, 256, 0, stream>>>(deg_i, spart);
  scan_base_kernel<<<1, 256, 0, stream>>>(spart, sbase);
  scan_write_kernel<<<SCAN_NB, 256, 0, stream>>>(deg_i, sbase, offs);
  csr_fill_kernel<<<nb(E_N, 256), 256, 0, stream>>>(lit_idx, offs, cursor, csr);
  fill_b16<<<2048, 256, 0, stream>>>(variables, (size_t)V_N * 64, 1.0f);
  fill_b16<<<2048, 256, 0, stream>>>(clauses, (size_t)C_N * 64, 1.0f);
  // pack weights into MFMA B-fragment order
  pack_w_kernel<<<nb(96 * 64, 256), 256, 0, stream>>>(vq_W0, wflag, 68, 96, 64, 64, 0, BIG, 1.f, vq_W0p);
  pack_w_kernel<<<nb(64 * 64, 256), 256, 0, stream>>>(vq_W1, wflag, 64, 64, 64, 64, 0, BIG, 1.f, vq_W1p);
  pack_w_kernel<<<nb(128 * 128, 256), 256, 0, stream>>>(cm_W0, wflag, 128, 128, 128, 128, 0, 64, 4.f, cm_W0p);
  pack_w_kernel<<<nb(128 * 128, 256), 256, 0, stream>>>(cm_W1, wflag, 128, 128, 128, 128, 0, BIG, 1.f, cm_W1p);
  pack_w_kernel<<<nb(256 * 128, 256), 256, 0, stream>>>(ug_W0, wflag, 256, 256, 128, 128, 0, BIG, 1.f, ug_W0p);
  pack_w_kernel<<<nb(128 * 128, 256), 256, 0, stream>>>(ug_W1, wflag, 128, 128, 128, 128, 0, BIG, 1.f, ug_W1p);
  pack_w_kernel<<<nb(128 * 64, 256), 256, 0, stream>>>(ug_W2, wflag, 128, 128, 64, 64, 0, BIG, 1.f, ug_W2p);
  pack_w_kernel<<<nb(64 * 64, 256), 256, 0, stream>>>(co_W0, wflag, 64, 64, 64, 64, 0, BIG, 1.f, co_W0p);

  // ---- rounds (10 launches each) ----
  for (int r = 0; r < NROUNDS; r++) {
    vq_fused_kernel<<<nb(V_N, 64), 256, 0, stream>>>(
        variables, vq_W0p, vq_b0, vq_W1p, vq_b1, wflag, kw0[r], kw1[r], Q, SP, V_N);
    cl_kernel<<<nb(C_N * 8, 256), 256, 0, stream>>>(SP, lit_idx, clb, stats);
    qgrad_kernel<<<nb(V_N * 8, 256), 256, 0, stream>>>(Q, clb, csr, offs, vdw, QG);
    cm_fused_kernel<<<nb(C_N, 64), 256, 0, stream>>>(
        clauses, clb, cm_W0p, cm_b0, cm_W1p, cm_b1, wflag, Dl, Dn, C_N);
    pn_stats_kernel<bf16><<<128, wb, 0, stream>>>(Dn, clause_gid, C_N, S1, S2);
    pn_apply_kernel<bf16><<<nb(C_N * 8, 256), 256, 0, stream>>>(
        Dn, clause_gid, C_N, cntc, S1, S2, clauses, (r == NROUNDS - 1) ? 1.0f : 0.2f);
    vlb_gather_kernel<<<nb(L_N * 8, 256), 256, 0, stream>>>(Dl, csr, offs, deg_f, VLb, stats);
    ug_fused_kernel<<<nb(V_N, 64), 256, 0, stream>>>(
        QG, variables, VLb, ug_W0p, ug_b0, ug_W1p, ug_b1, ug_W2p, ug_b2,
        wflag, NV, V_N);
    pn_stats_kernel<float><<<128, wb, 0, stream>>>(NV, var_gid, V_N, S1, S2);
    pn_apply_kernel<float><<<nb(V_N * 8, 256), 256, 0, stream>>>(
        NV, var_gid, V_N, cntv, S1, S2, variables, 1.0f);
  }
  co_final_kernel<<<nb(C_N, 64), 256, 0, stream>>>(
      clauses, co_W0p, co_b0, co_W1, co_b1, wflag, kw0[8], kw1[8], out);
}

// Round 15
// 4023.277 us; speedup vs baseline: 5.8021x; 1.1450x over previous
//
#include <hip/hip_runtime.h>
#include <hip/hip_bf16.h>
#include <cstdint>
#include <cstddef>

// ---------------------------------------------------------------------------
// Problem constants
// ---------------------------------------------------------------------------
constexpr int V_N = 100000;   // variables
constexpr int C_N = 420000;   // clauses
constexpr int L_N = 2 * V_N;  // literals
constexpr int E_N = 3 * C_N;  // nnz edges
constexpr int NGR = 32;       // graphs
constexpr int NROUNDS = 8;
constexpr int SCAN_NB = (L_N + 255) / 256;   // 782 scan blocks

using bf16 = __hip_bfloat16;
typedef __attribute__((ext_vector_type(8))) short short8;   // 8 bf16 (4 VGPRs)
typedef __attribute__((ext_vector_type(4))) float float4v;  // 4 fp32 acc

__device__ inline float b2f(bf16 h) { return __bfloat162float(h); }
__device__ inline bf16 f2b(float f) { return __float2bfloat16(f); }
__device__ inline float sb2f(short s) { return __uint_as_float(((uint32_t)(uint16_t)s) << 16); }
__device__ inline short f2sb(float f) { bf16 h = f2b(f); return *(short*)&h; }

template<typename T> __device__ inline float loadT(const T* p);
template<> __device__ inline float loadT<float>(const float* p) { return *p; }
template<> __device__ inline float loadT<bf16>(const bf16* p) { return b2f(*p); }

// load 8 consecutive values as f32
template<typename TX> __device__ inline void load8(const TX* p, float* v);
template<> __device__ inline void load8<bf16>(const bf16* p, float* v) {
  short8 s = *(const short8*)p;
#pragma unroll
  for (int e = 0; e < 8; e++) v[e] = sb2f(s[e]);
}
template<> __device__ inline void load8<float>(const float* p, float* v) {
  float4 a = *(const float4*)p;
  float4 b = *(const float4*)(p + 4);
  v[0] = a.x; v[1] = a.y; v[2] = a.z; v[3] = a.w;
  v[4] = b.x; v[5] = b.y; v[6] = b.z; v[7] = b.w;
}

// runtime-dtype weight load: isf32 ? f32 buffer : packed bf16 buffer
__device__ inline float wload(const void* W, size_t idx, int isf32) {
  return isf32 ? ((const float*)W)[idx] : b2f(((const bf16*)W)[idx]);
}

// ---------------------------------------------------------------------------
// Threefry-2x32 (JAX-compatible, partitionable) — host+device
// ---------------------------------------------------------------------------
__host__ __device__ inline void tf2x32(uint32_t k0, uint32_t k1,
                                       uint32_t x0, uint32_t x1,
                                       uint32_t* o0, uint32_t* o1) {
  uint32_t ks2 = k0 ^ k1 ^ 0x1BD11BDAu;
  x0 += k0; x1 += k1;
#define TFR(d) do { x0 += x1; x1 = (x1 << (d)) | (x1 >> (32 - (d))); x1 ^= x0; } while (0)
  TFR(13); TFR(15); TFR(26); TFR(6);
  x0 += k1;  x1 += ks2 + 1u;
  TFR(17); TFR(29); TFR(16); TFR(24);
  x0 += ks2; x1 += k0 + 2u;
  TFR(13); TFR(15); TFR(26); TFR(6);
  x0 += k0;  x1 += k1 + 3u;
  TFR(17); TFR(29); TFR(16); TFR(24);
  x0 += k1;  x1 += ks2 + 4u;
  TFR(13); TFR(15); TFR(26); TFR(6);
  x0 += ks2; x1 += k0 + 5u;
#undef TFR
  *o0 = x0; *o1 = x1;
}

__device__ inline uint32_t part_bits(uint32_t ka, uint32_t kb, uint32_t e) {
  uint32_t h1, h2;
  tf2x32(ka, kb, 0u, e, &h1, &h2);
  return h1 ^ h2;
}

// XLA ErfInv32 polynomial (Giles)
__device__ inline float erfinv_f32(float x) {
  float w = -log1pf(-x * x);
  float p;
  if (w < 5.0f) {
    w -= 2.5f;
    p = 2.81022636e-08f;
    p = fmaf(p, w, 3.43273939e-07f);
    p = fmaf(p, w, -3.5233877e-06f);
    p = fmaf(p, w, -4.39150654e-06f);
    p = fmaf(p, w, 0.00021858087f);
    p = fmaf(p, w, -0.00125372503f);
    p = fmaf(p, w, -0.00417768164f);
    p = fmaf(p, w, 0.246640727f);
    p = fmaf(p, w, 1.50140941f);
  } else {
    w = sqrtf(w) - 3.0f;
    p = -0.000200214257f;
    p = fmaf(p, w, 0.000100950558f);
    p = fmaf(p, w, 0.00134934322f);
    p = fmaf(p, w, -0.00367342844f);
    p = fmaf(p, w, 0.00573950773f);
    p = fmaf(p, w, -0.0076224613f);
    p = fmaf(p, w, 0.00943887047f);
    p = fmaf(p, w, 1.00167406f);
    p = fmaf(p, w, 2.83297682f);
  }
  return p * x;
}

__device__ inline float normal_from_bits(uint32_t bits) {
  float u01 = __uint_as_float((bits >> 9) | 0x3f800000u) - 1.0f;  // [0,1)
  const float lo = -0.99999994f;
  float u = u01 * 2.0f + lo;
  u = fmaxf(lo, u);
  return 1.41421356f * erfinv_f32(u);
}

// ---------------------------------------------------------------------------
// Utility kernels
// ---------------------------------------------------------------------------
__global__ void fill_f32(float* p, size_t n, float v) {
  size_t i = (size_t)blockIdx.x * blockDim.x + threadIdx.x;
  size_t stride = (size_t)gridDim.x * blockDim.x;
  for (; i < n; i += stride) p[i] = v;
}
__global__ void fill_u32(uint32_t* p, size_t n, uint32_t v) {
  size_t i = (size_t)blockIdx.x * blockDim.x + threadIdx.x;
  size_t stride = (size_t)gridDim.x * blockDim.x;
  for (; i < n; i += stride) p[i] = v;
}
__global__ void fill_b16(bf16* p, size_t n, float v) {
  size_t i = (size_t)blockIdx.x * blockDim.x + threadIdx.x;
  size_t stride = (size_t)gridDim.x * blockDim.x;
  bf16 b = f2b(v);
  for (; i < n; i += stride) p[i] = b;
}

// Detect weight dtype (R8-verified). flag=1 -> f32, flag=0 -> bf16.
__global__ void detect_dtype_kernel(const uint32_t* __restrict__ w, int* __restrict__ flag) {
  if (blockIdx.x == 0 && threadIdx.x == 0) {
    int votes = 0;
    for (int i = 0; i < 16; i++) {
      uint32_t lo = w[i] & 0xFFFFu;
      uint32_t e = (lo >> 7) & 0xFFu;
      if (e >= 0x70u && e < 0x80u) votes++;
    }
    *flag = (votes >= 12) ? 0 : 1;
  }
}

// Pack W into MFMA B-fragment order (bf16).
__global__ void pack_w_kernel(const void* __restrict__ W, const int* __restrict__ flagp,
                              int realK, int Kpad, int M, int Wld, int wcol0,
                              int srow0, float sscale, bf16* __restrict__ out) {
  int idx = blockIdx.x * 256 + threadIdx.x;
  if (idx >= Kpad * M) return;
  int j = idx & 7;
  int lane = (idx >> 3) & 63;
  int t = idx >> 9;
  int MT = M / 16;
  int kt = t / MT, nt = t - kt * MT;
  int k = kt * 32 + (lane >> 4) * 8 + j;
  int n = nt * 16 + (lane & 15);
  float v = 0.0f;
  if (k < realK) {
    v = wload(W, (size_t)k * Wld + wcol0 + n, *flagp);
    if (k >= srow0) v *= sscale;
  }
  out[idx] = f2b(v);
}

__global__ void count_deg_kernel(const int* __restrict__ lit, int* __restrict__ deg) {
  int e = blockIdx.x * 256 + threadIdx.x;
  if (e < E_N) atomicAdd(&deg[lit[e]], 1);
}

__global__ void hist32_kernel(const int* __restrict__ gid, int n, int* __restrict__ out) {
  __shared__ int bins[NGR];
  int t = threadIdx.x;
  if (t < NGR) bins[t] = 0;
  __syncthreads();
  int i = blockIdx.x * 256 + t;
  if (i < n) atomicAdd(&bins[gid[i]], 1);
  __syncthreads();
  if (t < NGR && bins[t] > 0) atomicAdd(&out[t], bins[t]);
}

__global__ void weights_kernel(const int* __restrict__ deg,
                               float* __restrict__ dw, float* __restrict__ vdw) {
  int l = blockIdx.x * 256 + threadIdx.x;
  if (l < L_N) dw[l] = rsqrtf(fmaxf((float)deg[l], 1.0f));
  if (l < V_N) vdw[l] = 4.0f * rsqrtf(fmaxf((float)(deg[l] + deg[l + V_N]), 1.0f));
}

// ---- parallel 3-phase exclusive scan of L_N degrees -> offs[L_N+1] ----
__global__ void scan_partial_kernel(const int* __restrict__ deg, int* __restrict__ part) {
  __shared__ int red[256];
  int b = blockIdx.x, t = threadIdx.x;
  int i = b * 256 + t;
  red[t] = (i < L_N) ? deg[i] : 0;
  __syncthreads();
  for (int o = 128; o > 0; o >>= 1) {
    if (t < o) red[t] += red[t + o];
    __syncthreads();
  }
  if (t == 0) part[b] = red[0];
}

__global__ void scan_base_kernel(const int* __restrict__ part, int* __restrict__ base) {
  __shared__ int buf[SCAN_NB + 1];
  int t = threadIdx.x;
  for (int i = t; i < SCAN_NB; i += 256) buf[i] = part[i];
  __syncthreads();
  if (t == 0) {
    int acc = 0;
    for (int i = 0; i < SCAN_NB; i++) { int v = buf[i]; buf[i] = acc; acc += v; }
    buf[SCAN_NB] = acc;
  }
  __syncthreads();
  for (int i = t; i <= SCAN_NB; i += 256) base[i] = buf[i];
}

__global__ void scan_write_kernel(const int* __restrict__ deg, const int* __restrict__ base,
                                  int* __restrict__ offs) {
  __shared__ int s[256];
  int b = blockIdx.x, t = threadIdx.x;
  int i = b * 256 + t;
  int v = (i < L_N) ? deg[i] : 0;
  s[t] = v;
  __syncthreads();
  for (int o = 1; o < 256; o <<= 1) {
    int x = (t >= o) ? s[t - o] : 0;
    __syncthreads();
    s[t] += x;
    __syncthreads();
  }
  if (i < L_N) offs[i] = base[b] + s[t] - v;   // exclusive
  if (b == 0 && t == 0) offs[L_N] = base[SCAN_NB];
}

__global__ void csr_fill_kernel(const int* __restrict__ lit,
                                const int* __restrict__ offs, int* __restrict__ cursor,
                                int* __restrict__ csr) {
  int e = blockIdx.x * 256 + threadIdx.x;
  if (e < E_N) {
    int l = lit[e];
    int p = atomicAdd(&cursor[l], 1);
    csr[offs[l] + p] = e / 3;
  }
}

// ---------------------------------------------------------------------------
// Fused MLP kernels (MFMA). 256 thr = 4 waves; wave w owns 16 rows.
// ---------------------------------------------------------------------------

// vq: q = MLP([variables|Z]); writes per-literal SIGMOID table:
// SG[v] = sigmoid(-q) = exp(-softplus(q)); SG[v+V] = sigmoid(q).
// (cl = product of 3 gathered sigmoids; qgrad reads sigmoids from table.)
// Z computed inline via partitionable threefry.
__global__ __launch_bounds__(256) void vq_fused_kernel(
    const bf16* __restrict__ variables,
    const bf16* __restrict__ W0p, const void* __restrict__ b0,
    const bf16* __restrict__ W1p, const void* __restrict__ b1,
    const int* __restrict__ flagp, uint32_t ka, uint32_t kb,
    bf16* __restrict__ SG, int N) {
  __shared__ bf16 hs[64][72];
  int tid = threadIdx.x;
  int wave = tid >> 6, lane = tid & 63, quad = lane >> 4, m16 = lane & 15;
  int row = blockIdx.x * 64 + wave * 16 + m16;
  int rowc = min(row, N - 1);
  int isf32 = *flagp;
  float4v acc[4];
#pragma unroll
  for (int nt = 0; nt < 4; nt++) acc[nt] = (float4v){0.f, 0.f, 0.f, 0.f};
  const short8* w0 = (const short8*)W0p;
  for (int k0 = 0; k0 < 96; k0 += 32) {
    int ks = k0 + quad * 8;
    short8 a;
    if (ks < 64) {
      a = *(const short8*)(variables + (size_t)rowc * 64 + ks);
    } else if (ks == 64) {
#pragma unroll
      for (int e = 0; e < 8; e++)
        a[e] = (e < 4)
             ? f2sb(normal_from_bits(part_bits(ka, kb, (uint32_t)(rowc * 4 + e))))
             : (short)0;
    } else {
      a = (short8){0, 0, 0, 0, 0, 0, 0, 0};
    }
#pragma unroll
    for (int nt = 0; nt < 4; nt++) {
      short8 b = w0[((k0 >> 5) * 4 + nt) * 64 + lane];
      acc[nt] = __builtin_amdgcn_mfma_f32_16x16x32_bf16(a, b, acc[nt], 0, 0, 0);
    }
  }
  int rl = wave * 16 + quad * 4;
#pragma unroll
  for (int nt = 0; nt < 4; nt++) {
    int col = nt * 16 + m16;
    float bv = wload(b0, col, isf32);
#pragma unroll
    for (int i = 0; i < 4; i++)
      hs[rl + i][col] = f2b(fmaxf(acc[nt][i] + bv, 0.0f));
  }
  __syncthreads();
  float4v acc2[4];
#pragma unroll
  for (int nt = 0; nt < 4; nt++) acc2[nt] = (float4v){0.f, 0.f, 0.f, 0.f};
  const short8* w1 = (const short8*)W1p;
  for (int k0 = 0; k0 < 64; k0 += 32) {
    short8 a = *(const short8*)&hs[wave * 16 + m16][k0 + quad * 8];
#pragma unroll
    for (int nt = 0; nt < 4; nt++) {
      short8 b = w1[((k0 >> 5) * 4 + nt) * 64 + lane];
      acc2[nt] = __builtin_amdgcn_mfma_f32_16x16x32_bf16(a, b, acc2[nt], 0, 0, 0);
    }
  }
  int rbase = blockIdx.x * 64 + wave * 16 + quad * 4;
#pragma unroll
  for (int nt = 0; nt < 4; nt++) {
    int col = nt * 16 + m16;
    float bv = wload(b1, col, isf32);
#pragma unroll
    for (int i = 0; i < 4; i++) {
      int r = rbase + i;
      if (r < N) {
        float q = acc2[nt][i] + bv;
        float sgn = 1.0f / (1.0f + expf(q));    // sigmoid(-q)
        float sgp = 1.0f / (1.0f + expf(-q));   // sigmoid(q)
        SG[(size_t)r * 64 + col] = f2b(sgn);
        SG[(size_t)(r + V_N) * 64 + col] = f2b(sgp);
      }
    }
  }
}

// cm: H = relu([clauses|clb]@W0+b0); D = H@W1+b1; Dl=D[:,:64], Dn=D[:,64:].
__global__ __launch_bounds__(256) void cm_fused_kernel(
    const bf16* __restrict__ clauses, const bf16* __restrict__ clb,
    const bf16* __restrict__ W0p, const void* __restrict__ b0,
    const bf16* __restrict__ W1p, const void* __restrict__ b1,
    const int* __restrict__ flagp,
    bf16* __restrict__ Dl, bf16* __restrict__ Dn, int N) {
  __shared__ bf16 hs[64][136];
  int tid = threadIdx.x;
  int wave = tid >> 6, lane = tid & 63, quad = lane >> 4, m16 = lane & 15;
  int row = blockIdx.x * 64 + wave * 16 + m16;
  int rowc = min(row, N - 1);
  int isf32 = *flagp;
  float4v acc[8];
#pragma unroll
  for (int nt = 0; nt < 8; nt++) acc[nt] = (float4v){0.f, 0.f, 0.f, 0.f};
  const short8* w0 = (const short8*)W0p;
  for (int k0 = 0; k0 < 128; k0 += 32) {
    int ks = k0 + quad * 8;
    const bf16* src = (ks < 64) ? clauses + (size_t)rowc * 64 + ks
                                : clb + (size_t)rowc * 64 + (ks - 64);
    short8 a = *(const short8*)src;
#pragma unroll
    for (int nt = 0; nt < 8; nt++) {
      short8 b = w0[((k0 >> 5) * 8 + nt) * 64 + lane];
      acc[nt] = __builtin_amdgcn_mfma_f32_16x16x32_bf16(a, b, acc[nt], 0, 0, 0);
    }
  }
  int rl = wave * 16 + quad * 4;
#pragma unroll
  for (int nt = 0; nt < 8; nt++) {
    int col = nt * 16 + m16;
    float bv = wload(b0, col, isf32);
#pragma unroll
    for (int i = 0; i < 4; i++)
      hs[rl + i][col] = f2b(fmaxf(acc[nt][i] + bv, 0.0f));
  }
  __syncthreads();
#pragma unroll
  for (int nt = 0; nt < 8; nt++) acc[nt] = (float4v){0.f, 0.f, 0.f, 0.f};
  const short8* w1 = (const short8*)W1p;
  for (int k0 = 0; k0 < 128; k0 += 32) {
    short8 a = *(const short8*)&hs[wave * 16 + m16][k0 + quad * 8];
#pragma unroll
    for (int nt = 0; nt < 8; nt++) {
      short8 b = w1[((k0 >> 5) * 8 + nt) * 64 + lane];
      acc[nt] = __builtin_amdgcn_mfma_f32_16x16x32_bf16(a, b, acc[nt], 0, 0, 0);
    }
  }
  int rbase = blockIdx.x * 64 + wave * 16 + quad * 4;
#pragma unroll
  for (int nt = 0; nt < 8; nt++) {
    int col = nt * 16 + m16;
    float bv = wload(b1, col, isf32);
#pragma unroll
    for (int i = 0; i < 4; i++) {
      int r = rbase + i;
      if (r < N) {
        float v = acc[nt][i] + bv;
        if (col < 64) Dl[(size_t)r * 64 + col] = f2b(v);
        else          Dn[(size_t)r * 64 + (col - 64)] = f2b(v);
      }
    }
  }
}

// ug: 3-layer MLP [QG|variables|VLb](K=256) ->128 ->128 ->64, NV f32 out.
__global__ __launch_bounds__(256) void ug_fused_kernel(
    const bf16* __restrict__ QG, const bf16* __restrict__ variables,
    const bf16* __restrict__ VLb,
    const bf16* __restrict__ W0p, const void* __restrict__ b0,
    const bf16* __restrict__ W1p, const void* __restrict__ b1,
    const bf16* __restrict__ W2p, const void* __restrict__ b2,
    const int* __restrict__ flagp, float* __restrict__ NV, int N) {
  __shared__ bf16 h1[64][136];
  __shared__ bf16 h2[64][136];
  int tid = threadIdx.x;
  int wave = tid >> 6, lane = tid & 63, quad = lane >> 4, m16 = lane & 15;
  int row = blockIdx.x * 64 + wave * 16 + m16;
  int rowc = min(row, N - 1);
  int isf32 = *flagp;
  int rl = wave * 16 + quad * 4;
  float4v acc[8];
#pragma unroll
  for (int nt = 0; nt < 8; nt++) acc[nt] = (float4v){0.f, 0.f, 0.f, 0.f};
  const short8* w0 = (const short8*)W0p;
  for (int k0 = 0; k0 < 256; k0 += 32) {
    int ks = k0 + quad * 8;
    const bf16* src;
    if (ks < 64)       src = QG + (size_t)rowc * 64 + ks;
    else if (ks < 128) src = variables + (size_t)rowc * 64 + (ks - 64);
    else               src = VLb + (size_t)rowc * 128 + (ks - 128);
    short8 a = *(const short8*)src;
#pragma unroll
    for (int nt = 0; nt < 8; nt++) {
      short8 b = w0[((k0 >> 5) * 8 + nt) * 64 + lane];
      acc[nt] = __builtin_amdgcn_mfma_f32_16x16x32_bf16(a, b, acc[nt], 0, 0, 0);
    }
  }
#pragma unroll
  for (int nt = 0; nt < 8; nt++) {
    int col = nt * 16 + m16;
    float bv = wload(b0, col, isf32);
#pragma unroll
    for (int i = 0; i < 4; i++)
      h1[rl + i][col] = f2b(fmaxf(acc[nt][i] + bv, 0.0f));
  }
  __syncthreads();
#pragma unroll
  for (int nt = 0; nt < 8; nt++) acc[nt] = (float4v){0.f, 0.f, 0.f, 0.f};
  const short8* w1 = (const short8*)W1p;
  for (int k0 = 0; k0 < 128; k0 += 32) {
    short8 a = *(const short8*)&h1[wave * 16 + m16][k0 + quad * 8];
#pragma unroll
    for (int nt = 0; nt < 8; nt++) {
      short8 b = w1[((k0 >> 5) * 8 + nt) * 64 + lane];
      acc[nt] = __builtin_amdgcn_mfma_f32_16x16x32_bf16(a, b, acc[nt], 0, 0, 0);
    }
  }
#pragma unroll
  for (int nt = 0; nt < 8; nt++) {
    int col = nt * 16 + m16;
    float bv = wload(b1, col, isf32);
#pragma unroll
    for (int i = 0; i < 4; i++)
      h2[rl + i][col] = f2b(fmaxf(acc[nt][i] + bv, 0.0f));
  }
  __syncthreads();
  float4v acc3[4];
#pragma unroll
  for (int nt = 0; nt < 4; nt++) acc3[nt] = (float4v){0.f, 0.f, 0.f, 0.f};
  const short8* w2 = (const short8*)W2p;
  for (int k0 = 0; k0 < 128; k0 += 32) {
    short8 a = *(const short8*)&h2[wave * 16 + m16][k0 + quad * 8];
#pragma unroll
    for (int nt = 0; nt < 4; nt++) {
      short8 b = w2[((k0 >> 5) * 4 + nt) * 64 + lane];
      acc3[nt] = __builtin_amdgcn_mfma_f32_16x16x32_bf16(a, b, acc3[nt], 0, 0, 0);
    }
  }
  int rbase = blockIdx.x * 64 + wave * 16 + quad * 4;
#pragma unroll
  for (int nt = 0; nt < 4; nt++) {
    int col = nt * 16 + m16;
    float bv = wload(b2, col, isf32);
#pragma unroll
    for (int i = 0; i < 4; i++) {
      int r = rbase + i;
      if (r < N) NV[(size_t)r * 64 + col] = acc3[nt][i] + bv;
    }
  }
}

// ---------------------------------------------------------------------------
// Vectorized edge / node kernels: 8 lanes per row, short8 (16B) per lane.
// ---------------------------------------------------------------------------
// cl = product of 3 gathered sigmoids (exp(-sum softplus) identity); no exp.
__global__ void cl_kernel(const bf16* __restrict__ SG, const int* __restrict__ lit,
                          bf16* __restrict__ cl, float* __restrict__ stats) {
  if (blockIdx.x == 0) {
    for (int i = threadIdx.x; i < 4096; i += 256) stats[i] = 0.0f;
  }
  int t = blockIdx.x * 256 + threadIdx.x;
  int c = t >> 3, j = t & 7;
  if (c >= C_N) return;
  int l0 = lit[3 * c], l1 = lit[3 * c + 1], l2 = lit[3 * c + 2];
  short8 s0 = *(const short8*)&SG[(size_t)l0 * 64 + j * 8];
  short8 s1 = *(const short8*)&SG[(size_t)l1 * 64 + j * 8];
  short8 s2 = *(const short8*)&SG[(size_t)l2 * 64 + j * 8];
  short8 r;
#pragma unroll
  for (int e = 0; e < 8; e++)
    r[e] = f2sb(sb2f(s0[e]) * sb2f(s1[e]) * sb2f(s2[e]));
  *(short8*)&cl[(size_t)c * 64 + j * 8] = r;
}

// qgrad: CSR gather of clb; sigmoids read from SG table (no exp).
__global__ void qgrad_kernel(const bf16* __restrict__ SG, const bf16* __restrict__ clb,
                             const int* __restrict__ csr, const int* __restrict__ offs,
                             const float* __restrict__ vdw, bf16* __restrict__ QG) {
  int t = blockIdx.x * 256 + threadIdx.x;
  int v = t >> 3, j = t & 7;
  if (v >= V_N) return;
  float gp[8], gn[8];
#pragma unroll
  for (int e = 0; e < 8; e++) { gp[e] = 0.0f; gn[e] = 0.0f; }
  int p0 = offs[v], p1 = offs[v + 1];
  for (int p = p0; p < p1; p++) {
    short8 x = *(const short8*)&clb[(size_t)csr[p] * 64 + j * 8];
#pragma unroll
    for (int e = 0; e < 8; e++) gp[e] += sb2f(x[e]);
  }
  p0 = offs[v + V_N]; p1 = offs[v + V_N + 1];
  for (int p = p0; p < p1; p++) {
    short8 x = *(const short8*)&clb[(size_t)csr[p] * 64 + j * 8];
#pragma unroll
    for (int e = 0; e < 8; e++) gn[e] += sb2f(x[e]);
  }
  short8 sgn = *(const short8*)&SG[(size_t)v * 64 + j * 8];          // sigmoid(-q)
  short8 sgp = *(const short8*)&SG[(size_t)(v + V_N) * 64 + j * 8];  // sigmoid(q)
  float w = vdw[v];
  short8 r;
#pragma unroll
  for (int e = 0; e < 8; e++)
    r[e] = f2sb((-sb2f(sgp[e]) * gp[e] + sb2f(sgn[e]) * gn[e]) * w);
  *(short8*)&QG[(size_t)v * 64 + j * 8] = r;
}

__global__ void vlb_gather_kernel(const bf16* __restrict__ Dl, const int* __restrict__ csr,
                                  const int* __restrict__ offs, const float* __restrict__ dw,
                                  bf16* __restrict__ VLb, float* __restrict__ stats) {
  if (blockIdx.x == 0) {
    for (int i = threadIdx.x; i < 4096; i += 256) stats[i] = 0.0f;
  }
  int t = blockIdx.x * 256 + threadIdx.x;
  int l = t >> 3, j = t & 7;
  if (l >= L_N) return;
  float s[8];
#pragma unroll
  for (int e = 0; e < 8; e++) s[e] = 0.0f;
  int p0 = offs[l], p1 = offs[l + 1];
  for (int p = p0; p < p1; p++) {
    short8 x = *(const short8*)&Dl[(size_t)csr[p] * 64 + j * 8];
#pragma unroll
    for (int e = 0; e < 8; e++) s[e] += sb2f(x[e]);
  }
  float w = dw[l];
  size_t v = (l < V_N) ? (size_t)l : (size_t)(l - V_N);
  int col = (l < V_N) ? 0 : 64;
  short8 r;
#pragma unroll
  for (int e = 0; e < 8; e++) r[e] = f2sb(s[e] * w);
  *(short8*)&VLb[v * 128 + col + j * 8] = r;
}

// ---------------------------------------------------------------------------
// PairNorm — vectorized one-pass stats + apply.
// ---------------------------------------------------------------------------
template<typename TX>
__global__ void pn_stats_kernel(const TX* __restrict__ X,
                                const int* __restrict__ gid, int n,
                                float* __restrict__ S1, float* __restrict__ S2) {
  int wave = blockIdx.x * blockDim.y + threadIdx.y;
  int nw = gridDim.x * blockDim.y;
  int chunk = (n + nw - 1) / nw;
  int i0 = wave * chunk;
  if (i0 >= n) return;
  int i1 = min(n, i0 + chunk);
  int lane = threadIdx.x;
  int sub = lane >> 3, j = lane & 7;
  float a1[8], a2[8];
#pragma unroll
  for (int e = 0; e < 8; e++) { a1[e] = 0.0f; a2[e] = 0.0f; }
  int ifirst = i0 + sub;
  if (ifirst >= i1) return;
  int g = gid[ifirst];
  for (int i = ifirst; i < i1; i += 8) {
    int gi = gid[i];
    if (gi != g) {
#pragma unroll
      for (int e = 0; e < 8; e++) {
        atomicAdd(&S1[g * 64 + j * 8 + e], a1[e]);
        atomicAdd(&S2[g * 64 + j * 8 + e], a2[e]);
        a1[e] = 0.0f; a2[e] = 0.0f;
      }
      g = gi;
    }
    float x[8];
    load8(&X[(size_t)i * 64 + j * 8], x);
#pragma unroll
    for (int e = 0; e < 8; e++) { a1[e] += x[e]; a2[e] += x[e] * x[e]; }
  }
#pragma unroll
  for (int e = 0; e < 8; e++) {
    atomicAdd(&S1[g * 64 + j * 8 + e], a1[e]);
    atomicAdd(&S2[g * 64 + j * 8 + e], a2[e]);
  }
}

template<typename TX>
__global__ void pn_apply_kernel(const TX* __restrict__ X,
                                const int* __restrict__ gid, int n,
                                const int* __restrict__ cnt, const float* __restrict__ S1,
                                const float* __restrict__ S2, bf16* __restrict__ state,
                                float post) {
  int t = blockIdx.x * 256 + threadIdx.x;
  int i = t >> 3, j = t & 7;
  if (i >= n) return;
  int g = gid[i];
  float c = fmaxf((float)cnt[g], 1.0f);
  float m[8], tv = 0.0f;
#pragma unroll
  for (int e = 0; e < 8; e++) {
    m[e] = S1[g * 64 + j * 8 + e] / c;
    tv += S2[g * 64 + j * 8 + e] / c - m[e] * m[e];
  }
#pragma unroll
  for (int o = 1; o < 8; o <<= 1) tv += __shfl_xor(tv, o);
  float var = fmaxf(tv, 0.0f) * (1.0f / 64.0f);
  float rs = rsqrtf(var + 1e-6f);
  float x[8];
  load8(&X[(size_t)i * 64 + j * 8], x);
  short8 st = *(const short8*)&state[(size_t)i * 64 + j * 8];
  short8 r;
#pragma unroll
  for (int e = 0; e < 8; e++) {
    float xn = (x[e] - m[e]) * rs;
    r[e] = f2sb((xn * 0.25f + 0.1f * sb2f(st[e])) * post);
  }
  *(short8*)&state[(size_t)i * 64 + j * 8] = r;
}

// MFMA co MLP + noise + sigmoid. 64 rows/block; col-reduce via 16-lane shfl.
__global__ __launch_bounds__(256) void co_final_kernel(
    const bf16* __restrict__ clauses, const bf16* __restrict__ W0p,
    const void* __restrict__ b0, const void* __restrict__ W1,
    const void* __restrict__ b1, const int* __restrict__ flagp,
    uint32_t ka, uint32_t kb, float* __restrict__ out) {
  int tid = threadIdx.x;
  int wave = tid >> 6, lane = tid & 63, quad = lane >> 4, m16 = lane & 15;
  int row = blockIdx.x * 64 + wave * 16 + m16;
  int rowc = min(row, C_N - 1);
  int isf32 = *flagp;
  float4v acc[4];
#pragma unroll
  for (int nt = 0; nt < 4; nt++) acc[nt] = (float4v){0.f, 0.f, 0.f, 0.f};
  const short8* w0 = (const short8*)W0p;
  for (int k0 = 0; k0 < 64; k0 += 32) {
    short8 a = *(const short8*)&clauses[(size_t)rowc * 64 + k0 + quad * 8];
#pragma unroll
    for (int nt = 0; nt < 4; nt++) {
      short8 b = w0[((k0 >> 5) * 4 + nt) * 64 + lane];
      acc[nt] = __builtin_amdgcn_mfma_f32_16x16x32_bf16(a, b, acc[nt], 0, 0, 0);
    }
  }
  float s[4] = {0.f, 0.f, 0.f, 0.f};
#pragma unroll
  for (int nt = 0; nt < 4; nt++) {
    int col = nt * 16 + m16;
    float bv = wload(b0, col, isf32);
    float w1v = wload(W1, col, isf32);
#pragma unroll
    for (int i = 0; i < 4; i++) s[i] += fmaxf(acc[nt][i] + bv, 0.0f) * w1v;
  }
#pragma unroll
  for (int o = 1; o < 16; o <<= 1) {
#pragma unroll
    for (int i = 0; i < 4; i++) s[i] += __shfl_xor(s[i], o);
  }
  if (m16 == 0) {
    int rbase = blockIdx.x * 64 + wave * 16 + quad * 4;
    float bb = wload(b1, 0, isf32);
#pragma unroll
    for (int i = 0; i < 4; i++) {
      int r = rbase + i;
      if (r < C_N) {
        float lg = s[i] + bb + normal_from_bits(part_bits(ka, kb, (uint32_t)r));
        out[r] = 1.0f / (1.0f + expf(-lg));
      }
    }
  }
}

// ---------------------------------------------------------------------------
// Launch
// ---------------------------------------------------------------------------
extern "C" void kernel_launch(void* const* d_in, const int* in_sizes, int n_in,
                              void* d_out, int out_size, void* d_ws, size_t ws_size,
                              hipStream_t stream) {
  (void)in_sizes; (void)n_in; (void)out_size;
  const int* lit_idx    = (const int*)d_in[0];
  const int* var_gid    = (const int*)d_in[2];
  const int* clause_gid = (const int*)d_in[3];
  const void* vq_W0 = d_in[4];
  const void* vq_b0 = d_in[5];
  const void* vq_W1 = d_in[6];
  const void* vq_b1 = d_in[7];
  const void* cm_W0 = d_in[8];
  const void* cm_b0 = d_in[9];
  const void* cm_W1 = d_in[10];
  const void* cm_b1 = d_in[11];
  const void* ug_W0 = d_in[12];
  const void* ug_b0 = d_in[13];
  const void* ug_W1 = d_in[14];
  const void* ug_b1 = d_in[15];
  const void* ug_W2 = d_in[16];
  const void* ug_b2 = d_in[17];
  const void* co_W0 = d_in[18];
  const void* co_b0 = d_in[19];
  const void* co_W1 = d_in[20];
  const void* co_b1 = d_in[21];
  float* out = (float*)d_out;

  // ---- workspace layout (~215 MB peak) ----
  char* ws = (char*)d_ws;
  size_t off = 0;
  auto alloc = [&](size_t bytes) -> void* {
    void* p = ws + off;
    off = (off + bytes + 255) & ~(size_t)255;
    return p;
  };
  bf16* variables = (bf16*)alloc((size_t)V_N * 64 * 2);   // persistent state
  bf16* clauses   = (bf16*)alloc((size_t)C_N * 64 * 2);   // persistent state
  // ZE (C*64*2): clb -> Dn (in-place overlay in cm_fused) -> VLb (V*128)
  char* ZE        = (char*)alloc((size_t)C_N * 64 * 2);
  // ZD (C*64*2): SG (L*64) -> Dl (C*64) -> NV f32 (V*64)
  char* ZD        = (char*)alloc((size_t)C_N * 64 * 2);
  bf16* QG        = (bf16*)alloc((size_t)V_N * 64 * 2);
  int*  izone     = (int*)alloc((size_t)(2 * L_N + 64) * 4);
  int*  offs      = (int*)alloc((size_t)(L_N + 1) * 4);
  int*  csr       = (int*)alloc((size_t)E_N * 4);
  int*  spart     = (int*)alloc((size_t)(2 * SCAN_NB + 2) * 4);
  float* deg_f    = (float*)alloc((size_t)L_N * 4);
  float* vdw      = (float*)alloc((size_t)V_N * 4);
  float* stats    = (float*)alloc((size_t)4096 * 4);
  int*   wflag    = (int*)alloc(256);
  // packed MFMA weights (bf16)
  bf16* vq_W0p = (bf16*)alloc((size_t)96 * 64 * 2);
  bf16* vq_W1p = (bf16*)alloc((size_t)64 * 64 * 2);
  bf16* cm_W0p = (bf16*)alloc((size_t)128 * 128 * 2);
  bf16* cm_W1p = (bf16*)alloc((size_t)128 * 128 * 2);
  bf16* ug_W0p = (bf16*)alloc((size_t)256 * 128 * 2);
  bf16* ug_W1p = (bf16*)alloc((size_t)128 * 128 * 2);
  bf16* ug_W2p = (bf16*)alloc((size_t)128 * 64 * 2);
  bf16* co_W0p = (bf16*)alloc((size_t)64 * 64 * 2);
  size_t need = off;

  auto nb = [](int n, int per) { return (n + per - 1) / per; };

  if (ws_size < need) {
    fill_f32<<<nb(C_N, 256), 256, 0, stream>>>(out, (size_t)C_N, 0.5f);
    return;
  }

  bf16* clb = (bf16*)ZE;                 // C x 64
  bf16* Dn  = (bf16*)ZE;                 // C x 64 (in-place overlay)
  bf16* VLb = (bf16*)ZE;                 // V x 128 (after Dn consumed)
  bf16* SG  = (bf16*)ZD;                 // L x 64 sigmoid table (vq -> cl,qgrad)
  bf16* Dl  = (bf16*)ZD;                 // C x 64 (cm -> vlb_gather)
  float* NV = (float*)ZD;                // V x 64 f32 (after Dl consumed)

  int* deg_i  = izone;
  int* cursor = izone + L_N;
  int* cntv   = izone + 2 * L_N;
  int* cntc   = cntv + 32;
  int* sbase  = spart + SCAN_NB;         // SCAN_NB+1 entries
  float* S1 = stats;              // 32 x 64
  float* S2 = stats + 2048;       // 32 x 64

  // JAX keys = split(key(42), 9), partitionable: subkey_i = threefry(key,0,i)
  uint32_t kw0[9], kw1[9];
  for (int i = 0; i < 9; i++) tf2x32(0u, 42u, 0u, (uint32_t)i, &kw0[i], &kw1[i]);

  dim3 wb(64, 4);
  const int BIG = 1 << 30;

  // ---- setup (re-done every call) ----
  detect_dtype_kernel<<<1, 64, 0, stream>>>((const uint32_t*)vq_W0, wflag);
  fill_u32<<<nb(2 * L_N + 64, 256), 256, 0, stream>>>((uint32_t*)izone, (size_t)(2 * L_N + 64), 0u);
  count_deg_kernel<<<nb(E_N, 256), 256, 0, stream>>>(lit_idx, deg_i);
  hist32_kernel<<<nb(V_N, 256), 256, 0, stream>>>(var_gid, V_N, cntv);
  hist32_kernel<<<nb(C_N, 256), 256, 0, stream>>>(clause_gid, C_N, cntc);
  weights_kernel<<<nb(L_N, 256), 256, 0, stream>>>(deg_i, deg_f, vdw);
  scan_partial_kernel<<<SCAN_NB, 256, 0, stream>>>(deg_i, spart);
  scan_base_kernel<<<1, 256, 0, stream>>>(spart, sbase);
  scan_write_kernel<<<SCAN_NB, 256, 0, stream>>>(deg_i, sbase, offs);
  csr_fill_kernel<<<nb(E_N, 256), 256, 0, stream>>>(lit_idx, offs, cursor, csr);
  fill_b16<<<2048, 256, 0, stream>>>(variables, (size_t)V_N * 64, 1.0f);
  fill_b16<<<2048, 256, 0, stream>>>(clauses, (size_t)C_N * 64, 1.0f);
  // pack weights into MFMA B-fragment order
  pack_w_kernel<<<nb(96 * 64, 256), 256, 0, stream>>>(vq_W0, wflag, 68, 96, 64, 64, 0, BIG, 1.f, vq_W0p);
  pack_w_kernel<<<nb(64 * 64, 256), 256, 0, stream>>>(vq_W1, wflag, 64, 64, 64, 64, 0, BIG, 1.f, vq_W1p);
  pack_w_kernel<<<nb(128 * 128, 256), 256, 0, stream>>>(cm_W0, wflag, 128, 128, 128, 128, 0, 64, 4.f, cm_W0p);
  pack_w_kernel<<<nb(128 * 128, 256), 256, 0, stream>>>(cm_W1, wflag, 128, 128, 128, 128, 0, BIG, 1.f, cm_W1p);
  pack_w_kernel<<<nb(256 * 128, 256), 256, 0, stream>>>(ug_W0, wflag, 256, 256, 128, 128, 0, BIG, 1.f, ug_W0p);
  pack_w_kernel<<<nb(128 * 128, 256), 256, 0, stream>>>(ug_W1, wflag, 128, 128, 128, 128, 0, BIG, 1.f, ug_W1p);
  pack_w_kernel<<<nb(128 * 64, 256), 256, 0, stream>>>(ug_W2, wflag, 128, 128, 64, 64, 0, BIG, 1.f, ug_W2p);
  pack_w_kernel<<<nb(64 * 64, 256), 256, 0, stream>>>(co_W0, wflag, 64, 64, 64, 64, 0, BIG, 1.f, co_W0p);

  // ---- rounds (10 launches each) ----
  for (int r = 0; r < NROUNDS; r++) {
    vq_fused_kernel<<<nb(V_N, 64), 256, 0, stream>>>(
        variables, vq_W0p, vq_b0, vq_W1p, vq_b1, wflag, kw0[r], kw1[r], SG, V_N);
    cl_kernel<<<nb(C_N * 8, 256), 256, 0, stream>>>(SG, lit_idx, clb, stats);
    qgrad_kernel<<<nb(V_N * 8, 256), 256, 0, stream>>>(SG, clb, csr, offs, vdw, QG);
    cm_fused_kernel<<<nb(C_N, 64), 256, 0, stream>>>(
        clauses, clb, cm_W0p, cm_b0, cm_W1p, cm_b1, wflag, Dl, Dn, C_N);
    pn_stats_kernel<bf16><<<128, wb, 0, stream>>>(Dn, clause_gid, C_N, S1, S2);
    pn_apply_kernel<bf16><<<nb(C_N * 8, 256), 256, 0, stream>>>(
        Dn, clause_gid, C_N, cntc, S1, S2, clauses, (r == NROUNDS - 1) ? 1.0f : 0.2f);
    vlb_gather_kernel<<<nb(L_N * 8, 256), 256, 0, stream>>>(Dl, csr, offs, deg_f, VLb, stats);
    ug_fused_kernel<<<nb(V_N, 64), 256, 0, stream>>>(
        QG, variables, VLb, ug_W0p, ug_b0, ug_W1p, ug_b1, ug_W2p, ug_b2,
        wflag, NV, V_N);
    pn_stats_kernel<float><<<128, wb, 0, stream>>>(NV, var_gid, V_N, S1, S2);
    pn_apply_kernel<float><<<nb(V_N * 8, 256), 256, 0, stream>>>(
        NV, var_gid, V_N, cntv, S1, S2, variables, 1.0f);
  }
  co_final_kernel<<<nb(C_N, 64), 256, 0, stream>>>(
      clauses, co_W0p, co_b0, co_W1, co_b1, wflag, kw0[8], kw1[8], out);
}